// Round 1
// baseline (715.973 us; speedup 1.0000x reference)
//
#include <hip/hip_runtime.h>
#include <hip/hip_bf16.h>

#define SCAN_BLK 1024

// ---------------- CSR build ----------------

__global__ void k_hist(const int* __restrict__ col, int* __restrict__ counts, int n) {
  int e = blockIdx.x * blockDim.x + threadIdx.x;
  if (e < n) atomicAdd(&counts[col[e]], 1);
}

__global__ void k_dinv(const int* __restrict__ counts, float* __restrict__ dinv, int n) {
  int i = blockIdx.x * blockDim.x + threadIdx.x;
  if (i < n) dinv[i] = rsqrtf((float)counts[i] + 1.0f);  // +1 self loop, deg>=1 always
}

__global__ void k_scan1(const int* __restrict__ counts, int* __restrict__ offs,
                        int* __restrict__ partials, int n) {
  __shared__ int buf[2][SCAN_BLK];
  int t = threadIdx.x;
  int gid = blockIdx.x * SCAN_BLK + t;
  int x = (gid < n) ? counts[gid] : 0;
  int cur = 0;
  buf[0][t] = x;
  __syncthreads();
  int v = x;
  for (int off = 1; off < SCAN_BLK; off <<= 1) {
    v = buf[cur][t];
    if (t >= off) v += buf[cur][t - off];
    buf[cur ^ 1][t] = v;
    cur ^= 1;
    __syncthreads();
  }
  if (gid < n) offs[gid] = v - x;                 // block-local exclusive
  if (t == SCAN_BLK - 1) partials[blockIdx.x] = v; // block total
}

__global__ void k_scan2(int* __restrict__ partials, int* __restrict__ total_out, int nb) {
  __shared__ int buf[2][128];
  int t = threadIdx.x;
  int x = (t < nb) ? partials[t] : 0;
  int cur = 0;
  buf[0][t] = x;
  __syncthreads();
  int v = x;
  for (int off = 1; off < 128; off <<= 1) {
    v = buf[cur][t];
    if (t >= off) v += buf[cur][t - off];
    buf[cur ^ 1][t] = v;
    cur ^= 1;
    __syncthreads();
  }
  if (t < nb) partials[t] = v - x;   // exclusive
  if (t == 127) *total_out = v;      // grand total -> offs[N]
}

__global__ void k_scan3(int* __restrict__ offs, int* __restrict__ cursor,
                        const int* __restrict__ partials, int n) {
  int gid = blockIdx.x * SCAN_BLK + threadIdx.x;
  if (gid < n) {
    int v = offs[gid] + partials[blockIdx.x];
    offs[gid] = v;
    cursor[gid] = v;  // fill cursor copy
  }
}

__global__ void k_fill(const int* __restrict__ erow, const int* __restrict__ ecol,
                       const float* __restrict__ dinv, int* __restrict__ cursor,
                       int* __restrict__ srow, float* __restrict__ sw, int n) {
  int e = blockIdx.x * blockDim.x + threadIdx.x;
  if (e < n) {
    int r = erow[e], c = ecol[e];
    int pos = atomicAdd(&cursor[c], 1);
    srow[pos] = r;
    sw[pos] = dinv[r] * dinv[c];
  }
}

// ---------------- GEMM: C[n,128] = X[n,128] @ W[128,128] ----------------
// 64x64 tile per block, 256 threads, 4x4 register tile, k-step 8, X staged transposed.

__global__ __launch_bounds__(256) void k_gemm128(const float* __restrict__ X,
                                                 const float* __restrict__ W,
                                                 float* __restrict__ C, int n) {
  __shared__ __align__(16) float Xs[8][68];  // Xs[k][m]
  __shared__ __align__(16) float Ws[8][68];  // Ws[k][nn]
  int t = threadIdx.x;
  int tx = t & 15, ty = t >> 4;
  int row0 = blockIdx.x * 64;
  int col0 = blockIdx.y * 64;
  float acc[4][4] = {};
  for (int k0 = 0; k0 < 128; k0 += 8) {
    if (t < 128) {
      int r = t >> 1, kq = t & 1;  // 64 rows x 2 float4
      int gr = row0 + r;
      float4 v = make_float4(0.f, 0.f, 0.f, 0.f);
      if (gr < n) v = *reinterpret_cast<const float4*>(&X[(size_t)gr * 128 + k0 + kq * 4]);
      Xs[kq * 4 + 0][r] = v.x;
      Xs[kq * 4 + 1][r] = v.y;
      Xs[kq * 4 + 2][r] = v.z;
      Xs[kq * 4 + 3][r] = v.w;
    } else {
      int u = t - 128;
      int kk = u >> 4, cq = u & 15;  // 8 k-rows x 16 float4
      float4 v = *reinterpret_cast<const float4*>(&W[(size_t)(k0 + kk) * 128 + col0 + cq * 4]);
      *reinterpret_cast<float4*>(&Ws[kk][cq * 4]) = v;
    }
    __syncthreads();
#pragma unroll
    for (int kk = 0; kk < 8; ++kk) {
      float4 a = *reinterpret_cast<const float4*>(&Xs[kk][ty * 4]);
      float4 b = *reinterpret_cast<const float4*>(&Ws[kk][tx * 4]);
      float av[4] = {a.x, a.y, a.z, a.w};
      float bv[4] = {b.x, b.y, b.z, b.w};
#pragma unroll
      for (int i = 0; i < 4; ++i)
#pragma unroll
        for (int j = 0; j < 4; ++j) acc[i][j] += av[i] * bv[j];
    }
    __syncthreads();
  }
#pragma unroll
  for (int i = 0; i < 4; ++i) {
    int gr = row0 + ty * 4 + i;
    if (gr < n) {
      float4 v = make_float4(acc[i][0], acc[i][1], acc[i][2], acc[i][3]);
      *reinterpret_cast<float4*>(&C[(size_t)gr * 128 + col0 + tx * 4]) = v;
    }
  }
}

// ---------------- Aggregation: out[i] = relu?( dinv_i^2*h[i] + sum_e w_e h[row_e] + b ) ----
// one wave (64 lanes) per node, float2 per lane (128 cols).

__global__ __launch_bounds__(256) void k_agg(const float* __restrict__ h,
                                             const int* __restrict__ offs,
                                             const int* __restrict__ srow,
                                             const float* __restrict__ sw,
                                             const float* __restrict__ dinv,
                                             const float* __restrict__ bias,
                                             float* __restrict__ out, int n, int do_relu) {
  int wid = (blockIdx.x * blockDim.x + threadIdx.x) >> 6;
  int lane = threadIdx.x & 63;
  if (wid >= n) return;
  float di = dinv[wid];
  float w0 = di * di;
  float2 acc = reinterpret_cast<const float2*>(h + (size_t)wid * 128)[lane];
  acc.x *= w0;
  acc.y *= w0;
  int s = offs[wid], e = offs[wid + 1];
  for (int p = s; p < e; ++p) {
    int r = srow[p];
    float w = sw[p];
    float2 hv = reinterpret_cast<const float2*>(h + (size_t)r * 128)[lane];
    acc.x += w * hv.x;
    acc.y += w * hv.y;
  }
  float2 b = reinterpret_cast<const float2*>(bias)[lane];
  acc.x += b.x;
  acc.y += b.y;
  if (do_relu) {
    acc.x = fmaxf(acc.x, 0.f);
    acc.y = fmaxf(acc.y, 0.f);
  }
  reinterpret_cast<float2*>(out + (size_t)wid * 128)[lane] = acc;
}

// ---------------- Output GEMM: out[n,40] = X[n,128] @ W[128,40] + b ----------------

__global__ __launch_bounds__(256) void k_gemm_out(const float* __restrict__ X,
                                                  const float* __restrict__ W,
                                                  const float* __restrict__ b,
                                                  float* __restrict__ out, int n) {
  __shared__ __align__(16) float Xs[32][129];
  __shared__ __align__(16) float Ws[128 * 40];
  int t = threadIdx.x;
  int row0 = blockIdx.x * 32;
#pragma unroll
  for (int j = 0; j < 4; ++j) {
    int f = t + j * 256;          // float4 id, 1024 total
    int r = f >> 5, q = f & 31;   // 32 rows x 32 float4
    float4 v = make_float4(0.f, 0.f, 0.f, 0.f);
    if (row0 + r < n) v = *reinterpret_cast<const float4*>(&X[(size_t)(row0 + r) * 128 + q * 4]);
    Xs[r][q * 4 + 0] = v.x;
    Xs[r][q * 4 + 1] = v.y;
    Xs[r][q * 4 + 2] = v.z;
    Xs[r][q * 4 + 3] = v.w;
  }
#pragma unroll
  for (int j = 0; j < 5; ++j) {
    int f = t + j * 256;          // 1280 float4 = 5120 floats
    reinterpret_cast<float4*>(Ws)[f] = reinterpret_cast<const float4*>(W)[f];
  }
  __syncthreads();
#pragma unroll
  for (int j = 0; j < 5; ++j) {
    int o = t + j * 256;          // 0..1279 = 32 rows x 40 cols
    int r = o / 40, c = o - r * 40;
    if (row0 + r < n) {
      float acc = b[c];
#pragma unroll
      for (int k = 0; k < 128; ++k) acc += Xs[r][k] * Ws[k * 40 + c];
      out[(size_t)(row0 + r) * 40 + c] = acc;
    }
  }
}

// ---------------- launch ----------------

extern "C" void kernel_launch(void* const* d_in, const int* in_sizes, int n_in,
                              void* d_out, int out_size, void* d_ws, size_t ws_size,
                              hipStream_t stream) {
  const float* x = (const float*)d_in[0];
  const int* ei = (const int*)d_in[1];
  const float* W1 = (const float*)d_in[2];
  const float* b1 = (const float*)d_in[3];
  const float* W2 = (const float*)d_in[4];
  const float* b2 = (const float*)d_in[5];
  const float* Wout = (const float*)d_in[6];
  const float* bout = (const float*)d_in[7];
  float* out = (float*)d_out;

  const int N = in_sizes[0] / 128;
  const int E = in_sizes[1] / 2;
  const int* erow = ei;      // edge_index[0] = source j
  const int* ecol = ei + E;  // edge_index[1] = target i

  char* ws = (char*)d_ws;
  size_t off = 0;
  auto alloc = [&](size_t bytes) -> void* {
    void* p = ws + off;
    off = (off + bytes + 255) & ~(size_t)255;
    return p;
  };
  int* counts = (int*)alloc((size_t)N * 4);          // later reused as fill cursor
  int* offs = (int*)alloc((size_t)(N + 1) * 4);
  float* dinv = (float*)alloc((size_t)N * 4);
  int* partials = (int*)alloc(128 * 4);
  int* srow = (int*)alloc((size_t)E * 4);
  float* sw = (float*)alloc((size_t)E * 4);
  float* bufA = (float*)alloc((size_t)N * 128 * 4);
  float* bufB = (float*)alloc((size_t)N * 128 * 4);

  hipMemsetAsync(counts, 0, (size_t)N * 4, stream);

  k_hist<<<(E + 255) / 256, 256, 0, stream>>>(ecol, counts, E);
  k_dinv<<<(N + 255) / 256, 256, 0, stream>>>(counts, dinv, N);

  int nb = (N + SCAN_BLK - 1) / SCAN_BLK;  // 98 for N=100000 (<=128 required)
  k_scan1<<<nb, SCAN_BLK, 0, stream>>>(counts, offs, partials, N);
  k_scan2<<<1, 128, 0, stream>>>(partials, offs + N, nb);
  k_scan3<<<nb, SCAN_BLK, 0, stream>>>(offs, counts, partials, N);
  k_fill<<<(E + 255) / 256, 256, 0, stream>>>(erow, ecol, dinv, counts, srow, sw, E);

  dim3 g128((N + 63) / 64, 2);
  k_gemm128<<<g128, 256, 0, stream>>>(x, W1, bufA, N);
  k_agg<<<(N + 3) / 4, 256, 0, stream>>>(bufA, offs, srow, sw, dinv, b1, bufB, N, 1);
  k_gemm128<<<g128, 256, 0, stream>>>(bufB, W2, bufA, N);
  k_agg<<<(N + 3) / 4, 256, 0, stream>>>(bufA, offs, srow, sw, dinv, b2, bufB, N, 1);
  k_gemm_out<<<(N + 31) / 32, 256, 0, stream>>>(bufB, Wout, bout, out, N);
}

// Round 2
// 590.844 us; speedup vs baseline: 1.2118x; 1.2118x over previous
//
#include <hip/hip_runtime.h>
#include <hip/hip_bf16.h>

#define SCAN_BLK 1024

// ---------------- CSR build ----------------

__global__ void k_hist(const int* __restrict__ col, int* __restrict__ counts, int n) {
  int e = blockIdx.x * blockDim.x + threadIdx.x;
  if (e < n) atomicAdd(&counts[col[e]], 1);
}

__global__ void k_dinv(const int* __restrict__ counts, float* __restrict__ dinv, int n) {
  int i = blockIdx.x * blockDim.x + threadIdx.x;
  if (i < n) dinv[i] = rsqrtf((float)counts[i] + 1.0f);  // +1 self loop, deg>=1 always
}

__global__ void k_scan1(const int* __restrict__ counts, int* __restrict__ offs,
                        int* __restrict__ partials, int n) {
  __shared__ int buf[2][SCAN_BLK];
  int t = threadIdx.x;
  int gid = blockIdx.x * SCAN_BLK + t;
  int x = (gid < n) ? counts[gid] : 0;
  int cur = 0;
  buf[0][t] = x;
  __syncthreads();
  int v = x;
  for (int off = 1; off < SCAN_BLK; off <<= 1) {
    v = buf[cur][t];
    if (t >= off) v += buf[cur][t - off];
    buf[cur ^ 1][t] = v;
    cur ^= 1;
    __syncthreads();
  }
  if (gid < n) offs[gid] = v - x;                 // block-local exclusive
  if (t == SCAN_BLK - 1) partials[blockIdx.x] = v; // block total
}

__global__ void k_scan2(int* __restrict__ partials, int* __restrict__ total_out, int nb) {
  __shared__ int buf[2][128];
  int t = threadIdx.x;
  int x = (t < nb) ? partials[t] : 0;
  int cur = 0;
  buf[0][t] = x;
  __syncthreads();
  int v = x;
  for (int off = 1; off < 128; off <<= 1) {
    v = buf[cur][t];
    if (t >= off) v += buf[cur][t - off];
    buf[cur ^ 1][t] = v;
    cur ^= 1;
    __syncthreads();
  }
  if (t < nb) partials[t] = v - x;   // exclusive
  if (t == 127) *total_out = v;      // grand total -> offs[N]
}

__global__ void k_scan3(int* __restrict__ offs, int* __restrict__ cursor,
                        const int* __restrict__ partials, int n) {
  int gid = blockIdx.x * SCAN_BLK + threadIdx.x;
  if (gid < n) {
    int v = offs[gid] + partials[blockIdx.x];
    offs[gid] = v;
    cursor[gid] = v;  // fill cursor copy
  }
}

__global__ void k_fill(const int* __restrict__ erow, const int* __restrict__ ecol,
                       const float* __restrict__ dinv, int* __restrict__ cursor,
                       int2* __restrict__ adj, int n) {
  int e = blockIdx.x * blockDim.x + threadIdx.x;
  if (e < n) {
    int r = erow[e], c = ecol[e];
    int pos = atomicAdd(&cursor[c], 1);
    adj[pos] = make_int2(r, __float_as_int(dinv[r] * dinv[c]));
  }
}

// ---------------- GEMM: C[n,128] = X[n,128] @ W[128,128] ----------------
// 128x128 tile per block, 256 threads, 8x8 register tile (4+4 quadrant split),
// k-step 8, X staged transposed.

__global__ __launch_bounds__(256) void k_gemm128(const float* __restrict__ X,
                                                 const float* __restrict__ W,
                                                 float* __restrict__ C, int n) {
  __shared__ __align__(16) float Xs[8][128];  // Xs[k][m]
  __shared__ __align__(16) float Ws[8][128];  // Ws[k][nn]
  int t = threadIdx.x;
  int tx = t & 15, ty = t >> 4;  // 16 x 16 thread grid
  int row0 = blockIdx.x * 128;
  float acc[8][8] = {};
  for (int k0 = 0; k0 < 128; k0 += 8) {
    {
      int r = t >> 1, kq = t & 1;  // 128 rows x 2 float4
      int gr = row0 + r;
      float4 v = make_float4(0.f, 0.f, 0.f, 0.f);
      if (gr < n) v = *reinterpret_cast<const float4*>(&X[(size_t)gr * 128 + k0 + kq * 4]);
      Xs[kq * 4 + 0][r] = v.x;
      Xs[kq * 4 + 1][r] = v.y;
      Xs[kq * 4 + 2][r] = v.z;
      Xs[kq * 4 + 3][r] = v.w;
    }
    {
      int kk = t >> 5, cq = t & 31;  // 8 k-rows x 32 float4
      float4 v = *reinterpret_cast<const float4*>(&W[(size_t)(k0 + kk) * 128 + cq * 4]);
      *reinterpret_cast<float4*>(&Ws[kk][cq * 4]) = v;
    }
    __syncthreads();
#pragma unroll
    for (int kk = 0; kk < 8; ++kk) {
      float4 a0 = *reinterpret_cast<const float4*>(&Xs[kk][ty * 4]);
      float4 a1 = *reinterpret_cast<const float4*>(&Xs[kk][64 + ty * 4]);
      float4 b0 = *reinterpret_cast<const float4*>(&Ws[kk][tx * 4]);
      float4 b1 = *reinterpret_cast<const float4*>(&Ws[kk][64 + tx * 4]);
      float av[8] = {a0.x, a0.y, a0.z, a0.w, a1.x, a1.y, a1.z, a1.w};
      float bv[8] = {b0.x, b0.y, b0.z, b0.w, b1.x, b1.y, b1.z, b1.w};
#pragma unroll
      for (int i = 0; i < 8; ++i)
#pragma unroll
        for (int j = 0; j < 8; ++j) acc[i][j] = fmaf(av[i], bv[j], acc[i][j]);
    }
    __syncthreads();
  }
#pragma unroll
  for (int i = 0; i < 8; ++i) {
    int gr = row0 + (i < 4 ? ty * 4 + i : 64 + ty * 4 + (i - 4));
    if (gr < n) {
      *reinterpret_cast<float4*>(&C[(size_t)gr * 128 + tx * 4]) =
          make_float4(acc[i][0], acc[i][1], acc[i][2], acc[i][3]);
      *reinterpret_cast<float4*>(&C[(size_t)gr * 128 + 64 + tx * 4]) =
          make_float4(acc[i][4], acc[i][5], acc[i][6], acc[i][7]);
    }
  }
}

// ---------------- Aggregation ----------------
// out[i] = relu?( dinv_i^2*h[i] + sum_e w_e h[src_e] + b ), one wave per node,
// float2 per lane, 8-deep software-pipelined edge loop.

__global__ __launch_bounds__(256) void k_agg(const float* __restrict__ h,
                                             const int* __restrict__ offs,
                                             const int2* __restrict__ adj,
                                             const float* __restrict__ dinv,
                                             const float* __restrict__ bias,
                                             float* __restrict__ out, int n, int do_relu) {
  int wid = (blockIdx.x * blockDim.x + threadIdx.x) >> 6;
  int lane = threadIdx.x & 63;
  if (wid >= n) return;
  float di = dinv[wid];
  float w0 = di * di;
  float2 acc = reinterpret_cast<const float2*>(h + (size_t)wid * 128)[lane];
  acc.x *= w0;
  acc.y *= w0;
  int s = offs[wid], e = offs[wid + 1];
  const int2* ap = adj + s;
  int cnt = e - s;
  int k = 0;
  for (; k + 8 <= cnt; k += 8) {
    int2 a0 = ap[k + 0], a1 = ap[k + 1], a2 = ap[k + 2], a3 = ap[k + 3];
    int2 a4 = ap[k + 4], a5 = ap[k + 5], a6 = ap[k + 6], a7 = ap[k + 7];
    float2 h0 = reinterpret_cast<const float2*>(h + (size_t)a0.x * 128)[lane];
    float2 h1 = reinterpret_cast<const float2*>(h + (size_t)a1.x * 128)[lane];
    float2 h2 = reinterpret_cast<const float2*>(h + (size_t)a2.x * 128)[lane];
    float2 h3 = reinterpret_cast<const float2*>(h + (size_t)a3.x * 128)[lane];
    float2 h4 = reinterpret_cast<const float2*>(h + (size_t)a4.x * 128)[lane];
    float2 h5 = reinterpret_cast<const float2*>(h + (size_t)a5.x * 128)[lane];
    float2 h6 = reinterpret_cast<const float2*>(h + (size_t)a6.x * 128)[lane];
    float2 h7 = reinterpret_cast<const float2*>(h + (size_t)a7.x * 128)[lane];
    float w;
    w = __int_as_float(a0.y); acc.x = fmaf(w, h0.x, acc.x); acc.y = fmaf(w, h0.y, acc.y);
    w = __int_as_float(a1.y); acc.x = fmaf(w, h1.x, acc.x); acc.y = fmaf(w, h1.y, acc.y);
    w = __int_as_float(a2.y); acc.x = fmaf(w, h2.x, acc.x); acc.y = fmaf(w, h2.y, acc.y);
    w = __int_as_float(a3.y); acc.x = fmaf(w, h3.x, acc.x); acc.y = fmaf(w, h3.y, acc.y);
    w = __int_as_float(a4.y); acc.x = fmaf(w, h4.x, acc.x); acc.y = fmaf(w, h4.y, acc.y);
    w = __int_as_float(a5.y); acc.x = fmaf(w, h5.x, acc.x); acc.y = fmaf(w, h5.y, acc.y);
    w = __int_as_float(a6.y); acc.x = fmaf(w, h6.x, acc.x); acc.y = fmaf(w, h6.y, acc.y);
    w = __int_as_float(a7.y); acc.x = fmaf(w, h7.x, acc.x); acc.y = fmaf(w, h7.y, acc.y);
  }
  for (; k < cnt; ++k) {
    int2 a = ap[k];
    float2 hv = reinterpret_cast<const float2*>(h + (size_t)a.x * 128)[lane];
    float w = __int_as_float(a.y);
    acc.x = fmaf(w, hv.x, acc.x);
    acc.y = fmaf(w, hv.y, acc.y);
  }
  float2 b = reinterpret_cast<const float2*>(bias)[lane];
  acc.x += b.x;
  acc.y += b.y;
  if (do_relu) {
    acc.x = fmaxf(acc.x, 0.f);
    acc.y = fmaxf(acc.y, 0.f);
  }
  reinterpret_cast<float2*>(out + (size_t)wid * 128)[lane] = acc;
}

// ---------------- Output GEMM: out[n,40] = X[n,128] @ W[128,40] + b ----------------

__global__ __launch_bounds__(256) void k_gemm_out(const float* __restrict__ X,
                                                  const float* __restrict__ W,
                                                  const float* __restrict__ b,
                                                  float* __restrict__ out, int n) {
  __shared__ __align__(16) float Xs[32][129];
  __shared__ __align__(16) float Ws[128 * 40];
  int t = threadIdx.x;
  int row0 = blockIdx.x * 32;
#pragma unroll
  for (int j = 0; j < 4; ++j) {
    int f = t + j * 256;          // float4 id, 1024 total
    int r = f >> 5, q = f & 31;   // 32 rows x 32 float4
    float4 v = make_float4(0.f, 0.f, 0.f, 0.f);
    if (row0 + r < n) v = *reinterpret_cast<const float4*>(&X[(size_t)(row0 + r) * 128 + q * 4]);
    Xs[r][q * 4 + 0] = v.x;
    Xs[r][q * 4 + 1] = v.y;
    Xs[r][q * 4 + 2] = v.z;
    Xs[r][q * 4 + 3] = v.w;
  }
#pragma unroll
  for (int j = 0; j < 5; ++j) {
    int f = t + j * 256;          // 1280 float4 = 5120 floats
    reinterpret_cast<float4*>(Ws)[f] = reinterpret_cast<const float4*>(W)[f];
  }
  __syncthreads();
#pragma unroll
  for (int j = 0; j < 5; ++j) {
    int o = t + j * 256;          // 0..1279 = 32 rows x 40 cols
    int r = o / 40, c = o - r * 40;
    if (row0 + r < n) {
      float acc = b[c];
#pragma unroll
      for (int k = 0; k < 128; ++k) acc += Xs[r][k] * Ws[k * 40 + c];
      out[(size_t)(row0 + r) * 40 + c] = acc;
    }
  }
}

// ---------------- launch ----------------

extern "C" void kernel_launch(void* const* d_in, const int* in_sizes, int n_in,
                              void* d_out, int out_size, void* d_ws, size_t ws_size,
                              hipStream_t stream) {
  const float* x = (const float*)d_in[0];
  const int* ei = (const int*)d_in[1];
  const float* W1 = (const float*)d_in[2];
  const float* b1 = (const float*)d_in[3];
  const float* W2 = (const float*)d_in[4];
  const float* b2 = (const float*)d_in[5];
  const float* Wout = (const float*)d_in[6];
  const float* bout = (const float*)d_in[7];
  float* out = (float*)d_out;

  const int N = in_sizes[0] / 128;
  const int E = in_sizes[1] / 2;
  const int* erow = ei;      // edge_index[0] = source j
  const int* ecol = ei + E;  // edge_index[1] = target i

  char* ws = (char*)d_ws;
  size_t off = 0;
  auto alloc = [&](size_t bytes) -> void* {
    void* p = ws + off;
    off = (off + bytes + 255) & ~(size_t)255;
    return p;
  };
  int* counts = (int*)alloc((size_t)N * 4);          // later reused as fill cursor
  int* offs = (int*)alloc((size_t)(N + 1) * 4);
  float* dinv = (float*)alloc((size_t)N * 4);
  int* partials = (int*)alloc(128 * 4);
  int2* adj = (int2*)alloc((size_t)E * 8);
  float* bufA = (float*)alloc((size_t)N * 128 * 4);
  float* bufB = (float*)alloc((size_t)N * 128 * 4);

  hipMemsetAsync(counts, 0, (size_t)N * 4, stream);

  k_hist<<<(E + 255) / 256, 256, 0, stream>>>(ecol, counts, E);
  k_dinv<<<(N + 255) / 256, 256, 0, stream>>>(counts, dinv, N);

  int nb = (N + SCAN_BLK - 1) / SCAN_BLK;  // 98 for N=100000 (<=128 required)
  k_scan1<<<nb, SCAN_BLK, 0, stream>>>(counts, offs, partials, N);
  k_scan2<<<1, 128, 0, stream>>>(partials, offs + N, nb);
  k_scan3<<<nb, SCAN_BLK, 0, stream>>>(offs, counts, partials, N);
  k_fill<<<(E + 255) / 256, 256, 0, stream>>>(erow, ecol, dinv, counts, adj, E);

  int gb = (N + 127) / 128;
  k_gemm128<<<gb, 256, 0, stream>>>(x, W1, bufA, N);
  k_agg<<<(N + 3) / 4, 256, 0, stream>>>(bufA, offs, adj, dinv, b1, bufB, N, 1);
  k_gemm128<<<gb, 256, 0, stream>>>(bufB, W2, bufA, N);
  k_agg<<<(N + 3) / 4, 256, 0, stream>>>(bufA, offs, adj, dinv, b2, bufB, N, 1);
  k_gemm_out<<<(N + 31) / 32, 256, 0, stream>>>(bufB, Wout, bout, out, N);
}

// Round 3
// 562.037 us; speedup vs baseline: 1.2739x; 1.0513x over previous
//
#include <hip/hip_runtime.h>
#include <hip/hip_bf16.h>

#define SCAN_BLK 1024

// ---------------- CSR build ----------------

__global__ void k_hist(const int* __restrict__ col, int* __restrict__ counts, int n) {
  int e = blockIdx.x * blockDim.x + threadIdx.x;
  if (e < n) atomicAdd(&counts[col[e]], 1);
}

__global__ void k_dinv(const int* __restrict__ counts, float* __restrict__ dinv, int n) {
  int i = blockIdx.x * blockDim.x + threadIdx.x;
  if (i < n) dinv[i] = rsqrtf((float)counts[i] + 1.0f);  // +1 self loop, deg>=1 always
}

__global__ void k_scan1(const int* __restrict__ counts, int* __restrict__ offs,
                        int* __restrict__ partials, int n) {
  __shared__ int buf[2][SCAN_BLK];
  int t = threadIdx.x;
  int gid = blockIdx.x * SCAN_BLK + t;
  int x = (gid < n) ? counts[gid] : 0;
  int cur = 0;
  buf[0][t] = x;
  __syncthreads();
  int v = x;
  for (int off = 1; off < SCAN_BLK; off <<= 1) {
    v = buf[cur][t];
    if (t >= off) v += buf[cur][t - off];
    buf[cur ^ 1][t] = v;
    cur ^= 1;
    __syncthreads();
  }
  if (gid < n) offs[gid] = v - x;                 // block-local exclusive
  if (t == SCAN_BLK - 1) partials[blockIdx.x] = v; // block total
}

__global__ void k_scan2(int* __restrict__ partials, int* __restrict__ total_out, int nb) {
  __shared__ int buf[2][128];
  int t = threadIdx.x;
  int x = (t < nb) ? partials[t] : 0;
  int cur = 0;
  buf[0][t] = x;
  __syncthreads();
  int v = x;
  for (int off = 1; off < 128; off <<= 1) {
    v = buf[cur][t];
    if (t >= off) v += buf[cur][t - off];
    buf[cur ^ 1][t] = v;
    cur ^= 1;
    __syncthreads();
  }
  if (t < nb) partials[t] = v - x;   // exclusive
  if (t == 127) *total_out = v;      // grand total -> offs[N]
}

__global__ void k_scan3(int* __restrict__ offs, int* __restrict__ cursor,
                        const int* __restrict__ partials, int n) {
  int gid = blockIdx.x * SCAN_BLK + threadIdx.x;
  if (gid < n) {
    int v = offs[gid] + partials[blockIdx.x];
    offs[gid] = v;
    cursor[gid] = v;  // fill cursor copy
  }
}

__global__ void k_fill(const int* __restrict__ erow, const int* __restrict__ ecol,
                       const float* __restrict__ dinv, int* __restrict__ cursor,
                       int2* __restrict__ adj, int n) {
  int e = blockIdx.x * blockDim.x + threadIdx.x;
  if (e < n) {
    int r = erow[e], c = ecol[e];
    int pos = atomicAdd(&cursor[c], 1);
    adj[pos] = make_int2(r, __float_as_int(dinv[r] * dinv[c]));
  }
}

// ---------------- GEMM: C[n,128] = X[n,128] @ W[128,128] ----------------
// 128x128 tile per block, 256 threads, 8x8 register tile (4+4 quadrant split),
// k-step 8, X staged transposed.

__global__ __launch_bounds__(256) void k_gemm128(const float* __restrict__ X,
                                                 const float* __restrict__ W,
                                                 float* __restrict__ C, int n) {
  __shared__ __align__(16) float Xs[8][128];  // Xs[k][m]
  __shared__ __align__(16) float Ws[8][128];  // Ws[k][nn]
  int t = threadIdx.x;
  int tx = t & 15, ty = t >> 4;  // 16 x 16 thread grid
  int row0 = blockIdx.x * 128;
  float acc[8][8] = {};
  for (int k0 = 0; k0 < 128; k0 += 8) {
    {
      int r = t >> 1, kq = t & 1;  // 128 rows x 2 float4
      int gr = row0 + r;
      float4 v = make_float4(0.f, 0.f, 0.f, 0.f);
      if (gr < n) v = *reinterpret_cast<const float4*>(&X[(size_t)gr * 128 + k0 + kq * 4]);
      Xs[kq * 4 + 0][r] = v.x;
      Xs[kq * 4 + 1][r] = v.y;
      Xs[kq * 4 + 2][r] = v.z;
      Xs[kq * 4 + 3][r] = v.w;
    }
    {
      int kk = t >> 5, cq = t & 31;  // 8 k-rows x 32 float4
      float4 v = *reinterpret_cast<const float4*>(&W[(size_t)(k0 + kk) * 128 + cq * 4]);
      *reinterpret_cast<float4*>(&Ws[kk][cq * 4]) = v;
    }
    __syncthreads();
#pragma unroll
    for (int kk = 0; kk < 8; ++kk) {
      float4 a0 = *reinterpret_cast<const float4*>(&Xs[kk][ty * 4]);
      float4 a1 = *reinterpret_cast<const float4*>(&Xs[kk][64 + ty * 4]);
      float4 b0 = *reinterpret_cast<const float4*>(&Ws[kk][tx * 4]);
      float4 b1 = *reinterpret_cast<const float4*>(&Ws[kk][64 + tx * 4]);
      float av[8] = {a0.x, a0.y, a0.z, a0.w, a1.x, a1.y, a1.z, a1.w};
      float bv[8] = {b0.x, b0.y, b0.z, b0.w, b1.x, b1.y, b1.z, b1.w};
#pragma unroll
      for (int i = 0; i < 8; ++i)
#pragma unroll
        for (int j = 0; j < 8; ++j) acc[i][j] = fmaf(av[i], bv[j], acc[i][j]);
    }
    __syncthreads();
  }
#pragma unroll
  for (int i = 0; i < 8; ++i) {
    int gr = row0 + (i < 4 ? ty * 4 + i : 64 + ty * 4 + (i - 4));
    if (gr < n) {
      *reinterpret_cast<float4*>(&C[(size_t)gr * 128 + tx * 4]) =
          make_float4(acc[i][0], acc[i][1], acc[i][2], acc[i][3]);
      *reinterpret_cast<float4*>(&C[(size_t)gr * 128 + 64 + tx * 4]) =
          make_float4(acc[i][4], acc[i][5], acc[i][6], acc[i][7]);
    }
  }
}

// ---------------- Aggregation ----------------
// out[i] = relu?( dinv_i^2*h[i] + sum_e w_e h[src_e] + b ), one wave per node,
// float2 per lane. Wave-uniform scalars forced to SGPR via readfirstlane so
// adjacency loads become s_load; edge loop padded to multiple of 4 (own row,
// weight 0) so there is NO serial tail; 4-deep register double-buffer.

__global__ __launch_bounds__(256) void k_agg(const float* __restrict__ h,
                                             const int* __restrict__ offs,
                                             const int2* __restrict__ adj,
                                             const float* __restrict__ dinv,
                                             const float* __restrict__ bias,
                                             float* __restrict__ out, int n, int do_relu) {
  int wid = (blockIdx.x * blockDim.x + threadIdx.x) >> 6;
  wid = __builtin_amdgcn_readfirstlane(wid);  // wave-uniform by construction
  int lane = threadIdx.x & 63;
  if (wid >= n) return;
  float di = dinv[wid];
  float w0 = di * di;
  const float2* hv = reinterpret_cast<const float2*>(h);
  float2 acc = hv[(size_t)wid * 64 + lane];
  acc.x *= w0;
  acc.y *= w0;
  int s = offs[wid], e = offs[wid + 1];
  int cnt = e - s;
  const int2* ap = adj + s;
  const int2 pad = make_int2(wid, 0);  // own row, weight 0 (L1-hot, exact)

  int2 am0 = (0 < cnt) ? ap[0] : pad;
  int2 am1 = (1 < cnt) ? ap[1] : pad;
  int2 am2 = (2 < cnt) ? ap[2] : pad;
  int2 am3 = (3 < cnt) ? ap[3] : pad;
  float2 hg0 = hv[(size_t)am0.x * 64 + lane];
  float2 hg1 = hv[(size_t)am1.x * 64 + lane];
  float2 hg2 = hv[(size_t)am2.x * 64 + lane];
  float2 hg3 = hv[(size_t)am3.x * 64 + lane];

  for (int k0 = 0; k0 < cnt; k0 += 4) {
    int k1 = k0 + 4;
    bool more = k1 < cnt;  // wave-uniform
    int2 an0, an1, an2, an3;
    float2 hn0, hn1, hn2, hn3;
    if (more) {
      an0 = (k1 + 0 < cnt) ? ap[k1 + 0] : pad;
      an1 = (k1 + 1 < cnt) ? ap[k1 + 1] : pad;
      an2 = (k1 + 2 < cnt) ? ap[k1 + 2] : pad;
      an3 = (k1 + 3 < cnt) ? ap[k1 + 3] : pad;
      hn0 = hv[(size_t)an0.x * 64 + lane];
      hn1 = hv[(size_t)an1.x * 64 + lane];
      hn2 = hv[(size_t)an2.x * 64 + lane];
      hn3 = hv[(size_t)an3.x * 64 + lane];
    }
    float w;
    w = __int_as_float(am0.y); acc.x = fmaf(w, hg0.x, acc.x); acc.y = fmaf(w, hg0.y, acc.y);
    w = __int_as_float(am1.y); acc.x = fmaf(w, hg1.x, acc.x); acc.y = fmaf(w, hg1.y, acc.y);
    w = __int_as_float(am2.y); acc.x = fmaf(w, hg2.x, acc.x); acc.y = fmaf(w, hg2.y, acc.y);
    w = __int_as_float(am3.y); acc.x = fmaf(w, hg3.x, acc.x); acc.y = fmaf(w, hg3.y, acc.y);
    if (more) {
      am0 = an0; am1 = an1; am2 = an2; am3 = an3;
      hg0 = hn0; hg1 = hn1; hg2 = hn2; hg3 = hn3;
    }
  }

  float2 b = reinterpret_cast<const float2*>(bias)[lane];
  acc.x += b.x;
  acc.y += b.y;
  if (do_relu) {
    acc.x = fmaxf(acc.x, 0.f);
    acc.y = fmaxf(acc.y, 0.f);
  }
  reinterpret_cast<float2*>(out + (size_t)wid * 128)[lane] = acc;
}

// ---------------- Output GEMM: out[n,40] = X[n,128] @ W[128,40] + b ----------------
// 64-row tile, W transposed into LDS, float4 k-chunks; 2 rows x 5 cols/thread.

__global__ __launch_bounds__(256) void k_gemm_out(const float* __restrict__ X,
                                                  const float* __restrict__ W,
                                                  const float* __restrict__ b,
                                                  float* __restrict__ out, int n) {
  __shared__ __align__(16) float Xs[64][132];
  __shared__ __align__(16) float Wt[40][132];  // Wt[c][k]
  int t = threadIdx.x;
  int row0 = blockIdx.x * 64;
#pragma unroll
  for (int j = 0; j < 8; ++j) {
    int f = t + j * 256;          // 2048 float4 = 64 rows x 32 float4
    int r = f >> 5, q = f & 31;
    float4 v = make_float4(0.f, 0.f, 0.f, 0.f);
    if (row0 + r < n) v = *reinterpret_cast<const float4*>(&X[(size_t)(row0 + r) * 128 + q * 4]);
    *reinterpret_cast<float4*>(&Xs[r][q * 4]) = v;
  }
#pragma unroll
  for (int j = 0; j < 20; ++j) {
    int f = t + j * 256;          // 5120 floats of W, coalesced read, transposed write
    int k = f / 40, c = f - k * 40;
    Wt[c][k] = W[f];
  }
  __syncthreads();
  int rg = t >> 3;                // 0..31 -> rows rg*2, rg*2+1
  int cg = t & 7;                 // cols cg*5 .. cg*5+4
  int r0 = rg * 2, r1 = r0 + 1;
  int c0 = cg * 5;
  float acc[2][5] = {};
  for (int k0 = 0; k0 < 128; k0 += 4) {
    float4 x0 = *reinterpret_cast<const float4*>(&Xs[r0][k0]);
    float4 x1 = *reinterpret_cast<const float4*>(&Xs[r1][k0]);
#pragma unroll
    for (int i = 0; i < 5; ++i) {
      float4 wv = *reinterpret_cast<const float4*>(&Wt[c0 + i][k0]);
      acc[0][i] += x0.x * wv.x + x0.y * wv.y + x0.z * wv.z + x0.w * wv.w;
      acc[1][i] += x1.x * wv.x + x1.y * wv.y + x1.z * wv.z + x1.w * wv.w;
    }
  }
#pragma unroll
  for (int i = 0; i < 2; ++i) {
    int gr = row0 + r0 + i;
    if (gr < n) {
#pragma unroll
      for (int j = 0; j < 5; ++j) out[(size_t)gr * 40 + c0 + j] = acc[i][j] + b[c0 + j];
    }
  }
}

// ---------------- launch ----------------

extern "C" void kernel_launch(void* const* d_in, const int* in_sizes, int n_in,
                              void* d_out, int out_size, void* d_ws, size_t ws_size,
                              hipStream_t stream) {
  const float* x = (const float*)d_in[0];
  const int* ei = (const int*)d_in[1];
  const float* W1 = (const float*)d_in[2];
  const float* b1 = (const float*)d_in[3];
  const float* W2 = (const float*)d_in[4];
  const float* b2 = (const float*)d_in[5];
  const float* Wout = (const float*)d_in[6];
  const float* bout = (const float*)d_in[7];
  float* out = (float*)d_out;

  const int N = in_sizes[0] / 128;
  const int E = in_sizes[1] / 2;
  const int* erow = ei;      // edge_index[0] = source j
  const int* ecol = ei + E;  // edge_index[1] = target i

  char* ws = (char*)d_ws;
  size_t off = 0;
  auto alloc = [&](size_t bytes) -> void* {
    void* p = ws + off;
    off = (off + bytes + 255) & ~(size_t)255;
    return p;
  };
  int* counts = (int*)alloc((size_t)N * 4);          // later reused as fill cursor
  int* offs = (int*)alloc((size_t)(N + 1) * 4);
  float* dinv = (float*)alloc((size_t)N * 4);
  int* partials = (int*)alloc(128 * 4);
  int2* adj = (int2*)alloc((size_t)E * 8);
  float* bufA = (float*)alloc((size_t)N * 128 * 4);
  float* bufB = (float*)alloc((size_t)N * 128 * 4);

  hipMemsetAsync(counts, 0, (size_t)N * 4, stream);

  k_hist<<<(E + 255) / 256, 256, 0, stream>>>(ecol, counts, E);
  k_dinv<<<(N + 255) / 256, 256, 0, stream>>>(counts, dinv, N);

  int nb = (N + SCAN_BLK - 1) / SCAN_BLK;  // 98 for N=100000 (<=128 required)
  k_scan1<<<nb, SCAN_BLK, 0, stream>>>(counts, offs, partials, N);
  k_scan2<<<1, 128, 0, stream>>>(partials, offs + N, nb);
  k_scan3<<<nb, SCAN_BLK, 0, stream>>>(offs, counts, partials, N);
  k_fill<<<(E + 255) / 256, 256, 0, stream>>>(erow, ecol, dinv, counts, adj, E);

  int gb = (N + 127) / 128;
  k_gemm128<<<gb, 256, 0, stream>>>(x, W1, bufA, N);
  k_agg<<<(N + 3) / 4, 256, 0, stream>>>(bufA, offs, adj, dinv, b1, bufB, N, 1);
  k_gemm128<<<gb, 256, 0, stream>>>(bufB, W2, bufA, N);
  k_agg<<<(N + 3) / 4, 256, 0, stream>>>(bufA, offs, adj, dinv, b2, bufB, N, 1);
  k_gemm_out<<<(N + 31) / 32, 256, 0, stream>>>(bufB, Wout, bout, out, N);
}

// Round 4
// 459.672 us; speedup vs baseline: 1.5576x; 1.2227x over previous
//
#include <hip/hip_runtime.h>
#include <hip/hip_bf16.h>
#include <hip/hip_fp16.h>

#define SCAN_BLK 1024

struct half4 { __half2 a, b; };  // 8-byte packed 4x fp16

// ---------------- CSR build ----------------

__global__ void k_hist(const int* __restrict__ col, int* __restrict__ counts, int n) {
  int e = blockIdx.x * blockDim.x + threadIdx.x;
  if (e < n) atomicAdd(&counts[col[e]], 1);
}

__global__ void k_dinv(const int* __restrict__ counts, float* __restrict__ dinv, int n) {
  int i = blockIdx.x * blockDim.x + threadIdx.x;
  if (i < n) dinv[i] = rsqrtf((float)counts[i] + 1.0f);  // +1 self loop, deg>=1 always
}

__global__ void k_scan1(const int* __restrict__ counts, int* __restrict__ offs,
                        int* __restrict__ partials, int n) {
  __shared__ int buf[2][SCAN_BLK];
  int t = threadIdx.x;
  int gid = blockIdx.x * SCAN_BLK + t;
  int x = (gid < n) ? counts[gid] : 0;
  int cur = 0;
  buf[0][t] = x;
  __syncthreads();
  int v = x;
  for (int off = 1; off < SCAN_BLK; off <<= 1) {
    v = buf[cur][t];
    if (t >= off) v += buf[cur][t - off];
    buf[cur ^ 1][t] = v;
    cur ^= 1;
    __syncthreads();
  }
  if (gid < n) offs[gid] = v - x;                 // block-local exclusive
  if (t == SCAN_BLK - 1) partials[blockIdx.x] = v; // block total
}

__global__ void k_scan2(int* __restrict__ partials, int* __restrict__ total_out, int nb) {
  __shared__ int buf[2][128];
  int t = threadIdx.x;
  int x = (t < nb) ? partials[t] : 0;
  int cur = 0;
  buf[0][t] = x;
  __syncthreads();
  int v = x;
  for (int off = 1; off < 128; off <<= 1) {
    v = buf[cur][t];
    if (t >= off) v += buf[cur][t - off];
    buf[cur ^ 1][t] = v;
    cur ^= 1;
    __syncthreads();
  }
  if (t < nb) partials[t] = v - x;   // exclusive
  if (t == 127) *total_out = v;      // grand total -> offs[N]
}

__global__ void k_scan3(int* __restrict__ offs, int* __restrict__ cursor,
                        const int* __restrict__ partials, int n) {
  int gid = blockIdx.x * SCAN_BLK + threadIdx.x;
  if (gid < n) {
    int v = offs[gid] + partials[blockIdx.x];
    offs[gid] = v;
    cursor[gid] = v;  // fill cursor copy
  }
}

__global__ void k_fill(const int* __restrict__ erow, const int* __restrict__ ecol,
                       const float* __restrict__ dinv, int* __restrict__ cursor,
                       int2* __restrict__ adj, int n) {
  int e = blockIdx.x * blockDim.x + threadIdx.x;
  if (e < n) {
    int r = erow[e], c = ecol[e];
    int pos = atomicAdd(&cursor[c], 1);
    adj[pos] = make_int2(r, __float_as_int(dinv[r] * dinv[c]));
  }
}

// ---------------- GEMM: H[n,128](fp16) = X[n,128](f32) @ W[128,128](f32) ----------------
// 128x128 tile per block, 256 threads, 8x8 register tile, f32 compute, fp16 store.

__global__ __launch_bounds__(256) void k_gemm128(const float* __restrict__ X,
                                                 const float* __restrict__ W,
                                                 __half* __restrict__ C, int n) {
  __shared__ __align__(16) float Xs[8][128];  // Xs[k][m]
  __shared__ __align__(16) float Ws[8][128];  // Ws[k][nn]
  int t = threadIdx.x;
  int tx = t & 15, ty = t >> 4;  // 16 x 16 thread grid
  int row0 = blockIdx.x * 128;
  float acc[8][8] = {};
  for (int k0 = 0; k0 < 128; k0 += 8) {
    {
      int r = t >> 1, kq = t & 1;  // 128 rows x 2 float4
      int gr = row0 + r;
      float4 v = make_float4(0.f, 0.f, 0.f, 0.f);
      if (gr < n) v = *reinterpret_cast<const float4*>(&X[(size_t)gr * 128 + k0 + kq * 4]);
      Xs[kq * 4 + 0][r] = v.x;
      Xs[kq * 4 + 1][r] = v.y;
      Xs[kq * 4 + 2][r] = v.z;
      Xs[kq * 4 + 3][r] = v.w;
    }
    {
      int kk = t >> 5, cq = t & 31;  // 8 k-rows x 32 float4
      float4 v = *reinterpret_cast<const float4*>(&W[(size_t)(k0 + kk) * 128 + cq * 4]);
      *reinterpret_cast<float4*>(&Ws[kk][cq * 4]) = v;
    }
    __syncthreads();
#pragma unroll
    for (int kk = 0; kk < 8; ++kk) {
      float4 a0 = *reinterpret_cast<const float4*>(&Xs[kk][ty * 4]);
      float4 a1 = *reinterpret_cast<const float4*>(&Xs[kk][64 + ty * 4]);
      float4 b0 = *reinterpret_cast<const float4*>(&Ws[kk][tx * 4]);
      float4 b1 = *reinterpret_cast<const float4*>(&Ws[kk][64 + tx * 4]);
      float av[8] = {a0.x, a0.y, a0.z, a0.w, a1.x, a1.y, a1.z, a1.w};
      float bv[8] = {b0.x, b0.y, b0.z, b0.w, b1.x, b1.y, b1.z, b1.w};
#pragma unroll
      for (int i = 0; i < 8; ++i)
#pragma unroll
        for (int j = 0; j < 8; ++j) acc[i][j] = fmaf(av[i], bv[j], acc[i][j]);
    }
    __syncthreads();
  }
#pragma unroll
  for (int i = 0; i < 8; ++i) {
    int gr = row0 + (i < 4 ? ty * 4 + i : 64 + ty * 4 + (i - 4));
    if (gr < n) {
      half4* cp = reinterpret_cast<half4*>(C + (size_t)gr * 128);
      half4 q0, q1;
      q0.a = __floats2half2_rn(acc[i][0], acc[i][1]);
      q0.b = __floats2half2_rn(acc[i][2], acc[i][3]);
      q1.a = __floats2half2_rn(acc[i][4], acc[i][5]);
      q1.b = __floats2half2_rn(acc[i][6], acc[i][7]);
      cp[tx] = q0;        // cols tx*4 .. tx*4+3
      cp[16 + tx] = q1;   // cols 64+tx*4 ..
    }
  }
}

// ---------------- Aggregation ----------------
// out[i] = relu?( dinv_i^2*h[i] + sum_e w_e h[src_e] + b ), one wave per node,
// fp16 h gathered as __half2 (4 B/lane), f32 accumulate, f32 output.

__global__ __launch_bounds__(256) void k_agg(const __half* __restrict__ h,
                                             const int* __restrict__ offs,
                                             const int2* __restrict__ adj,
                                             const float* __restrict__ dinv,
                                             const float* __restrict__ bias,
                                             float* __restrict__ out, int n, int do_relu) {
  int wid = (blockIdx.x * blockDim.x + threadIdx.x) >> 6;
  wid = __builtin_amdgcn_readfirstlane(wid);  // wave-uniform by construction
  int lane = threadIdx.x & 63;
  if (wid >= n) return;
  const __half2* hv = reinterpret_cast<const __half2*>(h);
  float di = dinv[wid];
  float w0 = di * di;
  float2 acc = __half22float2(hv[(size_t)wid * 64 + lane]);
  acc.x *= w0;
  acc.y *= w0;
  int s = offs[wid], e = offs[wid + 1];
  int cnt = e - s;
  const int2* ap = adj + s;
  const int2 pad = make_int2(wid, 0);  // own row, weight 0 (L1-hot, exact)

  int2 am0 = (0 < cnt) ? ap[0] : pad;
  int2 am1 = (1 < cnt) ? ap[1] : pad;
  int2 am2 = (2 < cnt) ? ap[2] : pad;
  int2 am3 = (3 < cnt) ? ap[3] : pad;
  __half2 hg0 = hv[(size_t)am0.x * 64 + lane];
  __half2 hg1 = hv[(size_t)am1.x * 64 + lane];
  __half2 hg2 = hv[(size_t)am2.x * 64 + lane];
  __half2 hg3 = hv[(size_t)am3.x * 64 + lane];

  for (int k0 = 0; k0 < cnt; k0 += 4) {
    int k1 = k0 + 4;
    bool more = k1 < cnt;  // wave-uniform
    int2 an0, an1, an2, an3;
    __half2 hn0, hn1, hn2, hn3;
    if (more) {
      an0 = (k1 + 0 < cnt) ? ap[k1 + 0] : pad;
      an1 = (k1 + 1 < cnt) ? ap[k1 + 1] : pad;
      an2 = (k1 + 2 < cnt) ? ap[k1 + 2] : pad;
      an3 = (k1 + 3 < cnt) ? ap[k1 + 3] : pad;
      hn0 = hv[(size_t)an0.x * 64 + lane];
      hn1 = hv[(size_t)an1.x * 64 + lane];
      hn2 = hv[(size_t)an2.x * 64 + lane];
      hn3 = hv[(size_t)an3.x * 64 + lane];
    }
    float w;
    float2 f;
    w = __int_as_float(am0.y); f = __half22float2(hg0);
    acc.x = fmaf(w, f.x, acc.x); acc.y = fmaf(w, f.y, acc.y);
    w = __int_as_float(am1.y); f = __half22float2(hg1);
    acc.x = fmaf(w, f.x, acc.x); acc.y = fmaf(w, f.y, acc.y);
    w = __int_as_float(am2.y); f = __half22float2(hg2);
    acc.x = fmaf(w, f.x, acc.x); acc.y = fmaf(w, f.y, acc.y);
    w = __int_as_float(am3.y); f = __half22float2(hg3);
    acc.x = fmaf(w, f.x, acc.x); acc.y = fmaf(w, f.y, acc.y);
    if (more) {
      am0 = an0; am1 = an1; am2 = an2; am3 = an3;
      hg0 = hn0; hg1 = hn1; hg2 = hn2; hg3 = hn3;
    }
  }

  float2 b = reinterpret_cast<const float2*>(bias)[lane];
  acc.x += b.x;
  acc.y += b.y;
  if (do_relu) {
    acc.x = fmaxf(acc.x, 0.f);
    acc.y = fmaxf(acc.y, 0.f);
  }
  reinterpret_cast<float2*>(out + (size_t)wid * 128)[lane] = acc;
}

// ---------------- Output GEMM: out[n,40] = X[n,128] @ W[128,40] + b ----------------
// 64-row tile, W transposed into LDS, float4 k-chunks; 2 rows x 5 cols/thread.

__global__ __launch_bounds__(256) void k_gemm_out(const float* __restrict__ X,
                                                  const float* __restrict__ W,
                                                  const float* __restrict__ b,
                                                  float* __restrict__ out, int n) {
  __shared__ __align__(16) float Xs[64][132];
  __shared__ __align__(16) float Wt[40][132];  // Wt[c][k]
  int t = threadIdx.x;
  int row0 = blockIdx.x * 64;
#pragma unroll
  for (int j = 0; j < 8; ++j) {
    int f = t + j * 256;          // 2048 float4 = 64 rows x 32 float4
    int r = f >> 5, q = f & 31;
    float4 v = make_float4(0.f, 0.f, 0.f, 0.f);
    if (row0 + r < n) v = *reinterpret_cast<const float4*>(&X[(size_t)(row0 + r) * 128 + q * 4]);
    *reinterpret_cast<float4*>(&Xs[r][q * 4]) = v;
  }
#pragma unroll
  for (int j = 0; j < 20; ++j) {
    int f = t + j * 256;          // 5120 floats of W, coalesced read, transposed write
    int k = f / 40, c = f - k * 40;
    Wt[c][k] = W[f];
  }
  __syncthreads();
  int rg = t >> 3;                // 0..31 -> rows rg*2, rg*2+1
  int cg = t & 7;                 // cols cg*5 .. cg*5+4
  int r0 = rg * 2, r1 = r0 + 1;
  int c0 = cg * 5;
  float acc[2][5] = {};
  for (int k0 = 0; k0 < 128; k0 += 4) {
    float4 x0 = *reinterpret_cast<const float4*>(&Xs[r0][k0]);
    float4 x1 = *reinterpret_cast<const float4*>(&Xs[r1][k0]);
#pragma unroll
    for (int i = 0; i < 5; ++i) {
      float4 wv = *reinterpret_cast<const float4*>(&Wt[c0 + i][k0]);
      acc[0][i] += x0.x * wv.x + x0.y * wv.y + x0.z * wv.z + x0.w * wv.w;
      acc[1][i] += x1.x * wv.x + x1.y * wv.y + x1.z * wv.z + x1.w * wv.w;
    }
  }
#pragma unroll
  for (int i = 0; i < 2; ++i) {
    int gr = row0 + r0 + i;
    if (gr < n) {
#pragma unroll
      for (int j = 0; j < 5; ++j) out[(size_t)gr * 40 + c0 + j] = acc[i][j] + b[c0 + j];
    }
  }
}

// ---------------- launch ----------------

extern "C" void kernel_launch(void* const* d_in, const int* in_sizes, int n_in,
                              void* d_out, int out_size, void* d_ws, size_t ws_size,
                              hipStream_t stream) {
  const float* x = (const float*)d_in[0];
  const int* ei = (const int*)d_in[1];
  const float* W1 = (const float*)d_in[2];
  const float* b1 = (const float*)d_in[3];
  const float* W2 = (const float*)d_in[4];
  const float* b2 = (const float*)d_in[5];
  const float* Wout = (const float*)d_in[6];
  const float* bout = (const float*)d_in[7];
  float* out = (float*)d_out;

  const int N = in_sizes[0] / 128;
  const int E = in_sizes[1] / 2;
  const int* erow = ei;      // edge_index[0] = source j
  const int* ecol = ei + E;  // edge_index[1] = target i

  char* ws = (char*)d_ws;
  size_t off = 0;
  auto alloc = [&](size_t bytes) -> void* {
    void* p = ws + off;
    off = (off + bytes + 255) & ~(size_t)255;
    return p;
  };
  int* counts = (int*)alloc((size_t)N * 4);          // later reused as fill cursor
  int* offs = (int*)alloc((size_t)(N + 1) * 4);
  float* dinv = (float*)alloc((size_t)N * 4);
  int* partials = (int*)alloc(128 * 4);
  int2* adj = (int2*)alloc((size_t)E * 8);
  __half* bufH = (__half*)alloc((size_t)N * 128 * 2);  // fp16 h (gemm output)
  float* bufB = (float*)alloc((size_t)N * 128 * 4);    // f32 agg output

  hipMemsetAsync(counts, 0, (size_t)N * 4, stream);

  k_hist<<<(E + 255) / 256, 256, 0, stream>>>(ecol, counts, E);
  k_dinv<<<(N + 255) / 256, 256, 0, stream>>>(counts, dinv, N);

  int nb = (N + SCAN_BLK - 1) / SCAN_BLK;  // 98 for N=100000 (<=128 required)
  k_scan1<<<nb, SCAN_BLK, 0, stream>>>(counts, offs, partials, N);
  k_scan2<<<1, 128, 0, stream>>>(partials, offs + N, nb);
  k_scan3<<<nb, SCAN_BLK, 0, stream>>>(offs, counts, partials, N);
  k_fill<<<(E + 255) / 256, 256, 0, stream>>>(erow, ecol, dinv, counts, adj, E);

  int gb = (N + 127) / 128;
  k_gemm128<<<gb, 256, 0, stream>>>(x, W1, bufH, N);
  k_agg<<<(N + 3) / 4, 256, 0, stream>>>(bufH, offs, adj, dinv, b1, bufB, N, 1);
  k_gemm128<<<gb, 256, 0, stream>>>(bufB, W2, bufH, N);
  k_agg<<<(N + 3) / 4, 256, 0, stream>>>(bufH, offs, adj, dinv, b2, bufB, N, 1);
  k_gemm_out<<<(N + 31) / 32, 256, 0, stream>>>(bufB, Wout, bout, out, N);
}

// Round 5
// 454.963 us; speedup vs baseline: 1.5737x; 1.0104x over previous
//
#include <hip/hip_runtime.h>
#include <hip/hip_bf16.h>
#include <hip/hip_fp16.h>

#define SCAN_BLK 1024

struct half4 { __half2 a, b; };  // 8-byte packed 4x fp16

// ---------------- CSR build ----------------

// counts + per-edge rank (atomicAdd return) in one pass
__global__ void k_hist(const int* __restrict__ col, int* __restrict__ counts,
                       int* __restrict__ rank, int n) {
  int e = blockIdx.x * blockDim.x + threadIdx.x;
  if (e < n) rank[e] = atomicAdd(&counts[col[e]], 1);
}

__global__ void k_dinv(const int* __restrict__ counts, float* __restrict__ dinv, int n) {
  int i = blockIdx.x * blockDim.x + threadIdx.x;
  if (i < n) dinv[i] = rsqrtf((float)counts[i] + 1.0f);  // +1 self loop, deg>=1 always
}

__global__ void k_scan1(const int* __restrict__ counts, int* __restrict__ offs,
                        int* __restrict__ partials, int n) {
  __shared__ int buf[2][SCAN_BLK];
  int t = threadIdx.x;
  int gid = blockIdx.x * SCAN_BLK + t;
  int x = (gid < n) ? counts[gid] : 0;
  int cur = 0;
  buf[0][t] = x;
  __syncthreads();
  int v = x;
  for (int off = 1; off < SCAN_BLK; off <<= 1) {
    v = buf[cur][t];
    if (t >= off) v += buf[cur][t - off];
    buf[cur ^ 1][t] = v;
    cur ^= 1;
    __syncthreads();
  }
  if (gid < n) offs[gid] = v - x;                 // block-local exclusive
  if (t == SCAN_BLK - 1) partials[blockIdx.x] = v; // block total
}

__global__ void k_scan2(int* __restrict__ partials, int* __restrict__ total_out, int nb) {
  __shared__ int buf[2][128];
  int t = threadIdx.x;
  int x = (t < nb) ? partials[t] : 0;
  int cur = 0;
  buf[0][t] = x;
  __syncthreads();
  int v = x;
  for (int off = 1; off < 128; off <<= 1) {
    v = buf[cur][t];
    if (t >= off) v += buf[cur][t - off];
    buf[cur ^ 1][t] = v;
    cur ^= 1;
    __syncthreads();
  }
  if (t < nb) partials[t] = v - x;   // exclusive
  if (t == 127) *total_out = v;      // grand total -> offs[N]
}

__global__ void k_scan3(int* __restrict__ offs, const int* __restrict__ partials, int n) {
  int gid = blockIdx.x * SCAN_BLK + threadIdx.x;
  if (gid < n) offs[gid] += partials[blockIdx.x];
}

// scatter src index only; position precomputed (no atomic), grid-stride for MLP
__global__ void k_fill(const int* __restrict__ erow, const int* __restrict__ ecol,
                       const int* __restrict__ rank, const int* __restrict__ offs,
                       int* __restrict__ adj, int n) {
  int stride = gridDim.x * blockDim.x;
  for (int e = blockIdx.x * blockDim.x + threadIdx.x; e < n; e += stride) {
    int c = ecol[e];
    adj[offs[c] + rank[e]] = erow[e];
  }
}

// ---------------- GEMM: H[n,128](fp16) = X[n,128](f32) @ W[128,128](f32) ----------------
// 128x128 tile per block, 256 threads, 8x8 register tile, f32 compute, fp16 store.

__global__ __launch_bounds__(256) void k_gemm128(const float* __restrict__ X,
                                                 const float* __restrict__ W,
                                                 __half* __restrict__ C, int n) {
  __shared__ __align__(16) float Xs[8][128];  // Xs[k][m]
  __shared__ __align__(16) float Ws[8][128];  // Ws[k][nn]
  int t = threadIdx.x;
  int tx = t & 15, ty = t >> 4;  // 16 x 16 thread grid
  int row0 = blockIdx.x * 128;
  float acc[8][8] = {};
  for (int k0 = 0; k0 < 128; k0 += 8) {
    {
      int r = t >> 1, kq = t & 1;  // 128 rows x 2 float4
      int gr = row0 + r;
      float4 v = make_float4(0.f, 0.f, 0.f, 0.f);
      if (gr < n) v = *reinterpret_cast<const float4*>(&X[(size_t)gr * 128 + k0 + kq * 4]);
      Xs[kq * 4 + 0][r] = v.x;
      Xs[kq * 4 + 1][r] = v.y;
      Xs[kq * 4 + 2][r] = v.z;
      Xs[kq * 4 + 3][r] = v.w;
    }
    {
      int kk = t >> 5, cq = t & 31;  // 8 k-rows x 32 float4
      float4 v = *reinterpret_cast<const float4*>(&W[(size_t)(k0 + kk) * 128 + cq * 4]);
      *reinterpret_cast<float4*>(&Ws[kk][cq * 4]) = v;
    }
    __syncthreads();
#pragma unroll
    for (int kk = 0; kk < 8; ++kk) {
      float4 a0 = *reinterpret_cast<const float4*>(&Xs[kk][ty * 4]);
      float4 a1 = *reinterpret_cast<const float4*>(&Xs[kk][64 + ty * 4]);
      float4 b0 = *reinterpret_cast<const float4*>(&Ws[kk][tx * 4]);
      float4 b1 = *reinterpret_cast<const float4*>(&Ws[kk][64 + tx * 4]);
      float av[8] = {a0.x, a0.y, a0.z, a0.w, a1.x, a1.y, a1.z, a1.w};
      float bv[8] = {b0.x, b0.y, b0.z, b0.w, b1.x, b1.y, b1.z, b1.w};
#pragma unroll
      for (int i = 0; i < 8; ++i)
#pragma unroll
        for (int j = 0; j < 8; ++j) acc[i][j] = fmaf(av[i], bv[j], acc[i][j]);
    }
    __syncthreads();
  }
#pragma unroll
  for (int i = 0; i < 8; ++i) {
    int gr = row0 + (i < 4 ? ty * 4 + i : 64 + ty * 4 + (i - 4));
    if (gr < n) {
      half4* cp = reinterpret_cast<half4*>(C + (size_t)gr * 128);
      half4 q0, q1;
      q0.a = __floats2half2_rn(acc[i][0], acc[i][1]);
      q0.b = __floats2half2_rn(acc[i][2], acc[i][3]);
      q1.a = __floats2half2_rn(acc[i][4], acc[i][5]);
      q1.b = __floats2half2_rn(acc[i][6], acc[i][7]);
      cp[tx] = q0;        // cols tx*4 .. tx*4+3
      cp[16 + tx] = q1;   // cols 64+tx*4 ..
    }
  }
}

// ---------------- Aggregation ----------------
// out[i] = relu?( dinv_i^2*h[i] + sum_e dinv_src*dinv_i * h[src] + b ), one wave
// per node, fp16 h gathered as __half2, f32 accumulate. Adjacency is 4B src
// index (scalar loads); weight computed from dinv (scalar loads); 8-deep
// register double-buffer, no serial tail (invalid slots -> own row, w=0).

__global__ __launch_bounds__(256) void k_agg(const __half* __restrict__ h,
                                             const int* __restrict__ offs,
                                             const int* __restrict__ adj,
                                             const float* __restrict__ dinv,
                                             const float* __restrict__ bias,
                                             float* __restrict__ out, int n, int do_relu) {
  int wid = (blockIdx.x * blockDim.x + threadIdx.x) >> 6;
  wid = __builtin_amdgcn_readfirstlane(wid);  // wave-uniform by construction
  int lane = threadIdx.x & 63;
  if (wid >= n) return;
  const __half2* hv = reinterpret_cast<const __half2*>(h);
  float ddst = dinv[wid];
  float w0 = ddst * ddst;
  float2 acc = __half22float2(hv[(size_t)wid * 64 + lane]);
  acc.x *= w0;
  acc.y *= w0;
  int s = offs[wid], e = offs[wid + 1];
  int cnt = e - s;
  const int* ap = adj + s;

  float wm[8];
  __half2 hg[8];
#pragma unroll
  for (int j = 0; j < 8; ++j) {
    bool v = j < cnt;
    int src = v ? ap[j] : wid;
    wm[j] = v ? dinv[src] * ddst : 0.f;
    hg[j] = hv[(size_t)src * 64 + lane];
  }
  for (int k0 = 0; k0 < cnt; k0 += 8) {
    int k1 = k0 + 8;
    bool more = k1 < cnt;  // wave-uniform
    float wn[8];
    __half2 hn[8];
    if (more) {
#pragma unroll
      for (int j = 0; j < 8; ++j) {
        bool v = k1 + j < cnt;
        int src = v ? ap[k1 + j] : wid;
        wn[j] = v ? dinv[src] * ddst : 0.f;
        hn[j] = hv[(size_t)src * 64 + lane];
      }
    }
#pragma unroll
    for (int j = 0; j < 8; ++j) {
      float2 f = __half22float2(hg[j]);
      acc.x = fmaf(wm[j], f.x, acc.x);
      acc.y = fmaf(wm[j], f.y, acc.y);
    }
    if (more) {
#pragma unroll
      for (int j = 0; j < 8; ++j) {
        wm[j] = wn[j];
        hg[j] = hn[j];
      }
    }
  }

  float2 b = reinterpret_cast<const float2*>(bias)[lane];
  acc.x += b.x;
  acc.y += b.y;
  if (do_relu) {
    acc.x = fmaxf(acc.x, 0.f);
    acc.y = fmaxf(acc.y, 0.f);
  }
  reinterpret_cast<float2*>(out + (size_t)wid * 128)[lane] = acc;
}

// ---------------- Output GEMM: out[n,40] = X[n,128] @ W[128,40] + b ----------------
// 64-row tile, W transposed into LDS, float4 k-chunks; 2 rows x 5 cols/thread.

__global__ __launch_bounds__(256) void k_gemm_out(const float* __restrict__ X,
                                                  const float* __restrict__ W,
                                                  const float* __restrict__ b,
                                                  float* __restrict__ out, int n) {
  __shared__ __align__(16) float Xs[64][132];
  __shared__ __align__(16) float Wt[40][132];  // Wt[c][k]
  int t = threadIdx.x;
  int row0 = blockIdx.x * 64;
#pragma unroll
  for (int j = 0; j < 8; ++j) {
    int f = t + j * 256;          // 2048 float4 = 64 rows x 32 float4
    int r = f >> 5, q = f & 31;
    float4 v = make_float4(0.f, 0.f, 0.f, 0.f);
    if (row0 + r < n) v = *reinterpret_cast<const float4*>(&X[(size_t)(row0 + r) * 128 + q * 4]);
    *reinterpret_cast<float4*>(&Xs[r][q * 4]) = v;
  }
#pragma unroll
  for (int j = 0; j < 20; ++j) {
    int f = t + j * 256;          // 5120 floats of W, coalesced read, transposed write
    int k = f / 40, c = f - k * 40;
    Wt[c][k] = W[f];
  }
  __syncthreads();
  int rg = t >> 3;                // 0..31 -> rows rg*2, rg*2+1
  int cg = t & 7;                 // cols cg*5 .. cg*5+4
  int r0 = rg * 2, r1 = r0 + 1;
  int c0 = cg * 5;
  float acc[2][5] = {};
  for (int k0 = 0; k0 < 128; k0 += 4) {
    float4 x0 = *reinterpret_cast<const float4*>(&Xs[r0][k0]);
    float4 x1 = *reinterpret_cast<const float4*>(&Xs[r1][k0]);
#pragma unroll
    for (int i = 0; i < 5; ++i) {
      float4 wv = *reinterpret_cast<const float4*>(&Wt[c0 + i][k0]);
      acc[0][i] += x0.x * wv.x + x0.y * wv.y + x0.z * wv.z + x0.w * wv.w;
      acc[1][i] += x1.x * wv.x + x1.y * wv.y + x1.z * wv.z + x1.w * wv.w;
    }
  }
#pragma unroll
  for (int i = 0; i < 2; ++i) {
    int gr = row0 + r0 + i;
    if (gr < n) {
#pragma unroll
      for (int j = 0; j < 5; ++j) out[(size_t)gr * 40 + c0 + j] = acc[i][j] + b[c0 + j];
    }
  }
}

// ---------------- launch ----------------

extern "C" void kernel_launch(void* const* d_in, const int* in_sizes, int n_in,
                              void* d_out, int out_size, void* d_ws, size_t ws_size,
                              hipStream_t stream) {
  const float* x = (const float*)d_in[0];
  const int* ei = (const int*)d_in[1];
  const float* W1 = (const float*)d_in[2];
  const float* b1 = (const float*)d_in[3];
  const float* W2 = (const float*)d_in[4];
  const float* b2 = (const float*)d_in[5];
  const float* Wout = (const float*)d_in[6];
  const float* bout = (const float*)d_in[7];
  float* out = (float*)d_out;

  const int N = in_sizes[0] / 128;
  const int E = in_sizes[1] / 2;
  const int* erow = ei;      // edge_index[0] = source j
  const int* ecol = ei + E;  // edge_index[1] = target i

  char* ws = (char*)d_ws;
  size_t off = 0;
  auto alloc = [&](size_t bytes) -> void* {
    void* p = ws + off;
    off = (off + bytes + 255) & ~(size_t)255;
    return p;
  };
  int* counts = (int*)alloc((size_t)N * 4);
  int* offs = (int*)alloc((size_t)(N + 1) * 4);
  float* dinv = (float*)alloc((size_t)N * 4);
  int* partials = (int*)alloc(128 * 4);
  int* rank = (int*)alloc((size_t)E * 4);
  int* adj = (int*)alloc((size_t)(E + 8) * 4);         // +8 pad: agg prefetch may over-read
  __half* bufH = (__half*)alloc((size_t)N * 128 * 2);  // fp16 h (gemm output)
  float* bufB = (float*)alloc((size_t)N * 128 * 4);    // f32 agg output

  hipMemsetAsync(counts, 0, (size_t)N * 4, stream);

  k_hist<<<(E + 255) / 256, 256, 0, stream>>>(ecol, counts, rank, E);
  k_dinv<<<(N + 255) / 256, 256, 0, stream>>>(counts, dinv, N);

  int nb = (N + SCAN_BLK - 1) / SCAN_BLK;  // 98 for N=100000 (<=128 required)
  k_scan1<<<nb, SCAN_BLK, 0, stream>>>(counts, offs, partials, N);
  k_scan2<<<1, 128, 0, stream>>>(partials, offs + N, nb);
  k_scan3<<<nb, SCAN_BLK, 0, stream>>>(offs, partials, N);
  k_fill<<<1024, 256, 0, stream>>>(erow, ecol, rank, offs, adj, E);

  int gb = (N + 127) / 128;
  k_gemm128<<<gb, 256, 0, stream>>>(x, W1, bufH, N);
  k_agg<<<(N + 3) / 4, 256, 0, stream>>>(bufH, offs, adj, dinv, b1, bufB, N, 1);
  k_gemm128<<<gb, 256, 0, stream>>>(bufB, W2, bufH, N);
  k_agg<<<(N + 3) / 4, 256, 0, stream>>>(bufH, offs, adj, dinv, b2, bufB, N, 1);
  k_gemm_out<<<(N + 31) / 32, 256, 0, stream>>>(bufB, Wout, bout, out, N);
}

// Round 6
// 350.487 us; speedup vs baseline: 2.0428x; 1.2981x over previous
//
#include <hip/hip_runtime.h>
#include <hip/hip_bf16.h>
#include <hip/hip_fp16.h>

#define SCAN_BLK 1024

typedef _Float16 f16x8 __attribute__((ext_vector_type(8)));
typedef float f32x4 __attribute__((ext_vector_type(4)));

// ---------------- CSR build ----------------

// counts + per-edge rank (atomicAdd return) in one pass
__global__ void k_hist(const int* __restrict__ col, int* __restrict__ counts,
                       int* __restrict__ rank, int n) {
  int e = blockIdx.x * blockDim.x + threadIdx.x;
  if (e < n) rank[e] = atomicAdd(&counts[col[e]], 1);
}

__global__ void k_dinv(const int* __restrict__ counts, float* __restrict__ dinv, int n) {
  int i = blockIdx.x * blockDim.x + threadIdx.x;
  if (i < n) dinv[i] = rsqrtf((float)counts[i] + 1.0f);  // +1 self loop, deg>=1 always
}

__global__ void k_scan1(const int* __restrict__ counts, int* __restrict__ offs,
                        int* __restrict__ partials, int n) {
  __shared__ int buf[2][SCAN_BLK];
  int t = threadIdx.x;
  int gid = blockIdx.x * SCAN_BLK + t;
  int x = (gid < n) ? counts[gid] : 0;
  int cur = 0;
  buf[0][t] = x;
  __syncthreads();
  int v = x;
  for (int off = 1; off < SCAN_BLK; off <<= 1) {
    v = buf[cur][t];
    if (t >= off) v += buf[cur][t - off];
    buf[cur ^ 1][t] = v;
    cur ^= 1;
    __syncthreads();
  }
  if (gid < n) offs[gid] = v - x;                 // block-local exclusive
  if (t == SCAN_BLK - 1) partials[blockIdx.x] = v; // block total
}

__global__ void k_scan2(int* __restrict__ partials, int* __restrict__ total_out, int nb) {
  __shared__ int buf[2][128];
  int t = threadIdx.x;
  int x = (t < nb) ? partials[t] : 0;
  int cur = 0;
  buf[0][t] = x;
  __syncthreads();
  int v = x;
  for (int off = 1; off < 128; off <<= 1) {
    v = buf[cur][t];
    if (t >= off) v += buf[cur][t - off];
    buf[cur ^ 1][t] = v;
    cur ^= 1;
    __syncthreads();
  }
  if (t < nb) partials[t] = v - x;   // exclusive
  if (t == 127) *total_out = v;      // grand total -> offs[N]
}

__global__ void k_scan3(int* __restrict__ offs, const int* __restrict__ partials, int n) {
  int gid = blockIdx.x * SCAN_BLK + threadIdx.x;
  if (gid < n) offs[gid] += partials[blockIdx.x];
}

// scatter {src, weight}; position precomputed (no atomic); grid-stride for MLP
__global__ void k_fill(const int* __restrict__ erow, const int* __restrict__ ecol,
                       const int* __restrict__ rank, const int* __restrict__ offs,
                       const float* __restrict__ dinv, int2* __restrict__ adj, int n) {
  int stride = gridDim.x * blockDim.x;
  for (int e = blockIdx.x * blockDim.x + threadIdx.x; e < n; e += stride) {
    int r = erow[e], c = ecol[e];
    adj[offs[c] + rank[e]] = make_int2(r, __float_as_int(dinv[r] * dinv[c]));
  }
}

// transpose + fp16-convert a 128x128 weight: Wt[c][k] = W[k][c]
__global__ void k_cvtWt(const float* __restrict__ W, __half* __restrict__ Wt) {
  int id = blockIdx.x * blockDim.x + threadIdx.x;  // 16384
  int k = id >> 7, c = id & 127;
  Wt[c * 128 + k] = __float2half(W[id]);
}

// ---------------- MFMA GEMM: C[n,128](fp16) = A[n,128] @ W[128,128] ----------------
// 4 waves/block, each wave 16 rows x 128 cols via 8x mfma_f32_16x16x32_f16 tiles,
// B-fragments read directly from pre-transposed fp16 Wt (L1/L2 hot), f32 accum,
// LDS repack epilogue for coalesced fp16 stores.
// Fragment layout (guide-verified): a[j]=A[l&15][(l>>4)*8+j], b[j]=B[(l>>4)*8+j][l&15],
// D: row=(l>>4)*4+reg, col=l&15.

template <int A_F32>
__global__ __launch_bounds__(256) void k_gemm_mfma(const void* __restrict__ Aptr,
                                                   const __half* __restrict__ Wt,
                                                   __half* __restrict__ C, int n) {
  __shared__ __half Cs[64][136];
  int t = threadIdx.x;
  int wv = t >> 6, l = t & 63;
  int lr = l & 15, lg = l >> 4;
  int row0 = blockIdx.x * 64;
  int arow = row0 + wv * 16 + lr;
  int crow = arow < n ? arow : 0;  // clamp; masked at store
  f16x8 a[4];
  if (A_F32) {
    const float* A = (const float*)Aptr + (size_t)crow * 128 + lg * 8;
#pragma unroll
    for (int ks = 0; ks < 4; ++ks) {
      float4 u0 = *reinterpret_cast<const float4*>(A + ks * 32);
      float4 u1 = *reinterpret_cast<const float4*>(A + ks * 32 + 4);
      f16x8 av;
      av[0] = (_Float16)u0.x; av[1] = (_Float16)u0.y;
      av[2] = (_Float16)u0.z; av[3] = (_Float16)u0.w;
      av[4] = (_Float16)u1.x; av[5] = (_Float16)u1.y;
      av[6] = (_Float16)u1.z; av[7] = (_Float16)u1.w;
      a[ks] = av;
    }
  } else {
    const __half* A = (const __half*)Aptr + (size_t)crow * 128 + lg * 8;
#pragma unroll
    for (int ks = 0; ks < 4; ++ks)
      a[ks] = *reinterpret_cast<const f16x8*>(A + ks * 32);
  }
  f32x4 acc[8];
#pragma unroll
  for (int nt = 0; nt < 8; ++nt) acc[nt] = (f32x4){0.f, 0.f, 0.f, 0.f};
  const __half* wb = Wt + lr * 128 + lg * 8;
#pragma unroll
  for (int ks = 0; ks < 4; ++ks) {
#pragma unroll
    for (int nt = 0; nt < 8; ++nt) {
      f16x8 b = *reinterpret_cast<const f16x8*>(wb + nt * 2048 + ks * 32);
      acc[nt] = __builtin_amdgcn_mfma_f32_16x16x32_f16(a[ks], b, acc[nt], 0, 0, 0);
    }
  }
#pragma unroll
  for (int nt = 0; nt < 8; ++nt)
#pragma unroll
    for (int r = 0; r < 4; ++r)
      Cs[wv * 16 + lg * 4 + r][nt * 16 + lr] = __float2half(acc[nt][r]);
  __syncthreads();
#pragma unroll
  for (int j = 0; j < 4; ++j) {
    int f = t + j * 256;          // 1024 chunks = 64 rows x 16 chunks of 8 halves
    int r = f >> 4, c0 = (f & 15) * 8;
    int gr = row0 + r;
    if (gr < n)
      *reinterpret_cast<uint4*>(&C[(size_t)gr * 128 + c0]) =
          *reinterpret_cast<const uint4*>(&Cs[r][c0]);
  }
}

// ---------------- Aggregation ----------------
// out[i](fp16) = relu( dinv_i^2*h[i] + sum_e w_e h[src_e] + b ), one wave/node,
// fp16 h gathered as __half2, f32 accumulate, fp16 output. int2 {src,w} adjacency
// via wave-uniform scalar loads; 8-deep register pipeline; pad slots (own row, w=0).

__global__ __launch_bounds__(256) void k_agg(const __half* __restrict__ h,
                                             const int* __restrict__ offs,
                                             const int2* __restrict__ adj,
                                             const float* __restrict__ dinv,
                                             const float* __restrict__ bias,
                                             __half* __restrict__ out, int n) {
  int wid = (blockIdx.x * blockDim.x + threadIdx.x) >> 6;
  wid = __builtin_amdgcn_readfirstlane(wid);  // wave-uniform by construction
  int lane = threadIdx.x & 63;
  if (wid >= n) return;
  const __half2* hv = reinterpret_cast<const __half2*>(h);
  float ddst = dinv[wid];
  float w0 = ddst * ddst;
  float2 acc = __half22float2(hv[(size_t)wid * 64 + lane]);
  acc.x *= w0;
  acc.y *= w0;
  int s = offs[wid], e = offs[wid + 1];
  int cnt = e - s;
  const int2* ap = adj + s;

  float wm[8];
  __half2 hg[8];
#pragma unroll
  for (int j = 0; j < 8; ++j) {
    int2 a = ap[j];                 // adj padded by 8: over-read safe
    bool v = j < cnt;
    int src = v ? a.x : wid;
    wm[j] = v ? __int_as_float(a.y) : 0.f;
    hg[j] = hv[(size_t)src * 64 + lane];
  }
  for (int k0 = 0; k0 < cnt; k0 += 8) {
    int k1 = k0 + 8;
    bool more = k1 < cnt;  // wave-uniform
    float wn[8];
    __half2 hn[8];
    if (more) {
#pragma unroll
      for (int j = 0; j < 8; ++j) {
        int2 a = ap[k1 + j];
        bool v = k1 + j < cnt;
        int src = v ? a.x : wid;
        wn[j] = v ? __int_as_float(a.y) : 0.f;
        hn[j] = hv[(size_t)src * 64 + lane];
      }
    }
#pragma unroll
    for (int j = 0; j < 8; ++j) {
      float2 f = __half22float2(hg[j]);
      acc.x = fmaf(wm[j], f.x, acc.x);
      acc.y = fmaf(wm[j], f.y, acc.y);
    }
    if (more) {
#pragma unroll
      for (int j = 0; j < 8; ++j) {
        wm[j] = wn[j];
        hg[j] = hn[j];
      }
    }
  }

  float2 b = reinterpret_cast<const float2*>(bias)[lane];
  acc.x = fmaxf(acc.x + b.x, 0.f);
  acc.y = fmaxf(acc.y + b.y, 0.f);
  reinterpret_cast<__half2*>(out + (size_t)wid * 128)[lane] = __floats2half2_rn(acc.x, acc.y);
}

// ---------------- Output GEMM: out[n,40](f32) = Z[n,128](fp16) @ W[128,40] + b ----------------
// 64-row tile, W transposed into LDS, float4 k-chunks; 2 rows x 5 cols/thread.

__global__ __launch_bounds__(256) void k_gemm_out(const __half* __restrict__ X,
                                                  const float* __restrict__ W,
                                                  const float* __restrict__ b,
                                                  float* __restrict__ out, int n) {
  __shared__ __align__(16) float Xs[64][132];
  __shared__ __align__(16) float Wt[40][132];  // Wt[c][k]
  int t = threadIdx.x;
  int row0 = blockIdx.x * 64;
#pragma unroll
  for (int j = 0; j < 8; ++j) {
    int f = t + j * 256;          // 2048 chunks of 4 halves (64 rows x 32)
    int r = f >> 5, q = f & 31;
    float4 v = make_float4(0.f, 0.f, 0.f, 0.f);
    if (row0 + r < n) {
      const __half2* xp = reinterpret_cast<const __half2*>(X + (size_t)(row0 + r) * 128);
      float2 f0 = __half22float2(xp[q * 2]);
      float2 f1 = __half22float2(xp[q * 2 + 1]);
      v = make_float4(f0.x, f0.y, f1.x, f1.y);
    }
    *reinterpret_cast<float4*>(&Xs[r][q * 4]) = v;
  }
#pragma unroll
  for (int j = 0; j < 20; ++j) {
    int f = t + j * 256;          // 5120 floats of W, coalesced read, transposed write
    int k = f / 40, c = f - k * 40;
    Wt[c][k] = W[f];
  }
  __syncthreads();
  int rg = t >> 3;                // 0..31 -> rows rg*2, rg*2+1
  int cg = t & 7;                 // cols cg*5 .. cg*5+4
  int r0 = rg * 2, r1 = r0 + 1;
  int c0 = cg * 5;
  float acc[2][5] = {};
  for (int k0 = 0; k0 < 128; k0 += 4) {
    float4 x0 = *reinterpret_cast<const float4*>(&Xs[r0][k0]);
    float4 x1 = *reinterpret_cast<const float4*>(&Xs[r1][k0]);
#pragma unroll
    for (int i = 0; i < 5; ++i) {
      float4 wv = *reinterpret_cast<const float4*>(&Wt[c0 + i][k0]);
      acc[0][i] += x0.x * wv.x + x0.y * wv.y + x0.z * wv.z + x0.w * wv.w;
      acc[1][i] += x1.x * wv.x + x1.y * wv.y + x1.z * wv.z + x1.w * wv.w;
    }
  }
#pragma unroll
  for (int i = 0; i < 2; ++i) {
    int gr = row0 + r0 + i;
    if (gr < n) {
#pragma unroll
      for (int j = 0; j < 5; ++j) out[(size_t)gr * 40 + c0 + j] = acc[i][j] + b[c0 + j];
    }
  }
}

// ---------------- launch ----------------

extern "C" void kernel_launch(void* const* d_in, const int* in_sizes, int n_in,
                              void* d_out, int out_size, void* d_ws, size_t ws_size,
                              hipStream_t stream) {
  const float* x = (const float*)d_in[0];
  const int* ei = (const int*)d_in[1];
  const float* W1 = (const float*)d_in[2];
  const float* b1 = (const float*)d_in[3];
  const float* W2 = (const float*)d_in[4];
  const float* b2 = (const float*)d_in[5];
  const float* Wout = (const float*)d_in[6];
  const float* bout = (const float*)d_in[7];
  float* out = (float*)d_out;

  const int N = in_sizes[0] / 128;
  const int E = in_sizes[1] / 2;
  const int* erow = ei;      // edge_index[0] = source j
  const int* ecol = ei + E;  // edge_index[1] = target i

  char* ws = (char*)d_ws;
  size_t off = 0;
  auto alloc = [&](size_t bytes) -> void* {
    void* p = ws + off;
    off = (off + bytes + 255) & ~(size_t)255;
    return p;
  };
  int* counts = (int*)alloc((size_t)N * 4);
  int* offs = (int*)alloc((size_t)(N + 1) * 4);
  float* dinv = (float*)alloc((size_t)N * 4);
  int* partials = (int*)alloc(128 * 4);
  int* rank = (int*)alloc((size_t)E * 4);
  int2* adj = (int2*)alloc((size_t)(E + 8) * 8);        // +8 pad: pipeline over-read
  __half* Wt1 = (__half*)alloc(128 * 128 * 2);
  __half* Wt2 = (__half*)alloc(128 * 128 * 2);
  __half* bufH = (__half*)alloc((size_t)N * 128 * 2);   // gemm output (h)
  __half* bufZ = (__half*)alloc((size_t)N * 128 * 2);   // agg output (z)

  hipMemsetAsync(counts, 0, (size_t)N * 4, stream);

  k_hist<<<(E + 255) / 256, 256, 0, stream>>>(ecol, counts, rank, E);
  k_dinv<<<(N + 255) / 256, 256, 0, stream>>>(counts, dinv, N);

  int nb = (N + SCAN_BLK - 1) / SCAN_BLK;  // 98 for N=100000 (<=128 required)
  k_scan1<<<nb, SCAN_BLK, 0, stream>>>(counts, offs, partials, N);
  k_scan2<<<1, 128, 0, stream>>>(partials, offs + N, nb);
  k_scan3<<<nb, SCAN_BLK, 0, stream>>>(offs, partials, N);
  k_fill<<<1024, 256, 0, stream>>>(erow, ecol, rank, offs, dinv, adj, E);

  k_cvtWt<<<64, 256, 0, stream>>>(W1, Wt1);
  k_cvtWt<<<64, 256, 0, stream>>>(W2, Wt2);

  int gb = (N + 63) / 64;
  k_gemm_mfma<1><<<gb, 256, 0, stream>>>(x, Wt1, bufH, N);
  k_agg<<<(N + 3) / 4, 256, 0, stream>>>(bufH, offs, adj, dinv, b1, bufZ, N);
  k_gemm_mfma<0><<<gb, 256, 0, stream>>>(bufZ, Wt2, bufH, N);
  k_agg<<<(N + 3) / 4, 256, 0, stream>>>(bufH, offs, adj, dinv, b2, bufZ, N);
  k_gemm_out<<<gb, 256, 0, stream>>>(bufZ, Wout, bout, out, N);
}

// Round 7
// 314.614 us; speedup vs baseline: 2.2757x; 1.1140x over previous
//
#include <hip/hip_runtime.h>
#include <hip/hip_bf16.h>
#include <hip/hip_fp16.h>

#define SCAN_BLK 1024

typedef _Float16 f16x8 __attribute__((ext_vector_type(8)));
typedef float f32x4 __attribute__((ext_vector_type(4)));

// ---------------- CSR build ----------------

// counts + per-edge rank (atomicAdd return) in one pass
__global__ void k_hist(const int* __restrict__ col, int* __restrict__ counts,
                       int* __restrict__ rank, int n) {
  int e = blockIdx.x * blockDim.x + threadIdx.x;
  if (e < n) rank[e] = atomicAdd(&counts[col[e]], 1);
}

__global__ void k_scan1(const int* __restrict__ counts, int* __restrict__ offs,
                        int* __restrict__ partials, float* __restrict__ dinv, int n) {
  __shared__ int buf[2][SCAN_BLK];
  int t = threadIdx.x;
  int gid = blockIdx.x * SCAN_BLK + t;
  int x = (gid < n) ? counts[gid] : 0;
  if (gid < n) dinv[gid] = rsqrtf((float)x + 1.0f);  // +1 self loop (fused k_dinv)
  int cur = 0;
  buf[0][t] = x;
  __syncthreads();
  int v = x;
  for (int off = 1; off < SCAN_BLK; off <<= 1) {
    v = buf[cur][t];
    if (t >= off) v += buf[cur][t - off];
    buf[cur ^ 1][t] = v;
    cur ^= 1;
    __syncthreads();
  }
  if (gid < n) offs[gid] = v - x;                 // block-local exclusive
  if (t == SCAN_BLK - 1) partials[blockIdx.x] = v; // block total
}

__global__ void k_scan2(int* __restrict__ partials, int* __restrict__ total_out, int nb) {
  __shared__ int buf[2][128];
  int t = threadIdx.x;
  int x = (t < nb) ? partials[t] : 0;
  int cur = 0;
  buf[0][t] = x;
  __syncthreads();
  int v = x;
  for (int off = 1; off < 128; off <<= 1) {
    v = buf[cur][t];
    if (t >= off) v += buf[cur][t - off];
    buf[cur ^ 1][t] = v;
    cur ^= 1;
    __syncthreads();
  }
  if (t < nb) partials[t] = v - x;   // exclusive
  if (t == 127) *total_out = v;      // grand total -> offs[N]
}

__global__ void k_scan3(int* __restrict__ offs, const int* __restrict__ partials, int n) {
  int gid = blockIdx.x * SCAN_BLK + threadIdx.x;
  if (gid < n) offs[gid] += partials[blockIdx.x];
}

// scatter {src, weight}; position precomputed (no atomic); grid-stride for MLP
__global__ void k_fill(const int* __restrict__ erow, const int* __restrict__ ecol,
                       const int* __restrict__ rank, const int* __restrict__ offs,
                       const float* __restrict__ dinv, int2* __restrict__ adj, int n) {
  int stride = gridDim.x * blockDim.x;
  for (int e = blockIdx.x * blockDim.x + threadIdx.x; e < n; e += stride) {
    int r = erow[e], c = ecol[e];
    adj[offs[c] + rank[e]] = make_int2(r, __float_as_int(dinv[r] * dinv[c]));
  }
}

// transpose + fp16-convert both 128x128 weights: Wt[c][k] = W[k][c]
__global__ void k_cvtWt(const float* __restrict__ W1, const float* __restrict__ W2,
                        __half* __restrict__ Wt1, __half* __restrict__ Wt2) {
  int id = blockIdx.x * blockDim.x + threadIdx.x;  // 32768
  const float* W = (id < 16384) ? W1 : W2;
  __half* Wt = (id < 16384) ? Wt1 : Wt2;
  int i = id & 16383;
  int k = i >> 7, c = i & 127;
  Wt[c * 128 + k] = __float2half(W[i]);
}

// ---------------- MFMA GEMM: C[n,128](fp16) = A[n,128] @ W[128,128] ----------------
// B (all 32 fragments of the 128x128 fp16 weight) is REGISTER-RESIDENT per wave
// (128 VGPRs), loaded once; each wave grid-strides over 16-row A tiles with a
// 2-stage A prefetch. Epilogue repacks D-frags through a PER-WAVE LDS region
// (same-wave LDS is in-order -> no barriers) for coalesced 16B fp16 stores.
// Fragment layout (verified R6): a[j]=A[lr][ks*32+lg*8+j], b[j]=B[ks*32+lg*8+j][nt*16+lr],
// D: row=lg*4+r, col=lr (within tile nt at col base nt*16).

template <int A_F32>
__global__ __launch_bounds__(256) void k_gemm_mfma(const void* __restrict__ Aptr,
                                                   const __half* __restrict__ Wt,
                                                   __half* __restrict__ C, int n) {
  __shared__ __half Cs[4][16][136];
  int t = threadIdx.x;
  int wv = t >> 6, l = t & 63;
  int lr = l & 15, lg = l >> 4;

  f16x8 B[8][4];  // 128 VGPRs
#pragma unroll
  for (int nt = 0; nt < 8; ++nt)
#pragma unroll
    for (int ks = 0; ks < 4; ++ks)
      B[nt][ks] = *reinterpret_cast<const f16x8*>(Wt + (nt * 16 + lr) * 128 + ks * 32 + lg * 8);

  int ntiles = (n + 15) >> 4;
  int wgid = blockIdx.x * 4 + wv;
  int wstride = gridDim.x * 4;

  float4 rf_c[8], rf_n[8];  // raw A (f32 path): 8 x float4 = 32 floats
  f16x8 rh_c[4], rh_n[4];   // raw A (f16 path)

  auto loadA = [&](int tile, float4* rf, f16x8* rh) {
    int arow = tile * 16 + lr;
    int crow = arow < n ? arow : 0;
    if (A_F32) {
      const float* A = (const float*)Aptr + (size_t)crow * 128 + lg * 8;
#pragma unroll
      for (int ks = 0; ks < 4; ++ks) {
        rf[ks * 2] = *reinterpret_cast<const float4*>(A + ks * 32);
        rf[ks * 2 + 1] = *reinterpret_cast<const float4*>(A + ks * 32 + 4);
      }
    } else {
      const __half* A = (const __half*)Aptr + (size_t)crow * 128 + lg * 8;
#pragma unroll
      for (int ks = 0; ks < 4; ++ks) rh[ks] = *reinterpret_cast<const f16x8*>(A + ks * 32);
    }
  };

  if (wgid < ntiles) loadA(wgid, rf_c, rh_c);

  for (int tile = wgid; tile < ntiles; tile += wstride) {
    int tnext = tile + wstride;
    if (tnext < ntiles) loadA(tnext, rf_n, rh_n);

    f16x8 a[4];
    if (A_F32) {
#pragma unroll
      for (int ks = 0; ks < 4; ++ks) {
        float4 u0 = rf_c[ks * 2], u1 = rf_c[ks * 2 + 1];
        f16x8 av;
        av[0] = (_Float16)u0.x; av[1] = (_Float16)u0.y;
        av[2] = (_Float16)u0.z; av[3] = (_Float16)u0.w;
        av[4] = (_Float16)u1.x; av[5] = (_Float16)u1.y;
        av[6] = (_Float16)u1.z; av[7] = (_Float16)u1.w;
        a[ks] = av;
      }
    } else {
#pragma unroll
      for (int ks = 0; ks < 4; ++ks) a[ks] = rh_c[ks];
    }

    f32x4 acc[8];
#pragma unroll
    for (int nt = 0; nt < 8; ++nt) acc[nt] = (f32x4){0.f, 0.f, 0.f, 0.f};
#pragma unroll
    for (int ks = 0; ks < 4; ++ks)
#pragma unroll
      for (int nt = 0; nt < 8; ++nt)
        acc[nt] = __builtin_amdgcn_mfma_f32_16x16x32_f16(a[ks], B[nt][ks], acc[nt], 0, 0, 0);

#pragma unroll
    for (int nt = 0; nt < 8; ++nt)
#pragma unroll
      for (int r = 0; r < 4; ++r)
        Cs[wv][lg * 4 + r][nt * 16 + lr] = __float2half(acc[nt][r]);
    // no barrier: per-wave LDS region, same-wave ds ops are in-order
#pragma unroll
    for (int j = 0; j < 4; ++j) {
      int row = j * 4 + lg;
      int gr = tile * 16 + row;
      if (gr < n)
        *reinterpret_cast<uint4*>(&C[(size_t)gr * 128 + lr * 8]) =
            *reinterpret_cast<const uint4*>(&Cs[wv][row][lr * 8]);
    }

    if (A_F32) {
#pragma unroll
      for (int j = 0; j < 8; ++j) rf_c[j] = rf_n[j];
    } else {
#pragma unroll
      for (int j = 0; j < 4; ++j) rh_c[j] = rh_n[j];
    }
  }
}

// ---------------- Aggregation ----------------
// out[i](fp16) = relu( dinv_i^2*h[i] + sum_e w_e h[src_e] + b ), one wave/node,
// fp16 h gathered as __half2, f32 accumulate, fp16 output. int2 {src,w} adjacency
// via wave-uniform scalar loads; 8-deep register pipeline; pad slots (own row, w=0).

__global__ __launch_bounds__(256) void k_agg(const __half* __restrict__ h,
                                             const int* __restrict__ offs,
                                             const int2* __restrict__ adj,
                                             const float* __restrict__ dinv,
                                             const float* __restrict__ bias,
                                             __half* __restrict__ out, int n) {
  int wid = (blockIdx.x * blockDim.x + threadIdx.x) >> 6;
  wid = __builtin_amdgcn_readfirstlane(wid);  // wave-uniform by construction
  int lane = threadIdx.x & 63;
  if (wid >= n) return;
  const __half2* hv = reinterpret_cast<const __half2*>(h);
  float ddst = dinv[wid];
  float w0 = ddst * ddst;
  float2 acc = __half22float2(hv[(size_t)wid * 64 + lane]);
  acc.x *= w0;
  acc.y *= w0;
  int s = offs[wid], e = offs[wid + 1];
  int cnt = e - s;
  const int2* ap = adj + s;

  float wm[8];
  __half2 hg[8];
#pragma unroll
  for (int j = 0; j < 8; ++j) {
    int2 a = ap[j];                 // adj padded by 8: over-read safe
    bool v = j < cnt;
    int src = v ? a.x : wid;
    wm[j] = v ? __int_as_float(a.y) : 0.f;
    hg[j] = hv[(size_t)src * 64 + lane];
  }
  for (int k0 = 0; k0 < cnt; k0 += 8) {
    int k1 = k0 + 8;
    bool more = k1 < cnt;  // wave-uniform
    float wn[8];
    __half2 hn[8];
    if (more) {
#pragma unroll
      for (int j = 0; j < 8; ++j) {
        int2 a = ap[k1 + j];
        bool v = k1 + j < cnt;
        int src = v ? a.x : wid;
        wn[j] = v ? __int_as_float(a.y) : 0.f;
        hn[j] = hv[(size_t)src * 64 + lane];
      }
    }
#pragma unroll
    for (int j = 0; j < 8; ++j) {
      float2 f = __half22float2(hg[j]);
      acc.x = fmaf(wm[j], f.x, acc.x);
      acc.y = fmaf(wm[j], f.y, acc.y);
    }
    if (more) {
#pragma unroll
      for (int j = 0; j < 8; ++j) {
        wm[j] = wn[j];
        hg[j] = hn[j];
      }
    }
  }

  float2 b = reinterpret_cast<const float2*>(bias)[lane];
  acc.x = fmaxf(acc.x + b.x, 0.f);
  acc.y = fmaxf(acc.y + b.y, 0.f);
  reinterpret_cast<__half2*>(out + (size_t)wid * 128)[lane] = __floats2half2_rn(acc.x, acc.y);
}

// ---------------- Output GEMM: out[n,40](f32) = Z[n,128](fp16) @ W[128,40] + b ----------------
// 64-row tile, W transposed into LDS, float4 k-chunks; 2 rows x 5 cols/thread.

__global__ __launch_bounds__(256) void k_gemm_out(const __half* __restrict__ X,
                                                  const float* __restrict__ W,
                                                  const float* __restrict__ b,
                                                  float* __restrict__ out, int n) {
  __shared__ __align__(16) float Xs[64][132];
  __shared__ __align__(16) float Wt[40][132];  // Wt[c][k]
  int t = threadIdx.x;
  int row0 = blockIdx.x * 64;
#pragma unroll
  for (int j = 0; j < 8; ++j) {
    int f = t + j * 256;          // 2048 chunks of 4 halves (64 rows x 32)
    int r = f >> 5, q = f & 31;
    float4 v = make_float4(0.f, 0.f, 0.f, 0.f);
    if (row0 + r < n) {
      const __half2* xp = reinterpret_cast<const __half2*>(X + (size_t)(row0 + r) * 128);
      float2 f0 = __half22float2(xp[q * 2]);
      float2 f1 = __half22float2(xp[q * 2 + 1]);
      v = make_float4(f0.x, f0.y, f1.x, f1.y);
    }
    *reinterpret_cast<float4*>(&Xs[r][q * 4]) = v;
  }
#pragma unroll
  for (int j = 0; j < 20; ++j) {
    int f = t + j * 256;          // 5120 floats of W, coalesced read, transposed write
    int k = f / 40, c = f - k * 40;
    Wt[c][k] = W[f];
  }
  __syncthreads();
  int rg = t >> 3;                // 0..31 -> rows rg*2, rg*2+1
  int cg = t & 7;                 // cols cg*5 .. cg*5+4
  int r0 = rg * 2, r1 = r0 + 1;
  int c0 = cg * 5;
  float acc[2][5] = {};
  for (int k0 = 0; k0 < 128; k0 += 4) {
    float4 x0 = *reinterpret_cast<const float4*>(&Xs[r0][k0]);
    float4 x1 = *reinterpret_cast<const float4*>(&Xs[r1][k0]);
#pragma unroll
    for (int i = 0; i < 5; ++i) {
      float4 wv = *reinterpret_cast<const float4*>(&Wt[c0 + i][k0]);
      acc[0][i] += x0.x * wv.x + x0.y * wv.y + x0.z * wv.z + x0.w * wv.w;
      acc[1][i] += x1.x * wv.x + x1.y * wv.y + x1.z * wv.z + x1.w * wv.w;
    }
  }
#pragma unroll
  for (int i = 0; i < 2; ++i) {
    int gr = row0 + r0 + i;
    if (gr < n) {
#pragma unroll
      for (int j = 0; j < 5; ++j) out[(size_t)gr * 40 + c0 + j] = acc[i][j] + b[c0 + j];
    }
  }
}

// ---------------- launch ----------------

extern "C" void kernel_launch(void* const* d_in, const int* in_sizes, int n_in,
                              void* d_out, int out_size, void* d_ws, size_t ws_size,
                              hipStream_t stream) {
  const float* x = (const float*)d_in[0];
  const int* ei = (const int*)d_in[1];
  const float* W1 = (const float*)d_in[2];
  const float* b1 = (const float*)d_in[3];
  const float* W2 = (const float*)d_in[4];
  const float* b2 = (const float*)d_in[5];
  const float* Wout = (const float*)d_in[6];
  const float* bout = (const float*)d_in[7];
  float* out = (float*)d_out;

  const int N = in_sizes[0] / 128;
  const int E = in_sizes[1] / 2;
  const int* erow = ei;      // edge_index[0] = source j
  const int* ecol = ei + E;  // edge_index[1] = target i

  char* ws = (char*)d_ws;
  size_t off = 0;
  auto alloc = [&](size_t bytes) -> void* {
    void* p = ws + off;
    off = (off + bytes + 255) & ~(size_t)255;
    return p;
  };
  int* counts = (int*)alloc((size_t)N * 4);
  int* offs = (int*)alloc((size_t)(N + 1) * 4);
  float* dinv = (float*)alloc((size_t)N * 4);
  int* partials = (int*)alloc(128 * 4);
  int* rank = (int*)alloc((size_t)E * 4);
  int2* adj = (int2*)alloc((size_t)(E + 8) * 8);        // +8 pad: pipeline over-read
  __half* Wt1 = (__half*)alloc(128 * 128 * 2);
  __half* Wt2 = (__half*)alloc(128 * 128 * 2);
  __half* bufH = (__half*)alloc((size_t)N * 128 * 2);   // gemm output (h)
  __half* bufZ = (__half*)alloc((size_t)N * 128 * 2);   // agg output (z)

  hipMemsetAsync(counts, 0, (size_t)N * 4, stream);

  k_hist<<<(E + 255) / 256, 256, 0, stream>>>(ecol, counts, rank, E);

  int nb = (N + SCAN_BLK - 1) / SCAN_BLK;  // 98 for N=100000 (<=128 required)
  k_scan1<<<nb, SCAN_BLK, 0, stream>>>(counts, offs, partials, dinv, N);
  k_scan2<<<1, 128, 0, stream>>>(partials, offs + N, nb);
  k_scan3<<<nb, SCAN_BLK, 0, stream>>>(offs, partials, N);
  k_fill<<<1024, 256, 0, stream>>>(erow, ecol, rank, offs, dinv, adj, E);

  k_cvtWt<<<128, 256, 0, stream>>>(W1, W2, Wt1, Wt2);

  k_gemm_mfma<1><<<512, 256, 0, stream>>>(x, Wt1, bufH, N);
  k_agg<<<(N + 3) / 4, 256, 0, stream>>>(bufH, offs, adj, dinv, b1, bufZ, N);
  k_gemm_mfma<0><<<512, 256, 0, stream>>>(bufZ, Wt2, bufH, N);
  k_agg<<<(N + 3) / 4, 256, 0, stream>>>(bufH, offs, adj, dinv, b2, bufZ, N);
  k_gemm_out<<<(N + 63) / 64, 256, 0, stream>>>(bufZ, Wout, bout, out, N);
}

// Round 8
// 300.270 us; speedup vs baseline: 2.3844x; 1.0478x over previous
//
#include <hip/hip_runtime.h>
#include <hip/hip_bf16.h>
#include <hip/hip_fp16.h>

#define SCAN_BLK 1024

typedef _Float16 f16x8 __attribute__((ext_vector_type(8)));
typedef _Float16 f16x4 __attribute__((ext_vector_type(4)));
typedef float f32x4 __attribute__((ext_vector_type(4)));

// ---------------- CSR build ----------------

// counts + per-edge rank (atomicAdd return) in one pass
__global__ void k_hist(const int* __restrict__ col, int* __restrict__ counts,
                       int* __restrict__ rank, int n) {
  int e = blockIdx.x * blockDim.x + threadIdx.x;
  if (e < n) rank[e] = atomicAdd(&counts[col[e]], 1);
}

__global__ void k_scan1(const int* __restrict__ counts, int* __restrict__ offs,
                        int* __restrict__ partials, float* __restrict__ dinv, int n) {
  __shared__ int buf[2][SCAN_BLK];
  int t = threadIdx.x;
  int gid = blockIdx.x * SCAN_BLK + t;
  int x = (gid < n) ? counts[gid] : 0;
  if (gid < n) dinv[gid] = rsqrtf((float)x + 1.0f);  // +1 self loop (fused k_dinv)
  int cur = 0;
  buf[0][t] = x;
  __syncthreads();
  int v = x;
  for (int off = 1; off < SCAN_BLK; off <<= 1) {
    v = buf[cur][t];
    if (t >= off) v += buf[cur][t - off];
    buf[cur ^ 1][t] = v;
    cur ^= 1;
    __syncthreads();
  }
  if (gid < n) offs[gid] = v - x;                 // block-local exclusive
  if (t == SCAN_BLK - 1) partials[blockIdx.x] = v; // block total
}

__global__ void k_scan2(int* __restrict__ partials, int* __restrict__ total_out, int nb) {
  __shared__ int buf[2][128];
  int t = threadIdx.x;
  int x = (t < nb) ? partials[t] : 0;
  int cur = 0;
  buf[0][t] = x;
  __syncthreads();
  int v = x;
  for (int off = 1; off < 128; off <<= 1) {
    v = buf[cur][t];
    if (t >= off) v += buf[cur][t - off];
    buf[cur ^ 1][t] = v;
    cur ^= 1;
    __syncthreads();
  }
  if (t < nb) partials[t] = v - x;   // exclusive
  if (t == 127) *total_out = v;      // grand total -> offs[N]
}

__global__ void k_scan3(int* __restrict__ offs, const int* __restrict__ partials, int n) {
  int gid = blockIdx.x * SCAN_BLK + threadIdx.x;
  if (gid < n) offs[gid] += partials[blockIdx.x];
}

// scatter {src, weight}; position precomputed (no atomic); grid-stride for MLP
__global__ void k_fill(const int* __restrict__ erow, const int* __restrict__ ecol,
                       const int* __restrict__ rank, const int* __restrict__ offs,
                       const float* __restrict__ dinv, int2* __restrict__ adj, int n) {
  int stride = gridDim.x * blockDim.x;
  for (int e = blockIdx.x * blockDim.x + threadIdx.x; e < n; e += stride) {
    int r = erow[e], c = ecol[e];
    adj[offs[c] + rank[e]] = make_int2(r, __float_as_int(dinv[r] * dinv[c]));
  }
}

// fp16-convert weights: Wt1/Wt2 transposed 128x128; WtO = Wout^T [40][128]
__global__ void k_cvtWt(const float* __restrict__ W1, const float* __restrict__ W2,
                        const float* __restrict__ Wout,
                        __half* __restrict__ Wt1, __half* __restrict__ Wt2,
                        __half* __restrict__ WtO) {
  int id = blockIdx.x * blockDim.x + threadIdx.x;  // 37888 total
  if (id < 32768) {
    const float* W = (id < 16384) ? W1 : W2;
    __half* Wt = (id < 16384) ? Wt1 : Wt2;
    int i = id & 16383;
    int k = i >> 7, c = i & 127;
    Wt[c * 128 + k] = __float2half(W[i]);
  } else if (id < 37888) {
    int i = id - 32768;          // Wout[k][c], k<128, c<40
    int k = i / 40, c = i - k * 40;
    WtO[c * 128 + k] = __float2half(Wout[i]);
  }
}

// ---------------- MFMA GEMM: C[n,128](fp16) = A[n,128] @ W[128,128] ----------------
// B register-resident per wave (128 VGPRs); waves grid-stride over 16-row tiles
// with 2-stage A prefetch; per-wave LDS repack epilogue (no barriers).

template <int A_F32>
__global__ __launch_bounds__(256) void k_gemm_mfma(const void* __restrict__ Aptr,
                                                   const __half* __restrict__ Wt,
                                                   __half* __restrict__ C, int n) {
  __shared__ __half Cs[4][16][136];
  int t = threadIdx.x;
  int wv = t >> 6, l = t & 63;
  int lr = l & 15, lg = l >> 4;

  f16x8 B[8][4];  // 128 VGPRs
#pragma unroll
  for (int nt = 0; nt < 8; ++nt)
#pragma unroll
    for (int ks = 0; ks < 4; ++ks)
      B[nt][ks] = *reinterpret_cast<const f16x8*>(Wt + (nt * 16 + lr) * 128 + ks * 32 + lg * 8);

  int ntiles = (n + 15) >> 4;
  int wgid = blockIdx.x * 4 + wv;
  int wstride = gridDim.x * 4;

  float4 rf_c[8], rf_n[8];
  f16x8 rh_c[4], rh_n[4];

  auto loadA = [&](int tile, float4* rf, f16x8* rh) {
    int arow = tile * 16 + lr;
    int crow = arow < n ? arow : 0;
    if (A_F32) {
      const float* A = (const float*)Aptr + (size_t)crow * 128 + lg * 8;
#pragma unroll
      for (int ks = 0; ks < 4; ++ks) {
        rf[ks * 2] = *reinterpret_cast<const float4*>(A + ks * 32);
        rf[ks * 2 + 1] = *reinterpret_cast<const float4*>(A + ks * 32 + 4);
      }
    } else {
      const __half* A = (const __half*)Aptr + (size_t)crow * 128 + lg * 8;
#pragma unroll
      for (int ks = 0; ks < 4; ++ks) rh[ks] = *reinterpret_cast<const f16x8*>(A + ks * 32);
    }
  };

  if (wgid < ntiles) loadA(wgid, rf_c, rh_c);

  for (int tile = wgid; tile < ntiles; tile += wstride) {
    int tnext = tile + wstride;
    if (tnext < ntiles) loadA(tnext, rf_n, rh_n);

    f16x8 a[4];
    if (A_F32) {
#pragma unroll
      for (int ks = 0; ks < 4; ++ks) {
        float4 u0 = rf_c[ks * 2], u1 = rf_c[ks * 2 + 1];
        f16x8 av;
        av[0] = (_Float16)u0.x; av[1] = (_Float16)u0.y;
        av[2] = (_Float16)u0.z; av[3] = (_Float16)u0.w;
        av[4] = (_Float16)u1.x; av[5] = (_Float16)u1.y;
        av[6] = (_Float16)u1.z; av[7] = (_Float16)u1.w;
        a[ks] = av;
      }
    } else {
#pragma unroll
      for (int ks = 0; ks < 4; ++ks) a[ks] = rh_c[ks];
    }

    f32x4 acc[8];
#pragma unroll
    for (int nt = 0; nt < 8; ++nt) acc[nt] = (f32x4){0.f, 0.f, 0.f, 0.f};
#pragma unroll
    for (int ks = 0; ks < 4; ++ks)
#pragma unroll
      for (int nt = 0; nt < 8; ++nt)
        acc[nt] = __builtin_amdgcn_mfma_f32_16x16x32_f16(a[ks], B[nt][ks], acc[nt], 0, 0, 0);

#pragma unroll
    for (int nt = 0; nt < 8; ++nt)
#pragma unroll
      for (int r = 0; r < 4; ++r)
        Cs[wv][lg * 4 + r][nt * 16 + lr] = __float2half(acc[nt][r]);
    // no barrier: per-wave LDS region, same-wave ds ops are in-order
#pragma unroll
    for (int j = 0; j < 4; ++j) {
      int row = j * 4 + lg;
      int gr = tile * 16 + row;
      if (gr < n)
        *reinterpret_cast<uint4*>(&C[(size_t)gr * 128 + lr * 8]) =
            *reinterpret_cast<const uint4*>(&Cs[wv][row][lr * 8]);
    }

    if (A_F32) {
#pragma unroll
      for (int j = 0; j < 8; ++j) rf_c[j] = rf_n[j];
    } else {
#pragma unroll
      for (int j = 0; j < 4; ++j) rh_c[j] = rh_n[j];
    }
  }
}

// ---------------- Aggregation (+ optional fused output GEMV) ----------------
// z[i] = relu( dinv_i^2*h[i] + sum_e w_e h[src_e] + b ), one wave/node.
// FUSE=0: write z as fp16.
// FUSE=1: keep z in f32, compute out[i] = z @ WoT^T + bout via per-wave LDS
//         (WoT staged fp16 [40][132] per block; lanes 0..39 own one column).

template <int FUSE>
__global__ __launch_bounds__(256) void k_agg(const __half* __restrict__ h,
                                             const int* __restrict__ offs,
                                             const int2* __restrict__ adj,
                                             const float* __restrict__ dinv,
                                             const float* __restrict__ bias,
                                             __half* __restrict__ outz,
                                             const __half* __restrict__ WoT,
                                             const float* __restrict__ bout,
                                             float* __restrict__ outf, int n) {
  extern __shared__ char smem[];  // FUSE: [wo 40x132 fp16 = 10560B][zs 4x128 f32 = 2048B]
  int t = threadIdx.x;
  int wv = t >> 6;
  int lane = t & 63;

  if (FUSE) {
    const uint* wsrc = (const uint*)WoT;  // 2560 uints (40x64)
    uint* wdst = (uint*)smem;             // stride 66 uints (132 halves)
#pragma unroll
    for (int j = 0; j < 10; ++j) {
      int u = t + j * 256;
      int c = u >> 6, kk = u & 63;
      wdst[c * 66 + kk] = wsrc[u];
    }
    __syncthreads();
  }

  int wid = (blockIdx.x * blockDim.x + t) >> 6;
  wid = __builtin_amdgcn_readfirstlane(wid);
  bool active = wid < n;
  int wid0 = active ? wid : 0;

  const __half2* hv = reinterpret_cast<const __half2*>(h);
  float ddst = dinv[wid0];
  float w0 = ddst * ddst;
  float2 acc = __half22float2(hv[(size_t)wid0 * 64 + lane]);
  acc.x *= w0;
  acc.y *= w0;
  int s = offs[wid0], e = offs[wid0 + 1];
  int cnt = active ? e - s : 0;
  const int2* ap = adj + s;

  float wm[8];
  __half2 hg[8];
#pragma unroll
  for (int j = 0; j < 8; ++j) {
    int2 a = ap[j];                 // adj padded by 8: over-read safe
    bool v = j < cnt;
    int src = v ? a.x : wid0;
    wm[j] = v ? __int_as_float(a.y) : 0.f;
    hg[j] = hv[(size_t)src * 64 + lane];
  }
  for (int k0 = 0; k0 < cnt; k0 += 8) {
    int k1 = k0 + 8;
    bool more = k1 < cnt;  // wave-uniform
    float wn[8];
    __half2 hn[8];
    if (more) {
#pragma unroll
      for (int j = 0; j < 8; ++j) {
        int2 a = ap[k1 + j];
        bool v = k1 + j < cnt;
        int src = v ? a.x : wid0;
        wn[j] = v ? __int_as_float(a.y) : 0.f;
        hn[j] = hv[(size_t)src * 64 + lane];
      }
    }
#pragma unroll
    for (int j = 0; j < 8; ++j) {
      float2 f = __half22float2(hg[j]);
      acc.x = fmaf(wm[j], f.x, acc.x);
      acc.y = fmaf(wm[j], f.y, acc.y);
    }
    if (more) {
#pragma unroll
      for (int j = 0; j < 8; ++j) {
        wm[j] = wn[j];
        hg[j] = hn[j];
      }
    }
  }

  float2 b = reinterpret_cast<const float2*>(bias)[lane];
  acc.x = fmaxf(acc.x + b.x, 0.f);
  acc.y = fmaxf(acc.y + b.y, 0.f);

  if (!FUSE) {
    if (active)
      reinterpret_cast<__half2*>(outz + (size_t)wid * 128)[lane] =
          __floats2half2_rn(acc.x, acc.y);
  } else {
    if (active) {
      float* zsw = (float*)(smem + 10560) + wv * 128;
      zsw[2 * lane] = acc.x;
      zsw[2 * lane + 1] = acc.y;
      // same-wave LDS write->read: in-order, compiler inserts lgkmcnt
      if (lane < 40) {
        const __half* wrow = (const __half*)smem + lane * 132;
        float o = bout[lane];
#pragma unroll
        for (int k0 = 0; k0 < 128; k0 += 8) {
          float4 z0 = *reinterpret_cast<const float4*>(zsw + k0);
          float4 z1 = *reinterpret_cast<const float4*>(zsw + k0 + 4);
          f16x4 u0 = *reinterpret_cast<const f16x4*>(wrow + k0);
          f16x4 u1 = *reinterpret_cast<const f16x4*>(wrow + k0 + 4);
          o += z0.x * (float)u0[0] + z0.y * (float)u0[1] +
               z0.z * (float)u0[2] + z0.w * (float)u0[3] +
               z1.x * (float)u1[0] + z1.y * (float)u1[1] +
               z1.z * (float)u1[2] + z1.w * (float)u1[3];
        }
        outf[(size_t)wid * 40 + lane] = o;
      }
    }
  }
}

// ---------------- launch ----------------

extern "C" void kernel_launch(void* const* d_in, const int* in_sizes, int n_in,
                              void* d_out, int out_size, void* d_ws, size_t ws_size,
                              hipStream_t stream) {
  const float* x = (const float*)d_in[0];
  const int* ei = (const int*)d_in[1];
  const float* W1 = (const float*)d_in[2];
  const float* b1 = (const float*)d_in[3];
  const float* W2 = (const float*)d_in[4];
  const float* b2 = (const float*)d_in[5];
  const float* Wout = (const float*)d_in[6];
  const float* bout = (const float*)d_in[7];
  float* out = (float*)d_out;

  const int N = in_sizes[0] / 128;
  const int E = in_sizes[1] / 2;
  const int* erow = ei;      // edge_index[0] = source j
  const int* ecol = ei + E;  // edge_index[1] = target i

  char* ws = (char*)d_ws;
  size_t off = 0;
  auto alloc = [&](size_t bytes) -> void* {
    void* p = ws + off;
    off = (off + bytes + 255) & ~(size_t)255;
    return p;
  };
  int* counts = (int*)alloc((size_t)N * 4);
  int* offs = (int*)alloc((size_t)(N + 1) * 4);
  float* dinv = (float*)alloc((size_t)N * 4);
  int* partials = (int*)alloc(128 * 4);
  int* rank = (int*)alloc((size_t)E * 4);
  int2* adj = (int2*)alloc((size_t)(E + 8) * 8);        // +8 pad: pipeline over-read
  __half* Wt1 = (__half*)alloc(128 * 128 * 2);
  __half* Wt2 = (__half*)alloc(128 * 128 * 2);
  __half* WtO = (__half*)alloc(40 * 128 * 2);
  __half* bufH = (__half*)alloc((size_t)N * 128 * 2);   // gemm output (h)
  __half* bufZ = (__half*)alloc((size_t)N * 128 * 2);   // agg1 output (z1)

  hipMemsetAsync(counts, 0, (size_t)N * 4, stream);

  k_hist<<<(E + 255) / 256, 256, 0, stream>>>(ecol, counts, rank, E);

  int nb = (N + SCAN_BLK - 1) / SCAN_BLK;  // 98 for N=100000 (<=128 required)
  k_scan1<<<nb, SCAN_BLK, 0, stream>>>(counts, offs, partials, dinv, N);
  k_scan2<<<1, 128, 0, stream>>>(partials, offs + N, nb);
  k_scan3<<<nb, SCAN_BLK, 0, stream>>>(offs, partials, N);
  k_fill<<<1024, 256, 0, stream>>>(erow, ecol, rank, offs, dinv, adj, E);

  k_cvtWt<<<148, 256, 0, stream>>>(W1, W2, Wout, Wt1, Wt2, WtO);

  k_gemm_mfma<1><<<512, 256, 0, stream>>>(x, Wt1, bufH, N);
  k_agg<0><<<(N + 3) / 4, 256, 0, stream>>>(bufH, offs, adj, dinv, b1, bufZ,
                                            nullptr, nullptr, nullptr, N);
  k_gemm_mfma<0><<<512, 256, 0, stream>>>(bufZ, Wt2, bufH, N);
  k_agg<1><<<(N + 3) / 4, 256, 12608, stream>>>(bufH, offs, adj, dinv, b2, nullptr,
                                                WtO, bout, out, N);
}

// Round 9
// 291.319 us; speedup vs baseline: 2.4577x; 1.0307x over previous
//
#include <hip/hip_runtime.h>
#include <hip/hip_bf16.h>
#include <hip/hip_fp16.h>

#define SCAN_BLK 1024

typedef _Float16 f16x8 __attribute__((ext_vector_type(8)));
typedef float f32x4 __attribute__((ext_vector_type(4)));

// ---------------- CSR build ----------------

// counts + per-edge rank (atomicAdd return) in one pass
__global__ void k_hist(const int* __restrict__ col, int* __restrict__ counts,
                       int* __restrict__ rank, int n) {
  int e = blockIdx.x * blockDim.x + threadIdx.x;
  if (e < n) rank[e] = atomicAdd(&counts[col[e]], 1);
}

__global__ void k_scan1(const int* __restrict__ counts, int* __restrict__ offs,
                        int* __restrict__ partials, float* __restrict__ dinv, int n) {
  __shared__ int buf[2][SCAN_BLK];
  int t = threadIdx.x;
  int gid = blockIdx.x * SCAN_BLK + t;
  int x = (gid < n) ? counts[gid] : 0;
  if (gid < n) dinv[gid] = rsqrtf((float)x + 1.0f);  // +1 self loop (fused k_dinv)
  int cur = 0;
  buf[0][t] = x;
  __syncthreads();
  int v = x;
  for (int off = 1; off < SCAN_BLK; off <<= 1) {
    v = buf[cur][t];
    if (t >= off) v += buf[cur][t - off];
    buf[cur ^ 1][t] = v;
    cur ^= 1;
    __syncthreads();
  }
  if (gid < n) offs[gid] = v - x;                 // block-local exclusive
  if (t == SCAN_BLK - 1) partials[blockIdx.x] = v; // block total
}

__global__ void k_scan2(int* __restrict__ partials, int* __restrict__ total_out, int nb) {
  __shared__ int buf[2][128];
  int t = threadIdx.x;
  int x = (t < nb) ? partials[t] : 0;
  int cur = 0;
  buf[0][t] = x;
  __syncthreads();
  int v = x;
  for (int off = 1; off < 128; off <<= 1) {
    v = buf[cur][t];
    if (t >= off) v += buf[cur][t - off];
    buf[cur ^ 1][t] = v;
    cur ^= 1;
    __syncthreads();
  }
  if (t < nb) partials[t] = v - x;   // exclusive
  if (t == 127) *total_out = v;      // grand total -> offs[N]
}

__global__ void k_scan3(int* __restrict__ offs, const int* __restrict__ partials, int n) {
  int gid = blockIdx.x * SCAN_BLK + threadIdx.x;
  if (gid < n) offs[gid] += partials[blockIdx.x];
}

// scatter {src, weight}; position precomputed (no atomic); grid-stride for MLP
__global__ void k_fill(const int* __restrict__ erow, const int* __restrict__ ecol,
                       const int* __restrict__ rank, const int* __restrict__ offs,
                       const float* __restrict__ dinv, int2* __restrict__ adj, int n) {
  int stride = gridDim.x * blockDim.x;
  for (int e = blockIdx.x * blockDim.x + threadIdx.x; e < n; e += stride) {
    int r = erow[e], c = ecol[e];
    adj[offs[c] + rank[e]] = make_int2(r, __float_as_int(dinv[r] * dinv[c]));
  }
}

// fp16-convert weights: Wt1/Wt2 transposed 128x128; WtO = Wout^T zero-padded [48][128]
__global__ void k_cvtWt(const float* __restrict__ W1, const float* __restrict__ W2,
                        const float* __restrict__ Wout,
                        __half* __restrict__ Wt1, __half* __restrict__ Wt2,
                        __half* __restrict__ WtO) {
  int id = blockIdx.x * blockDim.x + threadIdx.x;  // 38912 total
  if (id < 32768) {
    const float* W = (id < 16384) ? W1 : W2;
    __half* Wt = (id < 16384) ? Wt1 : Wt2;
    int i = id & 16383;
    int k = i >> 7, c = i & 127;
    Wt[c * 128 + k] = __float2half(W[i]);
  } else if (id < 38912) {
    int i = id - 32768;          // [48][128]: c = i>>7, k = i&127
    int c = i >> 7, k = i & 127;
    WtO[i] = (c < 40) ? __float2half(Wout[k * 40 + c]) : __half(0.0f);
  }
}

// ---------------- MFMA GEMM: C[n,128](fp16) = A[n,128] @ W[128,128] ----------------
// B register-resident per wave (128 VGPRs); waves grid-stride over 16-row tiles
// with 2-stage A prefetch; per-wave LDS repack epilogue (no barriers).

template <int A_F32>
__global__ __launch_bounds__(256) void k_gemm_mfma(const void* __restrict__ Aptr,
                                                   const __half* __restrict__ Wt,
                                                   __half* __restrict__ C, int n) {
  __shared__ __half Cs[4][16][136];
  int t = threadIdx.x;
  int wv = t >> 6, l = t & 63;
  int lr = l & 15, lg = l >> 4;

  f16x8 B[8][4];  // 128 VGPRs
#pragma unroll
  for (int nt = 0; nt < 8; ++nt)
#pragma unroll
    for (int ks = 0; ks < 4; ++ks)
      B[nt][ks] = *reinterpret_cast<const f16x8*>(Wt + (nt * 16 + lr) * 128 + ks * 32 + lg * 8);

  int ntiles = (n + 15) >> 4;
  int wgid = blockIdx.x * 4 + wv;
  int wstride = gridDim.x * 4;

  float4 rf_c[8], rf_n[8];
  f16x8 rh_c[4], rh_n[4];

  auto loadA = [&](int tile, float4* rf, f16x8* rh) {
    int arow = tile * 16 + lr;
    int crow = arow < n ? arow : 0;
    if (A_F32) {
      const float* A = (const float*)Aptr + (size_t)crow * 128 + lg * 8;
#pragma unroll
      for (int ks = 0; ks < 4; ++ks) {
        rf[ks * 2] = *reinterpret_cast<const float4*>(A + ks * 32);
        rf[ks * 2 + 1] = *reinterpret_cast<const float4*>(A + ks * 32 + 4);
      }
    } else {
      const __half* A = (const __half*)Aptr + (size_t)crow * 128 + lg * 8;
#pragma unroll
      for (int ks = 0; ks < 4; ++ks) rh[ks] = *reinterpret_cast<const f16x8*>(A + ks * 32);
    }
  };

  if (wgid < ntiles) loadA(wgid, rf_c, rh_c);

  for (int tile = wgid; tile < ntiles; tile += wstride) {
    int tnext = tile + wstride;
    if (tnext < ntiles) loadA(tnext, rf_n, rh_n);

    f16x8 a[4];
    if (A_F32) {
#pragma unroll
      for (int ks = 0; ks < 4; ++ks) {
        float4 u0 = rf_c[ks * 2], u1 = rf_c[ks * 2 + 1];
        f16x8 av;
        av[0] = (_Float16)u0.x; av[1] = (_Float16)u0.y;
        av[2] = (_Float16)u0.z; av[3] = (_Float16)u0.w;
        av[4] = (_Float16)u1.x; av[5] = (_Float16)u1.y;
        av[6] = (_Float16)u1.z; av[7] = (_Float16)u1.w;
        a[ks] = av;
      }
    } else {
#pragma unroll
      for (int ks = 0; ks < 4; ++ks) a[ks] = rh_c[ks];
    }

    f32x4 acc[8];
#pragma unroll
    for (int nt = 0; nt < 8; ++nt) acc[nt] = (f32x4){0.f, 0.f, 0.f, 0.f};
#pragma unroll
    for (int ks = 0; ks < 4; ++ks)
#pragma unroll
      for (int nt = 0; nt < 8; ++nt)
        acc[nt] = __builtin_amdgcn_mfma_f32_16x16x32_f16(a[ks], B[nt][ks], acc[nt], 0, 0, 0);

#pragma unroll
    for (int nt = 0; nt < 8; ++nt)
#pragma unroll
      for (int r = 0; r < 4; ++r)
        Cs[wv][lg * 4 + r][nt * 16 + lr] = __float2half(acc[nt][r]);
    // no barrier: per-wave LDS region, same-wave ds ops are in-order
#pragma unroll
    for (int j = 0; j < 4; ++j) {
      int row = j * 4 + lg;
      int gr = tile * 16 + row;
      if (gr < n)
        *reinterpret_cast<uint4*>(&C[(size_t)gr * 128 + lr * 8]) =
            *reinterpret_cast<const uint4*>(&Cs[wv][row][lr * 8]);
    }

    if (A_F32) {
#pragma unroll
      for (int j = 0; j < 8; ++j) rf_c[j] = rf_n[j];
    } else {
#pragma unroll
      for (int j = 0; j < 4; ++j) rh_c[j] = rh_n[j];
    }
  }
}

// ---------------- Aggregation ----------------
// z[i](fp16) = relu( dinv_i^2*h[i] + sum_e w_e h[src_e] + b ), one wave/node,
// fp16 h gathered as __half2, f32 accumulate. int2 {src,w} adjacency via
// wave-uniform scalar loads; 8-deep register pipeline; pad slots (own row, w=0).

__global__ __launch_bounds__(256) void k_agg(const __half* __restrict__ h,
                                             const int* __restrict__ offs,
                                             const int2* __restrict__ adj,
                                             const float* __restrict__ dinv,
                                             const float* __restrict__ bias,
                                             __half* __restrict__ out, int n) {
  int wid = (blockIdx.x * blockDim.x + threadIdx.x) >> 6;
  wid = __builtin_amdgcn_readfirstlane(wid);  // wave-uniform by construction
  int lane = threadIdx.x & 63;
  if (wid >= n) return;
  const __half2* hv = reinterpret_cast<const __half2*>(h);
  float ddst = dinv[wid];
  float w0 = ddst * ddst;
  float2 acc = __half22float2(hv[(size_t)wid * 64 + lane]);
  acc.x *= w0;
  acc.y *= w0;
  int s = offs[wid], e = offs[wid + 1];
  int cnt = e - s;
  const int2* ap = adj + s;

  float wm[8];
  __half2 hg[8];
#pragma unroll
  for (int j = 0; j < 8; ++j) {
    int2 a = ap[j];                 // adj padded by 8: over-read safe
    bool v = j < cnt;
    int src = v ? a.x : wid;
    wm[j] = v ? __int_as_float(a.y) : 0.f;
    hg[j] = hv[(size_t)src * 64 + lane];
  }
  for (int k0 = 0; k0 < cnt; k0 += 8) {
    int k1 = k0 + 8;
    bool more = k1 < cnt;  // wave-uniform
    float wn[8];
    __half2 hn[8];
    if (more) {
#pragma unroll
      for (int j = 0; j < 8; ++j) {
        int2 a = ap[k1 + j];
        bool v = k1 + j < cnt;
        int src = v ? a.x : wid;
        wn[j] = v ? __int_as_float(a.y) : 0.f;
        hn[j] = hv[(size_t)src * 64 + lane];
      }
    }
#pragma unroll
    for (int j = 0; j < 8; ++j) {
      float2 f = __half22float2(hg[j]);
      acc.x = fmaf(wm[j], f.x, acc.x);
      acc.y = fmaf(wm[j], f.y, acc.y);
    }
    if (more) {
#pragma unroll
      for (int j = 0; j < 8; ++j) {
        wm[j] = wn[j];
        hg[j] = hn[j];
      }
    }
  }

  float2 b = reinterpret_cast<const float2*>(bias)[lane];
  acc.x = fmaxf(acc.x + b.x, 0.f);
  acc.y = fmaxf(acc.y + b.y, 0.f);
  reinterpret_cast<__half2*>(out + (size_t)wid * 128)[lane] = __floats2half2_rn(acc.x, acc.y);
}

// ---------------- MFMA output GEMM: out[n,40](f32) = Z[n,128](fp16) @ Wout + b ----
// WoT zero-padded to [48][128] fp16; B register-resident (12 frags, 48 VGPRs);
// waves grid-stride over 16-row tiles; bias in-register; per-wave LDS repack
// (no barriers) then coalesced float4 stores of 40-f32 rows.

__global__ __launch_bounds__(256) void k_gemm_out(const __half* __restrict__ Z,
                                                  const __half* __restrict__ WtO,
                                                  const float* __restrict__ bout,
                                                  float* __restrict__ out, int n) {
  __shared__ float Cs[4][16][52];
  int t = threadIdx.x;
  int wv = t >> 6, l = t & 63;
  int lr = l & 15, lg = l >> 4;

  f16x8 B[3][4];  // 48 VGPRs
#pragma unroll
  for (int nt = 0; nt < 3; ++nt)
#pragma unroll
    for (int ks = 0; ks < 4; ++ks)
      B[nt][ks] = *reinterpret_cast<const f16x8*>(WtO + (nt * 16 + lr) * 128 + ks * 32 + lg * 8);

  float bb[3];
#pragma unroll
  for (int nt = 0; nt < 3; ++nt) {
    int c = nt * 16 + lr;
    bb[nt] = (c < 40) ? bout[c] : 0.f;
  }

  int ntiles = (n + 15) >> 4;
  int wgid = blockIdx.x * 4 + wv;
  int wstride = gridDim.x * 4;

  f16x8 rh_c[4], rh_n[4];
  auto loadA = [&](int tile, f16x8* rh) {
    int arow = tile * 16 + lr;
    int crow = arow < n ? arow : 0;
    const __half* A = Z + (size_t)crow * 128 + lg * 8;
#pragma unroll
    for (int ks = 0; ks < 4; ++ks) rh[ks] = *reinterpret_cast<const f16x8*>(A + ks * 32);
  };

  if (wgid < ntiles) loadA(wgid, rh_c);

  for (int tile = wgid; tile < ntiles; tile += wstride) {
    int tnext = tile + wstride;
    if (tnext < ntiles) loadA(tnext, rh_n);

    f32x4 acc[3];
#pragma unroll
    for (int nt = 0; nt < 3; ++nt) acc[nt] = (f32x4){0.f, 0.f, 0.f, 0.f};
#pragma unroll
    for (int ks = 0; ks < 4; ++ks)
#pragma unroll
      for (int nt = 0; nt < 3; ++nt)
        acc[nt] = __builtin_amdgcn_mfma_f32_16x16x32_f16(rh_c[ks], B[nt][ks], acc[nt], 0, 0, 0);

#pragma unroll
    for (int nt = 0; nt < 3; ++nt)
#pragma unroll
      for (int r = 0; r < 4; ++r)
        Cs[wv][lg * 4 + r][nt * 16 + lr] = acc[nt][r] + bb[nt];
    // no barrier: per-wave LDS region, same-wave ds ops are in-order
#pragma unroll
    for (int j = 0; j < 3; ++j) {
      int f = l + j * 64;  // 160 float4 chunks = 16 rows x 10
      if (f < 160) {
        int row = f / 10, c4 = f - row * 10;
        int gr = tile * 16 + row;
        if (gr < n)
          *reinterpret_cast<float4*>(&out[(size_t)gr * 40 + c4 * 4]) =
              *reinterpret_cast<const float4*>(&Cs[wv][row][c4 * 4]);
      }
    }
#pragma unroll
    for (int j = 0; j < 4; ++j) rh_c[j] = rh_n[j];
  }
}

// ---------------- launch ----------------

extern "C" void kernel_launch(void* const* d_in, const int* in_sizes, int n_in,
                              void* d_out, int out_size, void* d_ws, size_t ws_size,
                              hipStream_t stream) {
  const float* x = (const float*)d_in[0];
  const int* ei = (const int*)d_in[1];
  const float* W1 = (const float*)d_in[2];
  const float* b1 = (const float*)d_in[3];
  const float* W2 = (const float*)d_in[4];
  const float* b2 = (const float*)d_in[5];
  const float* Wout = (const float*)d_in[6];
  const float* bout = (const float*)d_in[7];
  float* out = (float*)d_out;

  const int N = in_sizes[0] / 128;
  const int E = in_sizes[1] / 2;
  const int* erow = ei;      // edge_index[0] = source j
  const int* ecol = ei + E;  // edge_index[1] = target i

  char* ws = (char*)d_ws;
  size_t off = 0;
  auto alloc = [&](size_t bytes) -> void* {
    void* p = ws + off;
    off = (off + bytes + 255) & ~(size_t)255;
    return p;
  };
  int* counts = (int*)alloc((size_t)N * 4);
  int* offs = (int*)alloc((size_t)(N + 1) * 4);
  float* dinv = (float*)alloc((size_t)N * 4);
  int* partials = (int*)alloc(128 * 4);
  int* rank = (int*)alloc((size_t)E * 4);
  int2* adj = (int2*)alloc((size_t)(E + 8) * 8);        // +8 pad: pipeline over-read
  __half* Wt1 = (__half*)alloc(128 * 128 * 2);
  __half* Wt2 = (__half*)alloc(128 * 128 * 2);
  __half* WtO = (__half*)alloc(48 * 128 * 2);
  __half* bufH = (__half*)alloc((size_t)N * 128 * 2);   // gemm output (h)
  __half* bufZ = (__half*)alloc((size_t)N * 128 * 2);   // agg output (z)

  hipMemsetAsync(counts, 0, (size_t)N * 4, stream);

  k_hist<<<(E + 255) / 256, 256, 0, stream>>>(ecol, counts, rank, E);

  int nb = (N + SCAN_BLK - 1) / SCAN_BLK;  // 98 for N=100000 (<=128 required)
  k_scan1<<<nb, SCAN_BLK, 0, stream>>>(counts, offs, partials, dinv, N);
  k_scan2<<<1, 128, 0, stream>>>(partials, offs + N, nb);
  k_scan3<<<nb, SCAN_BLK, 0, stream>>>(offs, partials, N);
  k_fill<<<1024, 256, 0, stream>>>(erow, ecol, rank, offs, dinv, adj, E);

  k_cvtWt<<<152, 256, 0, stream>>>(W1, W2, Wout, Wt1, Wt2, WtO);

  k_gemm_mfma<1><<<512, 256, 0, stream>>>(x, Wt1, bufH, N);
  k_agg<<<(N + 3) / 4, 256, 0, stream>>>(bufH, offs, adj, dinv, b1, bufZ, N);
  k_gemm_mfma<0><<<512, 256, 0, stream>>>(bufZ, Wt2, bufH, N);
  k_agg<<<(N + 3) / 4, 256, 0, stream>>>(bufH, offs, adj, dinv, b2, bufZ, N);
  k_gemm_out<<<512, 256, 0, stream>>>(bufZ, WtO, bout, out, N);
}

// Round 10
// 277.109 us; speedup vs baseline: 2.5837x; 1.0513x over previous
//
#include <hip/hip_runtime.h>
#include <hip/hip_bf16.h>
#include <hip/hip_fp16.h>

#define SCAN_BLK 1024

typedef _Float16 f16x8 __attribute__((ext_vector_type(8)));
typedef float f32x4 __attribute__((ext_vector_type(4)));

// ---------------- CSR build + weight convert (one launch) ----------------

// blocks [0, nbh): counts + per-edge rank (atomicAdd return).
// blocks [nbh, nbh+152): fp16 weight converts (independent work, saves a launch).
__global__ void k_hist(const int* __restrict__ col, int* __restrict__ counts,
                       int* __restrict__ rank, int n, int nbh,
                       const float* __restrict__ W1, const float* __restrict__ W2,
                       const float* __restrict__ Wout,
                       __half* __restrict__ Wt1, __half* __restrict__ Wt2,
                       __half* __restrict__ WtO) {
  if (blockIdx.x < nbh) {
    int e = blockIdx.x * blockDim.x + threadIdx.x;
    if (e < n) rank[e] = atomicAdd(&counts[col[e]], 1);
  } else {
    int id = (blockIdx.x - nbh) * blockDim.x + threadIdx.x;  // 38912 total
    if (id < 32768) {
      const float* W = (id < 16384) ? W1 : W2;
      __half* Wt = (id < 16384) ? Wt1 : Wt2;
      int i = id & 16383;
      int k = i >> 7, c = i & 127;
      Wt[c * 128 + k] = __float2half(W[i]);
    } else if (id < 38912) {
      int i = id - 32768;  // [48][128]: c = i>>7, k = i&127
      int c = i >> 7, k = i & 127;
      WtO[i] = (c < 40) ? __float2half(Wout[k * 40 + c]) : __half(0.0f);
    }
  }
}

__global__ void k_scan1(const int* __restrict__ counts, int* __restrict__ offs,
                        int* __restrict__ partials, float* __restrict__ dinv, int n) {
  __shared__ int buf[2][SCAN_BLK];
  int t = threadIdx.x;
  int gid = blockIdx.x * SCAN_BLK + t;
  int x = (gid < n) ? counts[gid] : 0;
  if (gid < n) dinv[gid] = rsqrtf((float)x + 1.0f);  // +1 self loop (fused k_dinv)
  int cur = 0;
  buf[0][t] = x;
  __syncthreads();
  int v = x;
  for (int off = 1; off < SCAN_BLK; off <<= 1) {
    v = buf[cur][t];
    if (t >= off) v += buf[cur][t - off];
    buf[cur ^ 1][t] = v;
    cur ^= 1;
    __syncthreads();
  }
  if (gid < n) offs[gid] = v - x;                 // block-local exclusive
  if (t == SCAN_BLK - 1) partials[blockIdx.x] = v; // block total
}

__global__ void k_scan2(int* __restrict__ partials, int* __restrict__ total_out, int nb) {
  __shared__ int buf[2][128];
  int t = threadIdx.x;
  int x = (t < nb) ? partials[t] : 0;
  int cur = 0;
  buf[0][t] = x;
  __syncthreads();
  int v = x;
  for (int off = 1; off < 128; off <<= 1) {
    v = buf[cur][t];
    if (t >= off) v += buf[cur][t - off];
    buf[cur ^ 1][t] = v;
    cur ^= 1;
    __syncthreads();
  }
  if (t < nb) partials[t] = v - x;   // exclusive
  if (t == 127) *total_out = v;      // grand total -> offs[N]
}

__global__ void k_scan3(int* __restrict__ offs, const int* __restrict__ partials, int n) {
  int gid = blockIdx.x * SCAN_BLK + threadIdx.x;
  if (gid < n) offs[gid] += partials[blockIdx.x];
}

// scatter packed 4B entry {w15 in bits 17..31, src in bits 0..16}; position
// precomputed (no atomic); grid-stride for MLP. 4B entries halve the
// (line x XCD) scattered-write amplification vs int2.
__global__ void k_fill(const int* __restrict__ erow, const int* __restrict__ ecol,
                       const int* __restrict__ rank, const int* __restrict__ offs,
                       const float* __restrict__ dinv, uint* __restrict__ adj, int n) {
  int stride = gridDim.x * blockDim.x;
  for (int e = blockIdx.x * blockDim.x + threadIdx.x; e < n; e += stride) {
    int r = erow[e], c = ecol[e];
    float w = dinv[r] * dinv[c];  // <= 0.5 (both endpoints have deg >= 1)
    uint q = (uint)fminf(w * 65536.0f + 0.5f, 32767.0f);
    adj[offs[c] + rank[e]] = (q << 17) | (uint)r;
  }
}

// ---------------- MFMA GEMM: C[n,128](fp16) = A[n,128] @ W[128,128] ----------------
// B register-resident per wave (128 VGPRs); waves grid-stride over 16-row tiles
// with 2-stage A prefetch; per-wave LDS repack epilogue (no barriers).

template <int A_F32>
__global__ __launch_bounds__(256) void k_gemm_mfma(const void* __restrict__ Aptr,
                                                   const __half* __restrict__ Wt,
                                                   __half* __restrict__ C, int n) {
  __shared__ __half Cs[4][16][136];
  int t = threadIdx.x;
  int wv = t >> 6, l = t & 63;
  int lr = l & 15, lg = l >> 4;

  f16x8 B[8][4];  // 128 VGPRs
#pragma unroll
  for (int nt = 0; nt < 8; ++nt)
#pragma unroll
    for (int ks = 0; ks < 4; ++ks)
      B[nt][ks] = *reinterpret_cast<const f16x8*>(Wt + (nt * 16 + lr) * 128 + ks * 32 + lg * 8);

  int ntiles = (n + 15) >> 4;
  int wgid = blockIdx.x * 4 + wv;
  int wstride = gridDim.x * 4;

  float4 rf_c[8], rf_n[8];
  f16x8 rh_c[4], rh_n[4];

  auto loadA = [&](int tile, float4* rf, f16x8* rh) {
    int arow = tile * 16 + lr;
    int crow = arow < n ? arow : 0;
    if (A_F32) {
      const float* A = (const float*)Aptr + (size_t)crow * 128 + lg * 8;
#pragma unroll
      for (int ks = 0; ks < 4; ++ks) {
        rf[ks * 2] = *reinterpret_cast<const float4*>(A + ks * 32);
        rf[ks * 2 + 1] = *reinterpret_cast<const float4*>(A + ks * 32 + 4);
      }
    } else {
      const __half* A = (const __half*)Aptr + (size_t)crow * 128 + lg * 8;
#pragma unroll
      for (int ks = 0; ks < 4; ++ks) rh[ks] = *reinterpret_cast<const f16x8*>(A + ks * 32);
    }
  };

  if (wgid < ntiles) loadA(wgid, rf_c, rh_c);

  for (int tile = wgid; tile < ntiles; tile += wstride) {
    int tnext = tile + wstride;
    if (tnext < ntiles) loadA(tnext, rf_n, rh_n);

    f16x8 a[4];
    if (A_F32) {
#pragma unroll
      for (int ks = 0; ks < 4; ++ks) {
        float4 u0 = rf_c[ks * 2], u1 = rf_c[ks * 2 + 1];
        f16x8 av;
        av[0] = (_Float16)u0.x; av[1] = (_Float16)u0.y;
        av[2] = (_Float16)u0.z; av[3] = (_Float16)u0.w;
        av[4] = (_Float16)u1.x; av[5] = (_Float16)u1.y;
        av[6] = (_Float16)u1.z; av[7] = (_Float16)u1.w;
        a[ks] = av;
      }
    } else {
#pragma unroll
      for (int ks = 0; ks < 4; ++ks) a[ks] = rh_c[ks];
    }

    f32x4 acc[8];
#pragma unroll
    for (int nt = 0; nt < 8; ++nt) acc[nt] = (f32x4){0.f, 0.f, 0.f, 0.f};
#pragma unroll
    for (int ks = 0; ks < 4; ++ks)
#pragma unroll
      for (int nt = 0; nt < 8; ++nt)
        acc[nt] = __builtin_amdgcn_mfma_f32_16x16x32_f16(a[ks], B[nt][ks], acc[nt], 0, 0, 0);

#pragma unroll
    for (int nt = 0; nt < 8; ++nt)
#pragma unroll
      for (int r = 0; r < 4; ++r)
        Cs[wv][lg * 4 + r][nt * 16 + lr] = __float2half(acc[nt][r]);
    // no barrier: per-wave LDS region, same-wave ds ops are in-order
#pragma unroll
    for (int j = 0; j < 4; ++j) {
      int row = j * 4 + lg;
      int gr = tile * 16 + row;
      if (gr < n)
        *reinterpret_cast<uint4*>(&C[(size_t)gr * 128 + lr * 8]) =
            *reinterpret_cast<const uint4*>(&Cs[wv][row][lr * 8]);
    }

    if (A_F32) {
#pragma unroll
      for (int j = 0; j < 8; ++j) rf_c[j] = rf_n[j];
    } else {
#pragma unroll
      for (int j = 0; j < 4; ++j) rh_c[j] = rh_n[j];
    }
  }
}

// ---------------- Aggregation ----------------
// z[i](fp16) = relu( dinv_i^2*h[i] + sum_e w_e h[src_e] + b ), one wave/node,
// fp16 h gathered as __half2, f32 accumulate. Packed 4B adjacency
// {w15<<17 | src} via wave-uniform scalar loads; 8-deep register pipeline;
// pad slots (own row, w=0).

__global__ __launch_bounds__(256) void k_agg(const __half* __restrict__ h,
                                             const int* __restrict__ offs,
                                             const uint* __restrict__ adj,
                                             const float* __restrict__ dinv,
                                             const float* __restrict__ bias,
                                             __half* __restrict__ out, int n) {
  int wid = (blockIdx.x * blockDim.x + threadIdx.x) >> 6;
  wid = __builtin_amdgcn_readfirstlane(wid);  // wave-uniform by construction
  int lane = threadIdx.x & 63;
  if (wid >= n) return;
  const __half2* hv = reinterpret_cast<const __half2*>(h);
  float ddst = dinv[wid];
  float w0 = ddst * ddst;
  float2 acc = __half22float2(hv[(size_t)wid * 64 + lane]);
  acc.x *= w0;
  acc.y *= w0;
  int s = offs[wid], e = offs[wid + 1];
  int cnt = e - s;
  const uint* ap = adj + s;
  const float qs = 1.0f / 65536.0f;

  float wm[8];
  __half2 hg[8];
#pragma unroll
  for (int j = 0; j < 8; ++j) {
    uint a = ap[j];                 // adj padded by 8: over-read safe
    bool v = j < cnt;
    int src = v ? (int)(a & 0x1FFFFu) : wid;
    wm[j] = v ? (float)(a >> 17) * qs : 0.f;
    hg[j] = hv[(size_t)src * 64 + lane];
  }
  for (int k0 = 0; k0 < cnt; k0 += 8) {
    int k1 = k0 + 8;
    bool more = k1 < cnt;  // wave-uniform
    float wn[8];
    __half2 hn[8];
    if (more) {
#pragma unroll
      for (int j = 0; j < 8; ++j) {
        uint a = ap[k1 + j];
        bool v = k1 + j < cnt;
        int src = v ? (int)(a & 0x1FFFFu) : wid;
        wn[j] = v ? (float)(a >> 17) * qs : 0.f;
        hn[j] = hv[(size_t)src * 64 + lane];
      }
    }
#pragma unroll
    for (int j = 0; j < 8; ++j) {
      float2 f = __half22float2(hg[j]);
      acc.x = fmaf(wm[j], f.x, acc.x);
      acc.y = fmaf(wm[j], f.y, acc.y);
    }
    if (more) {
#pragma unroll
      for (int j = 0; j < 8; ++j) {
        wm[j] = wn[j];
        hg[j] = hn[j];
      }
    }
  }

  float2 b = reinterpret_cast<const float2*>(bias)[lane];
  acc.x = fmaxf(acc.x + b.x, 0.f);
  acc.y = fmaxf(acc.y + b.y, 0.f);
  reinterpret_cast<__half2*>(out + (size_t)wid * 128)[lane] = __floats2half2_rn(acc.x, acc.y);
}

// ---------------- MFMA output GEMM: out[n,40](f32) = Z[n,128](fp16) @ Wout + b ----
// WoT zero-padded to [48][128] fp16; B register-resident (12 frags, 48 VGPRs);
// waves grid-stride over 16-row tiles; bias in-register; per-wave LDS repack
// (no barriers) then coalesced float4 stores of 40-f32 rows.

__global__ __launch_bounds__(256) void k_gemm_out(const __half* __restrict__ Z,
                                                  const __half* __restrict__ WtO,
                                                  const float* __restrict__ bout,
                                                  float* __restrict__ out, int n) {
  __shared__ float Cs[4][16][52];
  int t = threadIdx.x;
  int wv = t >> 6, l = t & 63;
  int lr = l & 15, lg = l >> 4;

  f16x8 B[3][4];  // 48 VGPRs
#pragma unroll
  for (int nt = 0; nt < 3; ++nt)
#pragma unroll
    for (int ks = 0; ks < 4; ++ks)
      B[nt][ks] = *reinterpret_cast<const f16x8*>(WtO + (nt * 16 + lr) * 128 + ks * 32 + lg * 8);

  float bb[3];
#pragma unroll
  for (int nt = 0; nt < 3; ++nt) {
    int c = nt * 16 + lr;
    bb[nt] = (c < 40) ? bout[c] : 0.f;
  }

  int ntiles = (n + 15) >> 4;
  int wgid = blockIdx.x * 4 + wv;
  int wstride = gridDim.x * 4;

  f16x8 rh_c[4], rh_n[4];
  auto loadA = [&](int tile, f16x8* rh) {
    int arow = tile * 16 + lr;
    int crow = arow < n ? arow : 0;
    const __half* A = Z + (size_t)crow * 128 + lg * 8;
#pragma unroll
    for (int ks = 0; ks < 4; ++ks) rh[ks] = *reinterpret_cast<const f16x8*>(A + ks * 32);
  };

  if (wgid < ntiles) loadA(wgid, rh_c);

  for (int tile = wgid; tile < ntiles; tile += wstride) {
    int tnext = tile + wstride;
    if (tnext < ntiles) loadA(tnext, rh_n);

    f32x4 acc[3];
#pragma unroll
    for (int nt = 0; nt < 3; ++nt) acc[nt] = (f32x4){0.f, 0.f, 0.f, 0.f};
#pragma unroll
    for (int ks = 0; ks < 4; ++ks)
#pragma unroll
      for (int nt = 0; nt < 3; ++nt)
        acc[nt] = __builtin_amdgcn_mfma_f32_16x16x32_f16(rh_c[ks], B[nt][ks], acc[nt], 0, 0, 0);

#pragma unroll
    for (int nt = 0; nt < 3; ++nt)
#pragma unroll
      for (int r = 0; r < 4; ++r)
        Cs[wv][lg * 4 + r][nt * 16 + lr] = acc[nt][r] + bb[nt];
    // no barrier: per-wave LDS region, same-wave ds ops are in-order
#pragma unroll
    for (int j = 0; j < 3; ++j) {
      int f = l + j * 64;  // 160 float4 chunks = 16 rows x 10
      if (f < 160) {
        int row = f / 10, c4 = f - row * 10;
        int gr = tile * 16 + row;
        if (gr < n)
          *reinterpret_cast<float4*>(&out[(size_t)gr * 40 + c4 * 4]) =
              *reinterpret_cast<const float4*>(&Cs[wv][row][c4 * 4]);
      }
    }
#pragma unroll
    for (int j = 0; j < 4; ++j) rh_c[j] = rh_n[j];
  }
}

// ---------------- launch ----------------

extern "C" void kernel_launch(void* const* d_in, const int* in_sizes, int n_in,
                              void* d_out, int out_size, void* d_ws, size_t ws_size,
                              hipStream_t stream) {
  const float* x = (const float*)d_in[0];
  const int* ei = (const int*)d_in[1];
  const float* W1 = (const float*)d_in[2];
  const float* b1 = (const float*)d_in[3];
  const float* W2 = (const float*)d_in[4];
  const float* b2 = (const float*)d_in[5];
  const float* Wout = (const float*)d_in[6];
  const float* bout = (const float*)d_in[7];
  float* out = (float*)d_out;

  const int N = in_sizes[0] / 128;
  const int E = in_sizes[1] / 2;
  const int* erow = ei;      // edge_index[0] = source j
  const int* ecol = ei + E;  // edge_index[1] = target i

  char* ws = (char*)d_ws;
  size_t off = 0;
  auto alloc = [&](size_t bytes) -> void* {
    void* p = ws + off;
    off = (off + bytes + 255) & ~(size_t)255;
    return p;
  };
  int* counts = (int*)alloc((size_t)N * 4);
  int* offs = (int*)alloc((size_t)(N + 1) * 4);
  float* dinv = (float*)alloc((size_t)N * 4);
  int* partials = (int*)alloc(128 * 4);
  int* rank = (int*)alloc((size_t)E * 4);
  uint* adj = (uint*)alloc((size_t)(E + 8) * 4);        // +8 pad: pipeline over-read
  __half* Wt1 = (__half*)alloc(128 * 128 * 2);
  __half* Wt2 = (__half*)alloc(128 * 128 * 2);
  __half* WtO = (__half*)alloc(48 * 128 * 2);
  __half* bufH = (__half*)alloc((size_t)N * 128 * 2);   // gemm output (h)
  __half* bufZ = (__half*)alloc((size_t)N * 128 * 2);   // agg output (z)

  hipMemsetAsync(counts, 0, (size_t)N * 4, stream);

  int nbh = (E + 255) / 256;
  k_hist<<<nbh + 152, 256, 0, stream>>>(ecol, counts, rank, E, nbh,
                                        W1, W2, Wout, Wt1, Wt2, WtO);

  int nb = (N + SCAN_BLK - 1) / SCAN_BLK;  // 98 for N=100000 (<=128 required)
  k_scan1<<<nb, SCAN_BLK, 0, stream>>>(counts, offs, partials, dinv, N);
  k_scan2<<<1, 128, 0, stream>>>(partials, offs + N, nb);
  k_scan3<<<nb, SCAN_BLK, 0, stream>>>(offs, partials, N);
  k_fill<<<1024, 256, 0, stream>>>(erow, ecol, rank, offs, dinv, adj, E);

  k_gemm_mfma<1><<<512, 256, 0, stream>>>(x, Wt1, bufH, N);
  k_agg<<<(N + 3) / 4, 256, 0, stream>>>(bufH, offs, adj, dinv, b1, bufZ, N);
  k_gemm_mfma<0><<<512, 256, 0, stream>>>(bufZ, Wt2, bufH, N);
  k_agg<<<(N + 3) / 4, 256, 0, stream>>>(bufH, offs, adj, dinv, b2, bufZ, N);
  k_gemm_out<<<512, 256, 0, stream>>>(bufZ, WtO, bout, out, N);
}

// Round 11
// 275.544 us; speedup vs baseline: 2.5984x; 1.0057x over previous
//
#include <hip/hip_runtime.h>
#include <hip/hip_bf16.h>
#include <hip/hip_fp16.h>

#define SCAN_BLK 1024
#define NCOPY 8

typedef _Float16 f16x8 __attribute__((ext_vector_type(8)));
typedef float f32x4 __attribute__((ext_vector_type(4)));

// ---------------- CSR build + weight convert (one launch) ----------------

// blocks [0, nbh): counts (8-copy, copy = blockIdx&7) + per-edge local rank.
// blocks [nbh, nbh+152): fp16 weight converts (independent work, saves a launch).
__global__ void k_hist(const int* __restrict__ col, int* __restrict__ counts8,
                       int* __restrict__ rank, int n, int nbh, int N,
                       const float* __restrict__ W1, const float* __restrict__ W2,
                       const float* __restrict__ Wout,
                       __half* __restrict__ Wt1, __half* __restrict__ Wt2,
                       __half* __restrict__ WtO) {
  if (blockIdx.x < nbh) {
    int e = blockIdx.x * blockDim.x + threadIdx.x;
    int cp = blockIdx.x & (NCOPY - 1);
    if (e < n) rank[e] = atomicAdd(&counts8[cp * N + col[e]], 1);
  } else {
    int id = (blockIdx.x - nbh) * blockDim.x + threadIdx.x;  // 38912 total
    if (id < 32768) {
      const float* W = (id < 16384) ? W1 : W2;
      __half* Wt = (id < 16384) ? Wt1 : Wt2;
      int i = id & 16383;
      int k = i >> 7, c = i & 127;
      Wt[c * 128 + k] = __float2half(W[i]);
    } else if (id < 38912) {
      int i = id - 32768;  // [48][128]: c = i>>7, k = i&127
      int c = i >> 7, k = i & 127;
      WtO[i] = (c < 40) ? __float2half(Wout[k * 40 + c]) : __half(0.0f);
    }
  }
}

__global__ void k_scan1(const int* __restrict__ counts8, int* __restrict__ offs,
                        int* __restrict__ partials, float* __restrict__ dinv,
                        int n, int N) {
  __shared__ int buf[2][SCAN_BLK];
  int t = threadIdx.x;
  int gid = blockIdx.x * SCAN_BLK + t;
  int x = 0;
  if (gid < n) {
#pragma unroll
    for (int k = 0; k < NCOPY; ++k) x += counts8[k * N + gid];
    dinv[gid] = rsqrtf((float)x + 1.0f);  // +1 self loop (fused k_dinv)
  }
  int cur = 0;
  buf[0][t] = x;
  __syncthreads();
  int v = x;
  for (int off = 1; off < SCAN_BLK; off <<= 1) {
    v = buf[cur][t];
    if (t >= off) v += buf[cur][t - off];
    buf[cur ^ 1][t] = v;
    cur ^= 1;
    __syncthreads();
  }
  if (gid < n) offs[gid] = v - x;                 // block-local exclusive
  if (t == SCAN_BLK - 1) partials[blockIdx.x] = v; // block total
}

__global__ void k_scan2(int* __restrict__ partials, int* __restrict__ total_out, int nb) {
  __shared__ int buf[2][128];
  int t = threadIdx.x;
  int x = (t < nb) ? partials[t] : 0;
  int cur = 0;
  buf[0][t] = x;
  __syncthreads();
  int v = x;
  for (int off = 1; off < 128; off <<= 1) {
    v = buf[cur][t];
    if (t >= off) v += buf[cur][t - off];
    buf[cur ^ 1][t] = v;
    cur ^= 1;
    __syncthreads();
  }
  if (t < nb) partials[t] = v - x;   // exclusive
  if (t == 127) *total_out = v;      // grand total -> offs[N]
}

// finalize offs and emit per-copy absolute bases
__global__ void k_scan3(int* __restrict__ offs, const int* __restrict__ partials,
                        const int* __restrict__ counts8, int* __restrict__ base8,
                        int n, int N) {
  int gid = blockIdx.x * SCAN_BLK + threadIdx.x;
  if (gid < n) {
    int v = offs[gid] + partials[blockIdx.x];
    offs[gid] = v;
#pragma unroll
    for (int k = 0; k < NCOPY; ++k) {
      base8[k * N + gid] = v;
      v += counts8[k * N + gid];
    }
  }
}

// scatter packed 4B entry {w15 in bits 17..31, src in bits 0..16}; position
// from per-copy base + local rank (no atomic); grid-stride for MLP.
__global__ void k_fill(const int* __restrict__ erow, const int* __restrict__ ecol,
                       const int* __restrict__ rank, const int* __restrict__ base8,
                       const float* __restrict__ dinv, uint* __restrict__ adj,
                       int n, int N) {
  int stride = gridDim.x * blockDim.x;
  for (int e = blockIdx.x * blockDim.x + threadIdx.x; e < n; e += stride) {
    int r = erow[e], c = ecol[e];
    int cp = (e >> 8) & (NCOPY - 1);  // hist block for edge e was e>>8
    float w = dinv[r] * dinv[c];      // <= 0.5 (both endpoints have deg >= 1)
    uint q = (uint)fminf(w * 65536.0f + 0.5f, 32767.0f);
    adj[base8[cp * N + c] + rank[e]] = (q << 17) | (uint)r;
  }
}

// ---------------- MFMA GEMM: C[n,128](fp16) = A[n,128] @ W[128,128] ----------------
// B register-resident per wave (128 VGPRs); waves grid-stride over 16-row tiles
// with 2-stage A prefetch; per-wave LDS repack epilogue (no barriers).

template <int A_F32>
__global__ __launch_bounds__(256) void k_gemm_mfma(const void* __restrict__ Aptr,
                                                   const __half* __restrict__ Wt,
                                                   __half* __restrict__ C, int n) {
  __shared__ __half Cs[4][16][136];
  int t = threadIdx.x;
  int wv = t >> 6, l = t & 63;
  int lr = l & 15, lg = l >> 4;

  f16x8 B[8][4];  // 128 VGPRs
#pragma unroll
  for (int nt = 0; nt < 8; ++nt)
#pragma unroll
    for (int ks = 0; ks < 4; ++ks)
      B[nt][ks] = *reinterpret_cast<const f16x8*>(Wt + (nt * 16 + lr) * 128 + ks * 32 + lg * 8);

  int ntiles = (n + 15) >> 4;
  int wgid = blockIdx.x * 4 + wv;
  int wstride = gridDim.x * 4;

  float4 rf_c[8], rf_n[8];
  f16x8 rh_c[4], rh_n[4];

  auto loadA = [&](int tile, float4* rf, f16x8* rh) {
    int arow = tile * 16 + lr;
    int crow = arow < n ? arow : 0;
    if (A_F32) {
      const float* A = (const float*)Aptr + (size_t)crow * 128 + lg * 8;
#pragma unroll
      for (int ks = 0; ks < 4; ++ks) {
        rf[ks * 2] = *reinterpret_cast<const float4*>(A + ks * 32);
        rf[ks * 2 + 1] = *reinterpret_cast<const float4*>(A + ks * 32 + 4);
      }
    } else {
      const __half* A = (const __half*)Aptr + (size_t)crow * 128 + lg * 8;
#pragma unroll
      for (int ks = 0; ks < 4; ++ks) rh[ks] = *reinterpret_cast<const f16x8*>(A + ks * 32);
    }
  };

  if (wgid < ntiles) loadA(wgid, rf_c, rh_c);

  for (int tile = wgid; tile < ntiles; tile += wstride) {
    int tnext = tile + wstride;
    if (tnext < ntiles) loadA(tnext, rf_n, rh_n);

    f16x8 a[4];
    if (A_F32) {
#pragma unroll
      for (int ks = 0; ks < 4; ++ks) {
        float4 u0 = rf_c[ks * 2], u1 = rf_c[ks * 2 + 1];
        f16x8 av;
        av[0] = (_Float16)u0.x; av[1] = (_Float16)u0.y;
        av[2] = (_Float16)u0.z; av[3] = (_Float16)u0.w;
        av[4] = (_Float16)u1.x; av[5] = (_Float16)u1.y;
        av[6] = (_Float16)u1.z; av[7] = (_Float16)u1.w;
        a[ks] = av;
      }
    } else {
#pragma unroll
      for (int ks = 0; ks < 4; ++ks) a[ks] = rh_c[ks];
    }

    f32x4 acc[8];
#pragma unroll
    for (int nt = 0; nt < 8; ++nt) acc[nt] = (f32x4){0.f, 0.f, 0.f, 0.f};
#pragma unroll
    for (int ks = 0; ks < 4; ++ks)
#pragma unroll
      for (int nt = 0; nt < 8; ++nt)
        acc[nt] = __builtin_amdgcn_mfma_f32_16x16x32_f16(a[ks], B[nt][ks], acc[nt], 0, 0, 0);

#pragma unroll
    for (int nt = 0; nt < 8; ++nt)
#pragma unroll
      for (int r = 0; r < 4; ++r)
        Cs[wv][lg * 4 + r][nt * 16 + lr] = __float2half(acc[nt][r]);
    // no barrier: per-wave LDS region, same-wave ds ops are in-order
#pragma unroll
    for (int j = 0; j < 4; ++j) {
      int row = j * 4 + lg;
      int gr = tile * 16 + row;
      if (gr < n)
        *reinterpret_cast<uint4*>(&C[(size_t)gr * 128 + lr * 8]) =
            *reinterpret_cast<const uint4*>(&Cs[wv][row][lr * 8]);
    }

    if (A_F32) {
#pragma unroll
      for (int j = 0; j < 8; ++j) rf_c[j] = rf_n[j];
    } else {
#pragma unroll
      for (int j = 0; j < 4; ++j) rh_c[j] = rh_n[j];
    }
  }
}

// ---------------- Aggregation ----------------
// z[i](fp16) = relu( dinv_i^2*h[i] + sum_e w_e h[src_e] + b ), one wave/node,
// fp16 h gathered as __half2, f32 accumulate. Packed 4B adjacency
// {w15<<17 | src} via wave-uniform scalar loads; 8-deep register pipeline;
// pad slots (own row, w=0).

__global__ __launch_bounds__(256) void k_agg(const __half* __restrict__ h,
                                             const int* __restrict__ offs,
                                             const uint* __restrict__ adj,
                                             const float* __restrict__ dinv,
                                             const float* __restrict__ bias,
                                             __half* __restrict__ out, int n) {
  int wid = (blockIdx.x * blockDim.x + threadIdx.x) >> 6;
  wid = __builtin_amdgcn_readfirstlane(wid);  // wave-uniform by construction
  int lane = threadIdx.x & 63;
  if (wid >= n) return;
  const __half2* hv = reinterpret_cast<const __half2*>(h);
  float ddst = dinv[wid];
  float w0 = ddst * ddst;
  float2 acc = __half22float2(hv[(size_t)wid * 64 + lane]);
  acc.x *= w0;
  acc.y *= w0;
  int s = offs[wid], e = offs[wid + 1];
  int cnt = e - s;
  const uint* ap = adj + s;
  const float qs = 1.0f / 65536.0f;

  float wm[8];
  __half2 hg[8];
#pragma unroll
  for (int j = 0; j < 8; ++j) {
    uint a = ap[j];                 // adj padded by 8: over-read safe
    bool v = j < cnt;
    int src = v ? (int)(a & 0x1FFFFu) : wid;
    wm[j] = v ? (float)(a >> 17) * qs : 0.f;
    hg[j] = hv[(size_t)src * 64 + lane];
  }
  for (int k0 = 0; k0 < cnt; k0 += 8) {
    int k1 = k0 + 8;
    bool more = k1 < cnt;  // wave-uniform
    float wn[8];
    __half2 hn[8];
    if (more) {
#pragma unroll
      for (int j = 0; j < 8; ++j) {
        uint a = ap[k1 + j];
        bool v = k1 + j < cnt;
        int src = v ? (int)(a & 0x1FFFFu) : wid;
        wn[j] = v ? (float)(a >> 17) * qs : 0.f;
        hn[j] = hv[(size_t)src * 64 + lane];
      }
    }
#pragma unroll
    for (int j = 0; j < 8; ++j) {
      float2 f = __half22float2(hg[j]);
      acc.x = fmaf(wm[j], f.x, acc.x);
      acc.y = fmaf(wm[j], f.y, acc.y);
    }
    if (more) {
#pragma unroll
      for (int j = 0; j < 8; ++j) {
        wm[j] = wn[j];
        hg[j] = hn[j];
      }
    }
  }

  float2 b = reinterpret_cast<const float2*>(bias)[lane];
  acc.x = fmaxf(acc.x + b.x, 0.f);
  acc.y = fmaxf(acc.y + b.y, 0.f);
  reinterpret_cast<__half2*>(out + (size_t)wid * 128)[lane] = __floats2half2_rn(acc.x, acc.y);
}

// ---------------- MFMA output GEMM: out[n,40](f32) = Z[n,128](fp16) @ Wout + b ----
// WoT zero-padded to [48][128] fp16; B register-resident (12 frags, 48 VGPRs);
// waves grid-stride over 16-row tiles; bias in-register; per-wave LDS repack
// (no barriers) then coalesced float4 stores of 40-f32 rows.

__global__ __launch_bounds__(256) void k_gemm_out(const __half* __restrict__ Z,
                                                  const __half* __restrict__ WtO,
                                                  const float* __restrict__ bout,
                                                  float* __restrict__ out, int n) {
  __shared__ float Cs[4][16][52];
  int t = threadIdx.x;
  int wv = t >> 6, l = t & 63;
  int lr = l & 15, lg = l >> 4;

  f16x8 B[3][4];  // 48 VGPRs
#pragma unroll
  for (int nt = 0; nt < 3; ++nt)
#pragma unroll
    for (int ks = 0; ks < 4; ++ks)
      B[nt][ks] = *reinterpret_cast<const f16x8*>(WtO + (nt * 16 + lr) * 128 + ks * 32 + lg * 8);

  float bb[3];
#pragma unroll
  for (int nt = 0; nt < 3; ++nt) {
    int c = nt * 16 + lr;
    bb[nt] = (c < 40) ? bout[c] : 0.f;
  }

  int ntiles = (n + 15) >> 4;
  int wgid = blockIdx.x * 4 + wv;
  int wstride = gridDim.x * 4;

  f16x8 rh_c[4], rh_n[4];
  auto loadA = [&](int tile, f16x8* rh) {
    int arow = tile * 16 + lr;
    int crow = arow < n ? arow : 0;
    const __half* A = Z + (size_t)crow * 128 + lg * 8;
#pragma unroll
    for (int ks = 0; ks < 4; ++ks) rh[ks] = *reinterpret_cast<const f16x8*>(A + ks * 32);
  };

  if (wgid < ntiles) loadA(wgid, rh_c);

  for (int tile = wgid; tile < ntiles; tile += wstride) {
    int tnext = tile + wstride;
    if (tnext < ntiles) loadA(tnext, rh_n);

    f32x4 acc[3];
#pragma unroll
    for (int nt = 0; nt < 3; ++nt) acc[nt] = (f32x4){0.f, 0.f, 0.f, 0.f};
#pragma unroll
    for (int ks = 0; ks < 4; ++ks)
#pragma unroll
      for (int nt = 0; nt < 3; ++nt)
        acc[nt] = __builtin_amdgcn_mfma_f32_16x16x32_f16(rh_c[ks], B[nt][ks], acc[nt], 0, 0, 0);

#pragma unroll
    for (int nt = 0; nt < 3; ++nt)
#pragma unroll
      for (int r = 0; r < 4; ++r)
        Cs[wv][lg * 4 + r][nt * 16 + lr] = acc[nt][r] + bb[nt];
    // no barrier: per-wave LDS region, same-wave ds ops are in-order
#pragma unroll
    for (int j = 0; j < 3; ++j) {
      int f = l + j * 64;  // 160 float4 chunks = 16 rows x 10
      if (f < 160) {
        int row = f / 10, c4 = f - row * 10;
        int gr = tile * 16 + row;
        if (gr < n)
          *reinterpret_cast<float4*>(&out[(size_t)gr * 40 + c4 * 4]) =
              *reinterpret_cast<const float4*>(&Cs[wv][row][c4 * 4]);
      }
    }
#pragma unroll
    for (int j = 0; j < 4; ++j) rh_c[j] = rh_n[j];
  }
}

// ---------------- launch ----------------

extern "C" void kernel_launch(void* const* d_in, const int* in_sizes, int n_in,
                              void* d_out, int out_size, void* d_ws, size_t ws_size,
                              hipStream_t stream) {
  const float* x = (const float*)d_in[0];
  const int* ei = (const int*)d_in[1];
  const float* W1 = (const float*)d_in[2];
  const float* b1 = (const float*)d_in[3];
  const float* W2 = (const float*)d_in[4];
  const float* b2 = (const float*)d_in[5];
  const float* Wout = (const float*)d_in[6];
  const float* bout = (const float*)d_in[7];
  float* out = (float*)d_out;

  const int N = in_sizes[0] / 128;
  const int E = in_sizes[1] / 2;
  const int* erow = ei;      // edge_index[0] = source j
  const int* ecol = ei + E;  // edge_index[1] = target i

  char* ws = (char*)d_ws;
  size_t off = 0;
  auto alloc = [&](size_t bytes) -> void* {
    void* p = ws + off;
    off = (off + bytes + 255) & ~(size_t)255;
    return p;
  };
  int* counts8 = (int*)alloc((size_t)N * NCOPY * 4);
  int* base8 = (int*)alloc((size_t)N * NCOPY * 4);
  int* offs = (int*)alloc((size_t)(N + 1) * 4);
  float* dinv = (float*)alloc((size_t)N * 4);
  int* partials = (int*)alloc(128 * 4);
  int* rank = (int*)alloc((size_t)E * 4);
  uint* adj = (uint*)alloc((size_t)(E + 8) * 4);        // +8 pad: pipeline over-read
  __half* Wt1 = (__half*)alloc(128 * 128 * 2);
  __half* Wt2 = (__half*)alloc(128 * 128 * 2);
  __half* WtO = (__half*)alloc(48 * 128 * 2);
  __half* bufH = (__half*)alloc((size_t)N * 128 * 2);   // gemm output (h)
  __half* bufZ = (__half*)alloc((size_t)N * 128 * 2);   // agg output (z)

  hipMemsetAsync(counts8, 0, (size_t)N * NCOPY * 4, stream);

  int nbh = (E + 255) / 256;
  k_hist<<<nbh + 152, 256, 0, stream>>>(ecol, counts8, rank, E, nbh, N,
                                        W1, W2, Wout, Wt1, Wt2, WtO);

  int nb = (N + SCAN_BLK - 1) / SCAN_BLK;  // 98 for N=100000 (<=128 required)
  k_scan1<<<nb, SCAN_BLK, 0, stream>>>(counts8, offs, partials, dinv, N, N);
  k_scan2<<<1, 128, 0, stream>>>(partials, offs + N, nb);
  k_scan3<<<nb, SCAN_BLK, 0, stream>>>(offs, partials, counts8, base8, N, N);
  k_fill<<<1024, 256, 0, stream>>>(erow, ecol, rank, base8, dinv, adj, E, N);

  k_gemm_mfma<1><<<512, 256, 0, stream>>>(x, Wt1, bufH, N);
  k_agg<<<(N + 3) / 4, 256, 0, stream>>>(bufH, offs, adj, dinv, b1, bufZ, N);
  k_gemm_mfma<0><<<512, 256, 0, stream>>>(bufZ, Wt2, bufH, N);
  k_agg<<<(N + 3) / 4, 256, 0, stream>>>(bufH, offs, adj, dinv, b2, bufZ, N);
  k_gemm_out<<<512, 256, 0, stream>>>(bufZ, WtO, bout, out, N);
}

// Round 12
// 218.014 us; speedup vs baseline: 3.2841x; 1.2639x over previous
//
#include <hip/hip_runtime.h>
#include <hip/hip_bf16.h>
#include <hip/hip_fp16.h>

#define NBKT 512  // allocated buckets (used: (N+255)>>8 = 391)

typedef _Float16 f16x8 __attribute__((ext_vector_type(8)));
typedef float f32x4 __attribute__((ext_vector_type(4)));

// ---------------- bucketed CSR build (LDS atomics only) ----------------

// blocks [0,256): per-block LDS histogram over 512 buckets (bucket = col>>8).
// blocks [256, 256+152): fp16 weight converts (independent, saves a launch).
__global__ __launch_bounds__(256) void k_bktA1(const int* __restrict__ ecol,
                                               int* __restrict__ blkBkt, int E, int chunk,
                                               const float* __restrict__ W1,
                                               const float* __restrict__ W2,
                                               const float* __restrict__ Wout,
                                               __half* __restrict__ Wt1,
                                               __half* __restrict__ Wt2,
                                               __half* __restrict__ WtO) {
  int t = threadIdx.x;
  if (blockIdx.x < 256) {
    __shared__ int h[NBKT];
    h[t] = 0;
    h[t + 256] = 0;
    __syncthreads();
    int s = blockIdx.x * chunk, e = min(s + chunk, E);
    for (int i = s + t; i < e; i += 256) atomicAdd(&h[ecol[i] >> 8], 1);
    __syncthreads();
    blkBkt[blockIdx.x * NBKT + t] = h[t];
    blkBkt[blockIdx.x * NBKT + t + 256] = h[t + 256];
  } else {
    int id = (blockIdx.x - 256) * 256 + t;  // 38912 total
    if (id < 32768) {
      const float* W = (id < 16384) ? W1 : W2;
      __half* Wt = (id < 16384) ? Wt1 : Wt2;
      int i = id & 16383;
      int k = i >> 7, c = i & 127;
      Wt[c * 128 + k] = __float2half(W[i]);
    } else if (id < 38912) {
      int i = id - 32768;  // [48][128]: c = i>>7, k = i&127
      int c = i >> 7, k = i & 127;
      WtO[i] = (c < 40) ? __float2half(Wout[k * 40 + c]) : __half(0.0f);
    }
  }
}

// per-bucket exclusive scan over the 256 block counts (in place) + bucket total
__global__ __launch_bounds__(256) void k_bktA2a(int* __restrict__ blkBkt,
                                                int* __restrict__ bktTotal) {
  __shared__ int buf[2][256];
  int b = blockIdx.x, t = threadIdx.x;
  int x = blkBkt[t * NBKT + b];
  int cur = 0;
  buf[0][t] = x;
  __syncthreads();
  int v = x;
  for (int off = 1; off < 256; off <<= 1) {
    v = buf[cur][t];
    if (t >= off) v += buf[cur][t - off];
    buf[cur ^ 1][t] = v;
    cur ^= 1;
    __syncthreads();
  }
  blkBkt[t * NBKT + b] = v - x;  // exclusive
  if (t == 255) bktTotal[b] = v;
}

// scan bucket totals -> bktBase[0..NBKT]; also offs[N] = E
__global__ __launch_bounds__(512) void k_bktA2b(const int* __restrict__ bktTotal,
                                                int* __restrict__ bktBase,
                                                int* __restrict__ offs, int N, int E) {
  __shared__ int buf[2][512];
  int t = threadIdx.x;
  int x = bktTotal[t];
  int cur = 0;
  buf[0][t] = x;
  __syncthreads();
  int v = x;
  for (int off = 1; off < 512; off <<= 1) {
    v = buf[cur][t];
    if (t >= off) v += buf[cur][t - off];
    buf[cur ^ 1][t] = v;
    cur ^= 1;
    __syncthreads();
  }
  bktBase[t] = v - x;  // exclusive
  if (t == 511) bktBase[512] = v;
  if (t == 0) offs[N] = E;
}

// scatter edges into bucket-sorted ebuf: entry = (c&255)<<17 | src
__global__ __launch_bounds__(256) void k_bktA3(const int* __restrict__ erow,
                                               const int* __restrict__ ecol,
                                               const int* __restrict__ blkBkt,
                                               const int* __restrict__ bktBase,
                                               uint* __restrict__ ebuf, int E, int chunk) {
  __shared__ int cur[NBKT];
  int t = threadIdx.x;
  cur[t] = bktBase[t] + blkBkt[blockIdx.x * NBKT + t];
  cur[t + 256] = bktBase[t + 256] + blkBkt[blockIdx.x * NBKT + t + 256];
  __syncthreads();
  int s = blockIdx.x * chunk, e = min(s + chunk, E);
  for (int i = s + t; i < e; i += 256) {
    int c = ecol[i], r = erow[i];
    int pos = atomicAdd(&cur[c >> 8], 1);  // LDS returning atomic
    ebuf[pos] = ((uint)(c & 255) << 17) | (uint)r;
  }
}

// per bucket: count 256 nodes (LDS), write dinv + offs (coalesced)
__global__ __launch_bounds__(256) void k_bktB1(const uint* __restrict__ ebuf,
                                               const int* __restrict__ bktBase,
                                               float* __restrict__ dinv,
                                               int* __restrict__ offs, int N) {
  __shared__ int cnt[256];
  __shared__ int buf[2][256];
  int b = blockIdx.x, t = threadIdx.x;
  int node0 = b << 8;
  cnt[t] = 0;
  __syncthreads();
  int s = bktBase[b], e = bktBase[b + 1];
  for (int i = s + t; i < e; i += 256) atomicAdd(&cnt[ebuf[i] >> 17], 1);
  __syncthreads();
  int x = cnt[t];
  if (node0 + t < N) dinv[node0 + t] = rsqrtf((float)x + 1.0f);  // +1 self loop
  int cur = 0;
  buf[0][t] = x;
  __syncthreads();
  int v = x;
  for (int off = 1; off < 256; off <<= 1) {
    v = buf[cur][t];
    if (t >= off) v += buf[cur][t - off];
    buf[cur ^ 1][t] = v;
    cur ^= 1;
    __syncthreads();
  }
  if (node0 + t < N) offs[node0 + t] = s + v - x;  // global exclusive
}

// per bucket: rank via LDS cursor, write packed adj {w15<<17 | src}
__global__ __launch_bounds__(256) void k_bktB2(const uint* __restrict__ ebuf,
                                               const int* __restrict__ bktBase,
                                               const int* __restrict__ offs,
                                               const float* __restrict__ dinv,
                                               uint* __restrict__ adj, int N) {
  __shared__ int cur[256];
  int b = blockIdx.x, t = threadIdx.x;
  int node0 = b << 8;
  cur[t] = (node0 + t < N) ? offs[node0 + t] : 0;
  __syncthreads();
  int s = bktBase[b], e = bktBase[b + 1];
  for (int i = s + t; i < e; i += 256) {
    uint ent = ebuf[i];
    int clow = (int)(ent >> 17);
    int r = (int)(ent & 0x1FFFFu);
    int pos = atomicAdd(&cur[clow], 1);  // LDS returning atomic
    float w = dinv[r] * dinv[node0 + clow];  // <= 0.5
    uint q = (uint)fminf(w * 65536.0f + 0.5f, 32767.0f);
    adj[pos] = (q << 17) | (uint)r;
  }
}

// ---------------- MFMA GEMM: C[n,128](fp16) = A[n,128] @ W[128,128] ----------------
// B register-resident per wave (128 VGPRs); waves grid-stride over 16-row tiles
// with 2-stage A prefetch; per-wave LDS repack epilogue (no barriers).

template <int A_F32>
__global__ __launch_bounds__(256) void k_gemm_mfma(const void* __restrict__ Aptr,
                                                   const __half* __restrict__ Wt,
                                                   __half* __restrict__ C, int n) {
  __shared__ __half Cs[4][16][136];
  int t = threadIdx.x;
  int wv = t >> 6, l = t & 63;
  int lr = l & 15, lg = l >> 4;

  f16x8 B[8][4];  // 128 VGPRs
#pragma unroll
  for (int nt = 0; nt < 8; ++nt)
#pragma unroll
    for (int ks = 0; ks < 4; ++ks)
      B[nt][ks] = *reinterpret_cast<const f16x8*>(Wt + (nt * 16 + lr) * 128 + ks * 32 + lg * 8);

  int ntiles = (n + 15) >> 4;
  int wgid = blockIdx.x * 4 + wv;
  int wstride = gridDim.x * 4;

  float4 rf_c[8], rf_n[8];
  f16x8 rh_c[4], rh_n[4];

  auto loadA = [&](int tile, float4* rf, f16x8* rh) {
    int arow = tile * 16 + lr;
    int crow = arow < n ? arow : 0;
    if (A_F32) {
      const float* A = (const float*)Aptr + (size_t)crow * 128 + lg * 8;
#pragma unroll
      for (int ks = 0; ks < 4; ++ks) {
        rf[ks * 2] = *reinterpret_cast<const float4*>(A + ks * 32);
        rf[ks * 2 + 1] = *reinterpret_cast<const float4*>(A + ks * 32 + 4);
      }
    } else {
      const __half* A = (const __half*)Aptr + (size_t)crow * 128 + lg * 8;
#pragma unroll
      for (int ks = 0; ks < 4; ++ks) rh[ks] = *reinterpret_cast<const f16x8*>(A + ks * 32);
    }
  };

  if (wgid < ntiles) loadA(wgid, rf_c, rh_c);

  for (int tile = wgid; tile < ntiles; tile += wstride) {
    int tnext = tile + wstride;
    if (tnext < ntiles) loadA(tnext, rf_n, rh_n);

    f16x8 a[4];
    if (A_F32) {
#pragma unroll
      for (int ks = 0; ks < 4; ++ks) {
        float4 u0 = rf_c[ks * 2], u1 = rf_c[ks * 2 + 1];
        f16x8 av;
        av[0] = (_Float16)u0.x; av[1] = (_Float16)u0.y;
        av[2] = (_Float16)u0.z; av[3] = (_Float16)u0.w;
        av[4] = (_Float16)u1.x; av[5] = (_Float16)u1.y;
        av[6] = (_Float16)u1.z; av[7] = (_Float16)u1.w;
        a[ks] = av;
      }
    } else {
#pragma unroll
      for (int ks = 0; ks < 4; ++ks) a[ks] = rh_c[ks];
    }

    f32x4 acc[8];
#pragma unroll
    for (int nt = 0; nt < 8; ++nt) acc[nt] = (f32x4){0.f, 0.f, 0.f, 0.f};
#pragma unroll
    for (int ks = 0; ks < 4; ++ks)
#pragma unroll
      for (int nt = 0; nt < 8; ++nt)
        acc[nt] = __builtin_amdgcn_mfma_f32_16x16x32_f16(a[ks], B[nt][ks], acc[nt], 0, 0, 0);

#pragma unroll
    for (int nt = 0; nt < 8; ++nt)
#pragma unroll
      for (int r = 0; r < 4; ++r)
        Cs[wv][lg * 4 + r][nt * 16 + lr] = __float2half(acc[nt][r]);
    // no barrier: per-wave LDS region, same-wave ds ops are in-order
#pragma unroll
    for (int j = 0; j < 4; ++j) {
      int row = j * 4 + lg;
      int gr = tile * 16 + row;
      if (gr < n)
        *reinterpret_cast<uint4*>(&C[(size_t)gr * 128 + lr * 8]) =
            *reinterpret_cast<const uint4*>(&Cs[wv][row][lr * 8]);
    }

    if (A_F32) {
#pragma unroll
      for (int j = 0; j < 8; ++j) rf_c[j] = rf_n[j];
    } else {
#pragma unroll
      for (int j = 0; j < 4; ++j) rh_c[j] = rh_n[j];
    }
  }
}

// ---------------- Aggregation ----------------
// z[i](fp16) = relu( dinv_i^2*h[i] + sum_e w_e h[src_e] + b ), one wave/node,
// fp16 h gathered as __half2, f32 accumulate. Packed 4B adjacency
// {w15<<17 | src} via wave-uniform scalar loads; 8-deep register pipeline;
// pad slots (own row, w=0).

__global__ __launch_bounds__(256) void k_agg(const __half* __restrict__ h,
                                             const int* __restrict__ offs,
                                             const uint* __restrict__ adj,
                                             const float* __restrict__ dinv,
                                             const float* __restrict__ bias,
                                             __half* __restrict__ out, int n) {
  int wid = (blockIdx.x * blockDim.x + threadIdx.x) >> 6;
  wid = __builtin_amdgcn_readfirstlane(wid);  // wave-uniform by construction
  int lane = threadIdx.x & 63;
  if (wid >= n) return;
  const __half2* hv = reinterpret_cast<const __half2*>(h);
  float ddst = dinv[wid];
  float w0 = ddst * ddst;
  float2 acc = __half22float2(hv[(size_t)wid * 64 + lane]);
  acc.x *= w0;
  acc.y *= w0;
  int s = offs[wid], e = offs[wid + 1];
  int cnt = e - s;
  const uint* ap = adj + s;
  const float qs = 1.0f / 65536.0f;

  float wm[8];
  __half2 hg[8];
#pragma unroll
  for (int j = 0; j < 8; ++j) {
    uint a = ap[j];                 // adj padded by 8: over-read safe
    bool v = j < cnt;
    int src = v ? (int)(a & 0x1FFFFu) : wid;
    wm[j] = v ? (float)(a >> 17) * qs : 0.f;
    hg[j] = hv[(size_t)src * 64 + lane];
  }
  for (int k0 = 0; k0 < cnt; k0 += 8) {
    int k1 = k0 + 8;
    bool more = k1 < cnt;  // wave-uniform
    float wn[8];
    __half2 hn[8];
    if (more) {
#pragma unroll
      for (int j = 0; j < 8; ++j) {
        uint a = ap[k1 + j];
        bool v = k1 + j < cnt;
        int src = v ? (int)(a & 0x1FFFFu) : wid;
        wn[j] = v ? (float)(a >> 17) * qs : 0.f;
        hn[j] = hv[(size_t)src * 64 + lane];
      }
    }
#pragma unroll
    for (int j = 0; j < 8; ++j) {
      float2 f = __half22float2(hg[j]);
      acc.x = fmaf(wm[j], f.x, acc.x);
      acc.y = fmaf(wm[j], f.y, acc.y);
    }
    if (more) {
#pragma unroll
      for (int j = 0; j < 8; ++j) {
        wm[j] = wn[j];
        hg[j] = hn[j];
      }
    }
  }

  float2 b = reinterpret_cast<const float2*>(bias)[lane];
  acc.x = fmaxf(acc.x + b.x, 0.f);
  acc.y = fmaxf(acc.y + b.y, 0.f);
  reinterpret_cast<__half2*>(out + (size_t)wid * 128)[lane] = __floats2half2_rn(acc.x, acc.y);
}

// ---------------- MFMA output GEMM: out[n,40](f32) = Z[n,128](fp16) @ Wout + b ----
// WoT zero-padded to [48][128] fp16; B register-resident (12 frags, 48 VGPRs);
// waves grid-stride over 16-row tiles; bias in-register; per-wave LDS repack
// (no barriers) then coalesced float4 stores of 40-f32 rows.

__global__ __launch_bounds__(256) void k_gemm_out(const __half* __restrict__ Z,
                                                  const __half* __restrict__ WtO,
                                                  const float* __restrict__ bout,
                                                  float* __restrict__ out, int n) {
  __shared__ float Cs[4][16][52];
  int t = threadIdx.x;
  int wv = t >> 6, l = t & 63;
  int lr = l & 15, lg = l >> 4;

  f16x8 B[3][4];  // 48 VGPRs
#pragma unroll
  for (int nt = 0; nt < 3; ++nt)
#pragma unroll
    for (int ks = 0; ks < 4; ++ks)
      B[nt][ks] = *reinterpret_cast<const f16x8*>(WtO + (nt * 16 + lr) * 128 + ks * 32 + lg * 8);

  float bb[3];
#pragma unroll
  for (int nt = 0; nt < 3; ++nt) {
    int c = nt * 16 + lr;
    bb[nt] = (c < 40) ? bout[c] : 0.f;
  }

  int ntiles = (n + 15) >> 4;
  int wgid = blockIdx.x * 4 + wv;
  int wstride = gridDim.x * 4;

  f16x8 rh_c[4], rh_n[4];
  auto loadA = [&](int tile, f16x8* rh) {
    int arow = tile * 16 + lr;
    int crow = arow < n ? arow : 0;
    const __half* A = Z + (size_t)crow * 128 + lg * 8;
#pragma unroll
    for (int ks = 0; ks < 4; ++ks) rh[ks] = *reinterpret_cast<const f16x8*>(A + ks * 32);
  };

  if (wgid < ntiles) loadA(wgid, rh_c);

  for (int tile = wgid; tile < ntiles; tile += wstride) {
    int tnext = tile + wstride;
    if (tnext < ntiles) loadA(tnext, rh_n);

    f32x4 acc[3];
#pragma unroll
    for (int nt = 0; nt < 3; ++nt) acc[nt] = (f32x4){0.f, 0.f, 0.f, 0.f};
#pragma unroll
    for (int ks = 0; ks < 4; ++ks)
#pragma unroll
      for (int nt = 0; nt < 3; ++nt)
        acc[nt] = __builtin_amdgcn_mfma_f32_16x16x32_f16(rh_c[ks], B[nt][ks], acc[nt], 0, 0, 0);

#pragma unroll
    for (int nt = 0; nt < 3; ++nt)
#pragma unroll
      for (int r = 0; r < 4; ++r)
        Cs[wv][lg * 4 + r][nt * 16 + lr] = acc[nt][r] + bb[nt];
    // no barrier: per-wave LDS region, same-wave ds ops are in-order
#pragma unroll
    for (int j = 0; j < 3; ++j) {
      int f = l + j * 64;  // 160 float4 chunks = 16 rows x 10
      if (f < 160) {
        int row = f / 10, c4 = f - row * 10;
        int gr = tile * 16 + row;
        if (gr < n)
          *reinterpret_cast<float4*>(&out[(size_t)gr * 40 + c4 * 4]) =
              *reinterpret_cast<const float4*>(&Cs[wv][row][c4 * 4]);
      }
    }
#pragma unroll
    for (int j = 0; j < 4; ++j) rh_c[j] = rh_n[j];
  }
}

// ---------------- launch ----------------

extern "C" void kernel_launch(void* const* d_in, const int* in_sizes, int n_in,
                              void* d_out, int out_size, void* d_ws, size_t ws_size,
                              hipStream_t stream) {
  const float* x = (const float*)d_in[0];
  const int* ei = (const int*)d_in[1];
  const float* W1 = (const float*)d_in[2];
  const float* b1 = (const float*)d_in[3];
  const float* W2 = (const float*)d_in[4];
  const float* b2 = (const float*)d_in[5];
  const float* Wout = (const float*)d_in[6];
  const float* bout = (const float*)d_in[7];
  float* out = (float*)d_out;

  const int N = in_sizes[0] / 128;
  const int E = in_sizes[1] / 2;
  const int* erow = ei;      // edge_index[0] = source j
  const int* ecol = ei + E;  // edge_index[1] = target i

  char* ws = (char*)d_ws;
  size_t off = 0;
  auto alloc = [&](size_t bytes) -> void* {
    void* p = ws + off;
    off = (off + bytes + 255) & ~(size_t)255;
    return p;
  };
  int* blkBkt = (int*)alloc((size_t)256 * NBKT * 4);
  int* bktTotal = (int*)alloc(NBKT * 4);
  int* bktBase = (int*)alloc((NBKT + 1) * 4);
  int* offs = (int*)alloc((size_t)(N + 1) * 4);
  float* dinv = (float*)alloc((size_t)N * 4);
  uint* ebuf = (uint*)alloc((size_t)E * 4);
  uint* adj = (uint*)alloc((size_t)(E + 8) * 4);        // +8 pad: pipeline over-read
  __half* Wt1 = (__half*)alloc(128 * 128 * 2);
  __half* Wt2 = (__half*)alloc(128 * 128 * 2);
  __half* WtO = (__half*)alloc(48 * 128 * 2);
  __half* bufH = (__half*)alloc((size_t)N * 128 * 2);   // gemm output (h)
  __half* bufZ = (__half*)alloc((size_t)N * 128 * 2);   // agg output (z)

  int chunk = (E + 255) / 256;       // edges per A-phase block
  int nbk = (N + 255) >> 8;          // used buckets (391)

  k_bktA1<<<256 + 152, 256, 0, stream>>>(ecol, blkBkt, E, chunk, W1, W2, Wout,
                                         Wt1, Wt2, WtO);
  k_bktA2a<<<NBKT, 256, 0, stream>>>(blkBkt, bktTotal);
  k_bktA2b<<<1, 512, 0, stream>>>(bktTotal, bktBase, offs, N, E);
  k_bktA3<<<256, 256, 0, stream>>>(erow, ecol, blkBkt, bktBase, ebuf, E, chunk);
  k_bktB1<<<nbk, 256, 0, stream>>>(ebuf, bktBase, dinv, offs, N);
  k_bktB2<<<nbk, 256, 0, stream>>>(ebuf, bktBase, offs, dinv, adj, N);

  k_gemm_mfma<1><<<512, 256, 0, stream>>>(x, Wt1, bufH, N);
  k_agg<<<(N + 3) / 4, 256, 0, stream>>>(bufH, offs, adj, dinv, b1, bufZ, N);
  k_gemm_mfma<0><<<512, 256, 0, stream>>>(bufZ, Wt2, bufH, N);
  k_agg<<<(N + 3) / 4, 256, 0, stream>>>(bufH, offs, adj, dinv, b2, bufZ, N);
  k_gemm_out<<<512, 256, 0, stream>>>(bufZ, WtO, bout, out, N);
}